// Round 2
// baseline (1657.048 us; speedup 1.0000x reference)
//
#include <hip/hip_runtime.h>

typedef unsigned short u16;
typedef __attribute__((ext_vector_type(8))) short s16x8;
typedef __attribute__((ext_vector_type(4))) float f32x4;

__device__ __forceinline__ float bf2f_(u16 b) { return __uint_as_float(((unsigned)b) << 16); }
__device__ __forceinline__ u16 f2bf_(float f) {
  unsigned u = __float_as_uint(f);
  return (u16)((u + 0x7FFFu + ((u >> 16) & 1u)) >> 16);
}

// ---------------- dtype detection (deterministic, device-side) ----------------
// flags[0]: count of "sane bf16 exponent" among 4096 even-indexed u16s of x
//           (bf16 data -> ~4090, fp32 data -> ~650). is_bf16 = flags[0] >= 2048.
// flags[1]: count of nonzero odd int32 words in edge_index head
//           (int32 data -> ~4095, int64 data -> 0). is_int64 = flags[1] < 100.
__global__ void k_zeroflags(int* f) { if (threadIdx.x < 4) f[threadIdx.x] = 0; }

__global__ __launch_bounds__(256) void k_detect(const u16* __restrict__ xb,
                                                const int* __restrict__ ei,
                                                int* __restrict__ flags) {
  int i = blockIdx.x * 256 + threadIdx.x;  // 4096 threads
  int e8 = (xb[2 * i] >> 7) & 0xFF;
  int sane = (e8 >= 100 && e8 <= 140) ? 1 : 0;
  int nz = (ei[2 * i + 1] != 0) ? 1 : 0;
  #pragma unroll
  for (int off = 32; off; off >>= 1) { sane += __shfl_down(sane, off); nz += __shfl_down(nz, off); }
  if ((threadIdx.x & 63) == 0) { atomicAdd(&flags[0], sane); atomicAdd(&flags[1], nz); }
}

// load float input (bf16 or fp32 per flag) -> fp32 workspace
__global__ void k_loadf(const void* __restrict__ src, float* __restrict__ dst, int n,
                        const int* __restrict__ flags) {
  int i = blockIdx.x * 256 + threadIdx.x;
  if (i >= n) return;
  bool isbf = flags[0] >= 2048;
  dst[i] = isbf ? bf2f_(((const u16*)src)[i]) : ((const float*)src)[i];
}

// ---------------- setup ----------------
__global__ void k_fill0(float4* __restrict__ p, long n4) {
  long i = blockIdx.x * 256L + threadIdx.x;
  long stride = (long)gridDim.x * 256L;
  for (; i < n4; i += stride) p[i] = make_float4(0.f, 0.f, 0.f, 0.f);
}

__global__ void k_edges(const int* __restrict__ ei, float* __restrict__ A, int E, int n,
                        const int* __restrict__ flags) {
  int e = blockIdx.x * 256 + threadIdx.x;
  if (e >= E) return;
  bool is64 = flags[1] < 100;
  int src = is64 ? ei[2 * e] : ei[e];
  int dst = is64 ? ei[2 * E + 2 * e] : ei[E + e];
  if (src >= 0 && src < n && dst >= 0 && dst < n)
    atomicAdd(&A[(size_t)dst * n + src], 1.0f);
}

__global__ void k_copy(const float* __restrict__ src, float* __restrict__ dst, int n) {
  int i = blockIdx.x * 256 + threadIdx.x;
  if (i < n) dst[i] = src[i];
}

// ---------------- GCN pieces ----------------
// dinv[row] = rsqrt(rowsum(A) + 2)
__global__ __launch_bounds__(256) void k_dinv(const float* __restrict__ A, float* __restrict__ dinv, int n) {
  int row = blockIdx.x;
  const float* r = A + (size_t)row * n;
  float s = 0.f;
  for (int j = threadIdx.x; j < n; j += 256) s += r[j];
  #pragma unroll
  for (int off = 32; off; off >>= 1) s += __shfl_down(s, off);
  __shared__ float red[4];
  int wave = threadIdx.x >> 6, lane = threadIdx.x & 63;
  if (lane == 0) red[wave] = s;
  __syncthreads();
  if (threadIdx.x == 0) {
    float deg = red[0] + red[1] + red[2] + red[3] + 2.0f;
    dinv[row] = rsqrtf(deg);
  }
}

// yp[r][c] = dinv[r] * sum_k x[r][k] * W[k][c]    (16 rows per block)
__global__ __launch_bounds__(256) void k_xw(const float* __restrict__ x, const float* __restrict__ W,
                                            const float* __restrict__ dinv, float* __restrict__ yp, int n) {
  __shared__ float xs_[16 * 128];
  int t = threadIdx.x;
  int row0 = blockIdx.x * 16;
  for (int e = t; e < 16 * 128; e += 256) {
    int r = e >> 7, c = e & 127;
    xs_[e] = x[(size_t)(row0 + r) * 128 + c];
  }
  __syncthreads();
  int c = t & 127, rh = t >> 7;
  float acc[8];
  #pragma unroll
  for (int ri = 0; ri < 8; ++ri) acc[ri] = 0.f;
  for (int k = 0; k < 128; ++k) {
    float wv = W[k * 128 + c];
    #pragma unroll
    for (int ri = 0; ri < 8; ++ri) acc[ri] += xs_[(rh * 8 + ri) * 128 + k] * wv;
  }
  #pragma unroll
  for (int ri = 0; ri < 8; ++ri) {
    int r = row0 + rh * 8 + ri;
    yp[(size_t)r * 128 + c] = dinv[r] * acc[ri];
  }
}

// z = A @ yp  (n x n fp32 @ n x 128), 16 rows per block
__global__ __launch_bounds__(256) void k_zgemm(const float* __restrict__ A, const float* __restrict__ y,
                                               float* __restrict__ z, int n) {
  __shared__ float As_[16 * 32];
  __shared__ float Ys_[32 * 128];
  int t = threadIdx.x;
  int row0 = blockIdx.x * 16;
  int tr = t >> 5, tc = t & 31;
  float acc[2][4];
  #pragma unroll
  for (int i = 0; i < 2; ++i)
    #pragma unroll
    for (int j = 0; j < 4; ++j) acc[i][j] = 0.f;
  for (int k0 = 0; k0 < n; k0 += 32) {
    __syncthreads();
    for (int e = t; e < 512; e += 256) {
      int r = e >> 5, c = e & 31;
      As_[e] = A[(size_t)(row0 + r) * n + k0 + c];
    }
    for (int e = t; e < 4096; e += 256) {
      int r = e >> 7, c = e & 127;
      Ys_[e] = y[(size_t)(k0 + r) * 128 + c];
    }
    __syncthreads();
    for (int kk = 0; kk < 32; ++kk) {
      float yv[4];
      #pragma unroll
      for (int j = 0; j < 4; ++j) yv[j] = Ys_[kk * 128 + tc + j * 32];
      #pragma unroll
      for (int i = 0; i < 2; ++i) {
        float av = As_[(tr * 2 + i) * 32 + kk];
        #pragma unroll
        for (int j = 0; j < 4; ++j) acc[i][j] += av * yv[j];
      }
    }
  }
  #pragma unroll
  for (int i = 0; i < 2; ++i)
    #pragma unroll
    for (int j = 0; j < 4; ++j)
      z[(size_t)(row0 + tr * 2 + i) * 128 + tc + j * 32] = acc[i][j];
}

// intermediate epilogue: out = leakyrelu( dinv[r]*(z + 2*yp) + b[c] ), fp32
__global__ void k_epi(const float* __restrict__ z, const float* __restrict__ yp,
                      const float* __restrict__ dinv, const float* __restrict__ b,
                      float* __restrict__ outf, int tot, int act) {
  int i = blockIdx.x * 256 + threadIdx.x;
  if (i >= tot) return;
  int r = i >> 7, c = i & 127;
  float v = dinv[r] * (z[i] + 2.0f * yp[i]) + b[c];
  if (act) v = (v >= 0.f) ? v : 0.01f * v;
  outf[i] = v;
}

// final epilogue: no activation; write bf16 or fp32 per flag
__global__ void k_epi_out(const float* __restrict__ z, const float* __restrict__ yp,
                          const float* __restrict__ dinv, const float* __restrict__ b,
                          void* __restrict__ out, int tot, const int* __restrict__ flags) {
  int i = blockIdx.x * 256 + threadIdx.x;
  if (i >= tot) return;
  int r = i >> 7, c = i & 127;
  float v = dinv[r] * (z[i] + 2.0f * yp[i]) + b[c];
  if (flags[0] >= 2048) ((u16*)out)[i] = f2bf_(v);
  else ((float*)out)[i] = v;
}

// ---------------- top-k pooling ----------------
__global__ __launch_bounds__(256) void k_score(const float* __restrict__ x, const float* __restrict__ w,
                                               float* __restrict__ ts, int n) {
  int wave = threadIdx.x >> 6, lane = threadIdx.x & 63;
  int row = blockIdx.x * 4 + wave;
  float w0 = w[lane], w1 = w[64 + lane];
  float nrm = w0 * w0 + w1 * w1;
  #pragma unroll
  for (int off = 32; off; off >>= 1) nrm += __shfl_down(nrm, off);
  nrm = sqrtf(__shfl(nrm, 0));
  if (row < n) {
    const float* xr = x + (size_t)row * 128;
    float d = xr[lane] * w0 + xr[64 + lane] * w1;
    #pragma unroll
    for (int off = 32; off; off >>= 1) d += __shfl_down(d, off);
    if (lane == 0) ts[row] = tanhf(d / nrm);
  }
}

// full bitonic sort (descending score, lower index first on ties) -> perm[0..k)
__global__ __launch_bounds__(1024) void k_topk(const float* __restrict__ ts, int n,
                                               int* __restrict__ perm, int k) {
  __shared__ unsigned long long keys[4096];
  int t = threadIdx.x;
  for (int i = t; i < n; i += 1024) {
    unsigned bits = __float_as_uint(ts[i]);
    unsigned u = (bits & 0x80000000u) ? ~bits : (bits | 0x80000000u);
    keys[i] = ((unsigned long long)u << 32) | (unsigned)(0xFFFFFFFFu - (unsigned)i);
  }
  __syncthreads();
  for (int size = 2; size <= n; size <<= 1) {
    for (int stride = size >> 1; stride > 0; stride >>= 1) {
      for (int i = t; i < n; i += 1024) {
        int l = i ^ stride;
        if (l > i) {
          bool descSeg = ((i & size) == 0);
          unsigned long long ki = keys[i], kl = keys[l];
          bool sw = descSeg ? (ki < kl) : (ki > kl);
          if (sw) { keys[i] = kl; keys[l] = ki; }
        }
      }
      __syncthreads();
    }
  }
  for (int i = t; i < k; i += 1024)
    perm[i] = (int)(0xFFFFFFFFu - (unsigned)(keys[i] & 0xFFFFFFFFu));
}

__global__ void k_gather(const float* __restrict__ x, const int* __restrict__ perm,
                         const float* __restrict__ ts, float* __restrict__ out, int k) {
  int i = blockIdx.x * 256 + threadIdx.x;
  if (i < k * 128) {
    int r = i >> 7, c = i & 127;
    int p = perm[r];
    out[i] = x[(size_t)p * 128 + c] * ts[p];
  }
}

__global__ void k_scatadd(float* __restrict__ dst, const float* __restrict__ src,
                          const int* __restrict__ perm, int k) {
  int i = blockIdx.x * 256 + threadIdx.x;
  if (i < k * 128) {
    int r = i >> 7, c = i & 127;
    dst[(size_t)perm[r] * 128 + c] += src[i];
  }
}

// ---------------- augment: bf16 A1 (offdiag A, diag 1) + transpose ----------------
__global__ __launch_bounds__(256) void k_prep(const float* __restrict__ A, u16* __restrict__ A1,
                                              u16* __restrict__ A1T, int n) {
  __shared__ float tile[32][33];
  int bi = blockIdx.y, bj = blockIdx.x;
  int tx = threadIdx.x & 31, ty = threadIdx.x >> 5;
  int r0 = bi * 32, c0 = bj * 32;
  #pragma unroll
  for (int yy = 0; yy < 4; ++yy) {
    int r = ty * 4 + yy;
    int gr = r0 + r, gc = c0 + tx;
    float v = A[(size_t)gr * n + gc];
    if (gr == gc) v = 1.0f;
    tile[r][tx] = v;
    A1[(size_t)gr * n + gc] = f2bf_(v);
  }
  __syncthreads();
  #pragma unroll
  for (int yy = 0; yy < 4; ++yy) {
    int r = ty * 4 + yy;
    int gr = c0 + r, gc = r0 + tx;
    A1T[(size_t)gr * n + gc] = f2bf_(tile[tx][r]);
  }
}

// C[i][j] = (A1@A1)[perm_i][perm_j], diag -> 0; 128x128 tile, 4 waves, mfma 16x16x32 bf16
__global__ __launch_bounds__(256) void k_mfma_pool(const u16* __restrict__ A1, const u16* __restrict__ A1T,
                                                   const int* __restrict__ perm, float* __restrict__ C,
                                                   int M, int K) {
  __shared__ __align__(16) u16 a_lds[128 * 32];
  __shared__ __align__(16) u16 b_lds[128 * 32];
  __shared__ int pr[128], pc[128];
  int t = threadIdx.x;
  int br = blockIdx.x, bc = blockIdx.y;
  if (t < 128) pr[t] = perm[br * 128 + t];
  else pc[t - 128] = perm[bc * 128 + (t - 128)];
  __syncthreads();
  int wave = t >> 6, lane = t & 63;
  int wr = wave >> 1, wc = wave & 1;
  int lrow = lane & 15, kb = lane >> 4;
  const f32x4 z4 = {0.f, 0.f, 0.f, 0.f};
  f32x4 acc[4][4];
  #pragma unroll
  for (int a = 0; a < 4; ++a)
    #pragma unroll
    for (int b = 0; b < 4; ++b) acc[a][b] = z4;

  for (int k0 = 0; k0 < K; k0 += 32) {
    __syncthreads();
    #pragma unroll
    for (int it = 0; it < 2; ++it) {
      int q = it * 256 + t;
      int r = q >> 2, c8 = (q & 3) << 3;
      s16x8 va = *(const s16x8*)(A1 + (size_t)pr[r] * K + k0 + c8);
      *(s16x8*)&a_lds[q * 8] = va;
      s16x8 vb = *(const s16x8*)(A1T + (size_t)pc[r] * K + k0 + c8);
      *(s16x8*)&b_lds[q * 8] = vb;
    }
    __syncthreads();
    s16x8 af[4], bfv[4];
    #pragma unroll
    for (int mi = 0; mi < 4; ++mi)
      af[mi] = *(const s16x8*)&a_lds[(wr * 64 + mi * 16 + lrow) * 32 + kb * 8];
    #pragma unroll
    for (int ni = 0; ni < 4; ++ni)
      bfv[ni] = *(const s16x8*)&b_lds[(wc * 64 + ni * 16 + lrow) * 32 + kb * 8];
    #pragma unroll
    for (int mi = 0; mi < 4; ++mi)
      #pragma unroll
      for (int ni = 0; ni < 4; ++ni)
        acc[mi][ni] = __builtin_amdgcn_mfma_f32_16x16x32_bf16(af[mi], bfv[ni], acc[mi][ni], 0, 0, 0);
  }
  int rbase = (lane >> 4) * 4;
  #pragma unroll
  for (int mi = 0; mi < 4; ++mi)
    #pragma unroll
    for (int ni = 0; ni < 4; ++ni)
      #pragma unroll
      for (int j = 0; j < 4; ++j) {
        int gi = br * 128 + wr * 64 + mi * 16 + rbase + j;
        int gj = bc * 128 + wc * 64 + ni * 16 + (lane & 15);
        C[(size_t)gi * M + gj] = (gi == gj) ? 0.0f : acc[mi][ni][j];
      }
}

// ---------------- driver ----------------
static void run_gcn(hipStream_t s, const float* A, int n, const float* xinp,
                    const float* W, const float* b, float* dinv, float* tmpY, float* tmpZ,
                    int act, float* outf, void* outfinal, const int* flags) {
  k_dinv<<<n, 256, 0, s>>>(A, dinv, n);
  k_xw<<<n / 16, 256, 0, s>>>(xinp, W, dinv, tmpY, n);
  k_zgemm<<<n / 16, 256, 0, s>>>(A, tmpY, tmpZ, n);
  int tot = n * 128;
  if (outf)
    k_epi<<<(tot + 255) / 256, 256, 0, s>>>(tmpZ, tmpY, dinv, b, outf, tot, act);
  else
    k_epi_out<<<(tot + 255) / 256, 256, 0, s>>>(tmpZ, tmpY, dinv, b, outfinal, tot, flags);
}

extern "C" void kernel_launch(void* const* d_in, const int* in_sizes, int n_in,
                              void* d_out, int out_size, void* d_ws, size_t ws_size,
                              hipStream_t stream) {
  (void)in_sizes; (void)n_in; (void)out_size; (void)ws_size;
  const void* x_in  = d_in[0];
  const int*  ei    = (const int*)d_in[1];
  const void* Wd_in = d_in[2];
  const void* bd_in = d_in[3];
  const void* Wu_in = d_in[4];
  const void* bu_in = d_in[5];
  const void* pw_in = d_in[6];

  char* p = (char*)d_ws;
  auto alloc = [&](size_t bytes) { char* r = p; p += (bytes + 255) & ~(size_t)255; return r; };
  float* A0   = (float*)alloc(4096ull * 4096 * 4);
  float* A1p  = (float*)alloc(2048ull * 2048 * 4);
  float* A2p  = (float*)alloc(1024ull * 1024 * 4);
  float* A3p  = (float*)alloc(512ull * 512 * 4);
  u16*   A1b  = (u16*)alloc(4096ull * 4096 * 2);
  u16*   A1bT = (u16*)alloc(4096ull * 4096 * 2);
  float* xb0  = (float*)alloc(4096 * 128 * 4);
  float* xb1  = (float*)alloc(2048 * 128 * 4);
  float* xb2  = (float*)alloc(1024 * 128 * 4);
  float* xb3  = (float*)alloc(512 * 128 * 4);
  float* xin  = (float*)alloc(4096 * 128 * 4);
  float* tmpX = (float*)alloc(4096 * 128 * 4);
  float* tmpY = (float*)alloc(4096 * 128 * 4);
  float* tmpZ = (float*)alloc(4096 * 128 * 4);
  float* dinv = (float*)alloc(4096 * 4);
  float* tsc  = (float*)alloc(4096 * 4);
  int*   perm1 = (int*)alloc(2048 * 4);
  int*   perm2 = (int*)alloc(1024 * 4);
  int*   perm3 = (int*)alloc(512 * 4);
  float* Wdf  = (float*)alloc(4 * 128 * 128 * 4);
  float* bdf  = (float*)alloc(4 * 128 * 4);
  float* Wuf  = (float*)alloc(3 * 128 * 128 * 4);
  float* buf_ = (float*)alloc(3 * 128 * 4);
  float* pwf  = (float*)alloc(3 * 128 * 4);
  int*   flags = (int*)alloc(4 * 4);

  // dtype detection
  k_zeroflags<<<1, 64, 0, stream>>>(flags);
  k_detect<<<16, 256, 0, stream>>>((const u16*)x_in, ei, flags);

  auto cvt = [&](const void* src, float* dst, int n) {
    k_loadf<<<(n + 255) / 256, 256, 0, stream>>>(src, dst, n, flags);
  };
  cvt(x_in, xin, 4096 * 128);
  cvt(Wd_in, Wdf, 4 * 128 * 128);
  cvt(bd_in, bdf, 4 * 128);
  cvt(Wu_in, Wuf, 3 * 128 * 128);
  cvt(bu_in, buf_, 3 * 128);
  cvt(pw_in, pwf, 3 * 128);

  // adjacency
  k_fill0<<<4096, 256, 0, stream>>>((float4*)A0, 4096L * 4096 / 4);
  k_edges<<<(65536 + 255) / 256, 256, 0, stream>>>(ei, A0, 65536, 4096, flags);

  // level-0 GCN
  run_gcn(stream, A0, 4096, xin, Wdf, bdf, dinv, tmpY, tmpZ, 1, xb0, nullptr, flags);

  // down path
  float* Anexts[3] = {A1p, A2p, A3p};
  int*   perms[3]  = {perm1, perm2, perm3};
  float* xouts[3]  = {xb1, xb2, xb3};
  float* Acur = A0;
  float* xcur = xb0;
  int n = 4096;
  for (int lvl = 1; lvl <= 3; ++lvl) {
    int k = n / 2;
    k_score<<<n / 4, 256, 0, stream>>>(xcur, pwf + (lvl - 1) * 128, tsc, n);
    k_topk<<<1, 1024, 0, stream>>>(tsc, n, perms[lvl - 1], k);
    k_prep<<<dim3(n / 32, n / 32), 256, 0, stream>>>(Acur, A1b, A1bT, n);
    k_mfma_pool<<<dim3(k / 128, k / 128), 256, 0, stream>>>(A1b, A1bT, perms[lvl - 1], Anexts[lvl - 1], k, n);
    k_gather<<<(k * 128 + 255) / 256, 256, 0, stream>>>(xcur, perms[lvl - 1], tsc, tmpX, k);
    run_gcn(stream, Anexts[lvl - 1], k, tmpX, Wdf + lvl * 16384, bdf + lvl * 128,
            dinv, tmpY, tmpZ, 1, xouts[lvl - 1], nullptr, flags);
    Acur = Anexts[lvl - 1];
    xcur = xouts[lvl - 1];
    n = k;
  }

  // up path
  float* prev = xb3;
  float* Ajs[3]  = {A2p, A1p, A0};
  int*   pjs[3]  = {perm3, perm2, perm1};
  float* resb[3] = {xb2, xb1, xb0};
  int    njs[3]  = {1024, 2048, 4096};
  for (int i = 0; i < 3; ++i) {
    int nj = njs[i], kk = nj / 2;
    k_copy<<<(nj * 128 + 255) / 256, 256, 0, stream>>>(resb[i], tmpX, nj * 128);
    k_scatadd<<<(kk * 128 + 255) / 256, 256, 0, stream>>>(tmpX, prev, pjs[i], kk);
    if (i < 2) {
      run_gcn(stream, Ajs[i], nj, tmpX, Wuf + i * 16384, buf_ + i * 128,
              dinv, tmpY, tmpZ, 1, resb[i], nullptr, flags);
      prev = resb[i];
    } else {
      run_gcn(stream, Ajs[i], nj, tmpX, Wuf + i * 16384, buf_ + i * 128,
              dinv, tmpY, tmpZ, 0, nullptr, d_out, flags);
    }
  }
}

// Round 3
// 673.153 us; speedup vs baseline: 2.4616x; 2.4616x over previous
//
#include <hip/hip_runtime.h>

typedef unsigned short u16;
typedef __attribute__((ext_vector_type(4))) short s16x4;
typedef __attribute__((ext_vector_type(8))) short s16x8;
typedef __attribute__((ext_vector_type(4))) float f32x4;

__device__ __forceinline__ float bf2f_(u16 b) { return __uint_as_float(((unsigned)b) << 16); }
__device__ __forceinline__ u16 f2bf_(float f) {
  unsigned u = __float_as_uint(f);
  return (u16)((u + 0x7FFFu + ((u >> 16) & 1u)) >> 16);
}

// ---------------- dtype detection (deterministic, device-side) ----------------
__global__ void k_zeroflags(int* f) { if (threadIdx.x < 4) f[threadIdx.x] = 0; }

__global__ __launch_bounds__(256) void k_detect(const u16* __restrict__ xb,
                                                const int* __restrict__ ei,
                                                int* __restrict__ flags) {
  int i = blockIdx.x * 256 + threadIdx.x;  // 4096 threads
  int e8 = (xb[2 * i] >> 7) & 0xFF;
  int sane = (e8 >= 100 && e8 <= 140) ? 1 : 0;
  int nz = (ei[2 * i + 1] != 0) ? 1 : 0;
  #pragma unroll
  for (int off = 32; off; off >>= 1) { sane += __shfl_down(sane, off); nz += __shfl_down(nz, off); }
  if ((threadIdx.x & 63) == 0) { atomicAdd(&flags[0], sane); atomicAdd(&flags[1], nz); }
}

__global__ void k_loadf(const void* __restrict__ src, float* __restrict__ dst, int n,
                        const int* __restrict__ flags) {
  int i = blockIdx.x * 256 + threadIdx.x;
  if (i >= n) return;
  bool isbf = flags[0] >= 2048;
  dst[i] = isbf ? bf2f_(((const u16*)src)[i]) : ((const float*)src)[i];
}

// ---------------- setup ----------------
__global__ void k_fill0(float4* __restrict__ p, long n4) {
  long i = blockIdx.x * 256L + threadIdx.x;
  long stride = (long)gridDim.x * 256L;
  for (; i < n4; i += stride) p[i] = make_float4(0.f, 0.f, 0.f, 0.f);
}

__global__ void k_edges(const int* __restrict__ ei, float* __restrict__ A, int E, int n,
                        const int* __restrict__ flags) {
  int e = blockIdx.x * 256 + threadIdx.x;
  if (e >= E) return;
  bool is64 = flags[1] < 100;
  int src = is64 ? ei[2 * e] : ei[e];
  int dst = is64 ? ei[2 * E + 2 * e] : ei[E + e];
  if (src >= 0 && src < n && dst >= 0 && dst < n)
    atomicAdd(&A[(size_t)dst * n + src], 1.0f);
}

__global__ void k_copy(const float* __restrict__ src, float* __restrict__ dst, int n) {
  int i = blockIdx.x * 256 + threadIdx.x;
  if (i < n) dst[i] = src[i];
}

// ---------------- GCN pieces ----------------
__global__ __launch_bounds__(256) void k_dinv(const float* __restrict__ A, float* __restrict__ dinv, int n) {
  int row = blockIdx.x;
  const float* r = A + (size_t)row * n;
  float s = 0.f;
  for (int j = threadIdx.x; j < n; j += 256) s += r[j];
  #pragma unroll
  for (int off = 32; off; off >>= 1) s += __shfl_down(s, off);
  __shared__ float red[4];
  int wave = threadIdx.x >> 6, lane = threadIdx.x & 63;
  if (lane == 0) red[wave] = s;
  __syncthreads();
  if (threadIdx.x == 0) {
    float deg = red[0] + red[1] + red[2] + red[3] + 2.0f;
    dinv[row] = rsqrtf(deg);
  }
}

// yp[r][c] = dinv[r] * sum_k x[r][k] * W[k][c]    (16 rows per block)
__global__ __launch_bounds__(256) void k_xw(const float* __restrict__ x, const float* __restrict__ W,
                                            const float* __restrict__ dinv, float* __restrict__ yp, int n) {
  __shared__ float xs_[16 * 128];
  int t = threadIdx.x;
  int row0 = blockIdx.x * 16;
  for (int e = t; e < 16 * 128; e += 256) {
    int r = e >> 7, c = e & 127;
    xs_[e] = x[(size_t)(row0 + r) * 128 + c];
  }
  __syncthreads();
  int c = t & 127, rh = t >> 7;
  float acc[8];
  #pragma unroll
  for (int ri = 0; ri < 8; ++ri) acc[ri] = 0.f;
  for (int k = 0; k < 128; ++k) {
    float wv = W[k * 128 + c];
    #pragma unroll
    for (int ri = 0; ri < 8; ++ri) acc[ri] += xs_[(rh * 8 + ri) * 128 + k] * wv;
  }
  #pragma unroll
  for (int ri = 0; ri < 8; ++ri) {
    int r = row0 + rh * 8 + ri;
    yp[(size_t)r * 128 + c] = dinv[r] * acc[ri];
  }
}

// transpose + hi/lo split: y [n x 128] fp32 -> yTh, yTl [128 x n] bf16
__global__ __launch_bounds__(256) void k_ytr(const float* __restrict__ y,
                                             u16* __restrict__ yTh, u16* __restrict__ yTl, int n) {
  __shared__ float tile[32][129];
  int t = threadIdx.x;
  int r0 = blockIdx.x * 32;
  #pragma unroll
  for (int it = 0; it < 4; ++it) {
    int q = it * 256 + t;           // 1024 float4 chunks: 32 rows x 32 chunks
    int r = q >> 5, c4 = (q & 31) * 4;
    float4 v = *(const float4*)&y[(size_t)(r0 + r) * 128 + c4];
    tile[r][c4] = v.x; tile[r][c4 + 1] = v.y; tile[r][c4 + 2] = v.z; tile[r][c4 + 3] = v.w;
  }
  __syncthreads();
  #pragma unroll
  for (int it = 0; it < 2; ++it) {
    int q = it * 256 + t;           // 512 chunks: 128 cols x 4 runs of 8
    int c = q >> 2, r8 = (q & 3) * 8;
    s16x8 h, l;
    #pragma unroll
    for (int j = 0; j < 8; ++j) {
      float v = tile[r8 + j][c];
      u16 hb = f2bf_(v);
      h[j] = (short)hb;
      l[j] = (short)f2bf_(v - bf2f_(hb));
    }
    *(s16x8*)&yTh[(size_t)c * n + r0 + r8] = h;
    *(s16x8*)&yTl[(size_t)c * n + r0 + r8] = l;
  }
}

// z-partials: zpart[s][i][c] = sum_{k in chunk s} A[i][k] * y[k][c]
// A fp32 -> bf16 hi(/lo) staged in-kernel; y pre-split yTh/yTl. 128x128 tile, 4 waves.
template<int ALO>
__global__ __launch_bounds__(256) void k_zgemm_mfma(const float* __restrict__ A,
                                                    const u16* __restrict__ yTh,
                                                    const u16* __restrict__ yTl,
                                                    float* __restrict__ zpart,
                                                    int n, int kchunk) {
  __shared__ __align__(16) u16 ah_[128 * 32];
  __shared__ __align__(16) u16 al_[128 * 32];
  __shared__ __align__(16) u16 bh_[128 * 32];
  __shared__ __align__(16) u16 bl_[128 * 32];
  int t = threadIdx.x;
  int row0 = blockIdx.x * 128;
  int s = blockIdx.y;
  int kbase = s * kchunk;
  int wave = t >> 6, lane = t & 63;
  int wr = wave >> 1, wc = wave & 1;
  int lrow = lane & 15, kb = lane >> 4;
  const f32x4 z4 = {0.f, 0.f, 0.f, 0.f};
  f32x4 acc[4][4];
  #pragma unroll
  for (int a = 0; a < 4; ++a)
    #pragma unroll
    for (int b = 0; b < 4; ++b) acc[a][b] = z4;

  for (int k0 = 0; k0 < kchunk; k0 += 32) {
    int koff = kbase + k0;
    __syncthreads();
    // stage A tile 128x32 fp32 -> bf16 hi/lo
    #pragma unroll
    for (int it = 0; it < 4; ++it) {
      int q = it * 256 + t;            // 1024 float4: 128 rows x 8 chunks
      int r = q >> 3, c4 = (q & 7) * 4;
      float4 v = *(const float4*)&A[(size_t)(row0 + r) * n + koff + c4];
      s16x4 h, l;
      float vv[4] = {v.x, v.y, v.z, v.w};
      #pragma unroll
      for (int j = 0; j < 4; ++j) {
        u16 hb = f2bf_(vv[j]);
        h[j] = (short)hb;
        if (ALO) l[j] = (short)f2bf_(vv[j] - bf2f_(hb));
      }
      *(s16x4*)&ah_[r * 32 + c4] = h;
      if (ALO) *(s16x4*)&al_[r * 32 + c4] = l;
    }
    // stage B tiles 128x32 bf16 (yTh, yTl rows are k-contiguous)
    #pragma unroll
    for (int it = 0; it < 2; ++it) {
      int q = it * 256 + t;            // 512 s16x8: 128 rows x 4 chunks
      int r = q >> 2, c8 = (q & 3) * 8;
      *(s16x8*)&bh_[r * 32 + c8] = *(const s16x8*)&yTh[(size_t)r * n + koff + c8];
      *(s16x8*)&bl_[r * 32 + c8] = *(const s16x8*)&yTl[(size_t)r * n + koff + c8];
    }
    __syncthreads();
    s16x8 af[4], alf[4], bhf[4], blf[4];
    #pragma unroll
    for (int mi = 0; mi < 4; ++mi) {
      af[mi] = *(const s16x8*)&ah_[(wr * 64 + mi * 16 + lrow) * 32 + kb * 8];
      if (ALO) alf[mi] = *(const s16x8*)&al_[(wr * 64 + mi * 16 + lrow) * 32 + kb * 8];
    }
    #pragma unroll
    for (int ni = 0; ni < 4; ++ni) {
      bhf[ni] = *(const s16x8*)&bh_[(wc * 64 + ni * 16 + lrow) * 32 + kb * 8];
      blf[ni] = *(const s16x8*)&bl_[(wc * 64 + ni * 16 + lrow) * 32 + kb * 8];
    }
    #pragma unroll
    for (int mi = 0; mi < 4; ++mi)
      #pragma unroll
      for (int ni = 0; ni < 4; ++ni) {
        acc[mi][ni] = __builtin_amdgcn_mfma_f32_16x16x32_bf16(af[mi], bhf[ni], acc[mi][ni], 0, 0, 0);
        acc[mi][ni] = __builtin_amdgcn_mfma_f32_16x16x32_bf16(af[mi], blf[ni], acc[mi][ni], 0, 0, 0);
        if (ALO) {
          acc[mi][ni] = __builtin_amdgcn_mfma_f32_16x16x32_bf16(alf[mi], bhf[ni], acc[mi][ni], 0, 0, 0);
          acc[mi][ni] = __builtin_amdgcn_mfma_f32_16x16x32_bf16(alf[mi], blf[ni], acc[mi][ni], 0, 0, 0);
        }
      }
  }
  int rbase = (lane >> 4) * 4;
  #pragma unroll
  for (int mi = 0; mi < 4; ++mi)
    #pragma unroll
    for (int ni = 0; ni < 4; ++ni)
      #pragma unroll
      for (int j = 0; j < 4; ++j) {
        int gi = row0 + wr * 64 + mi * 16 + rbase + j;
        int gj = wc * 64 + ni * 16 + (lane & 15);
        zpart[((size_t)s * n + gi) * 128 + gj] = acc[mi][ni][j];
      }
}

// epilogue: v = dinv[r]*(sum_s zpart + 2*yp) + b[c]; optional leakyrelu; fp32 out
__global__ void k_epi(const float* __restrict__ zpart, const float* __restrict__ yp,
                      const float* __restrict__ dinv, const float* __restrict__ b,
                      float* __restrict__ outf, int tot, int act, int n) {
  int i = blockIdx.x * 256 + threadIdx.x;
  if (i >= tot) return;
  int r = i >> 7, c = i & 127;
  float z = 0.f;
  #pragma unroll
  for (int s = 0; s < 8; ++s) z += zpart[((size_t)s * n + r) * 128 + c];
  float v = dinv[r] * (z + 2.0f * yp[i]) + b[c];
  if (act) v = (v >= 0.f) ? v : 0.01f * v;
  outf[i] = v;
}

// final epilogue: no activation; bf16 or fp32 per flag
__global__ void k_epi_out(const float* __restrict__ zpart, const float* __restrict__ yp,
                          const float* __restrict__ dinv, const float* __restrict__ b,
                          void* __restrict__ out, int tot, int n, const int* __restrict__ flags) {
  int i = blockIdx.x * 256 + threadIdx.x;
  if (i >= tot) return;
  int r = i >> 7, c = i & 127;
  float z = 0.f;
  #pragma unroll
  for (int s = 0; s < 8; ++s) z += zpart[((size_t)s * n + r) * 128 + c];
  float v = dinv[r] * (z + 2.0f * yp[i]) + b[c];
  if (flags[0] >= 2048) ((u16*)out)[i] = f2bf_(v);
  else ((float*)out)[i] = v;
}

// ---------------- top-k pooling ----------------
__global__ __launch_bounds__(256) void k_score(const float* __restrict__ x, const float* __restrict__ w,
                                               float* __restrict__ ts, int n) {
  int wave = threadIdx.x >> 6, lane = threadIdx.x & 63;
  int row = blockIdx.x * 4 + wave;
  float w0 = w[lane], w1 = w[64 + lane];
  float nrm = w0 * w0 + w1 * w1;
  #pragma unroll
  for (int off = 32; off; off >>= 1) nrm += __shfl_down(nrm, off);
  nrm = sqrtf(__shfl(nrm, 0));
  if (row < n) {
    const float* xr = x + (size_t)row * 128;
    float d = xr[lane] * w0 + xr[64 + lane] * w1;
    #pragma unroll
    for (int off = 32; off; off >>= 1) d += __shfl_down(d, off);
    if (lane == 0) ts[row] = tanhf(d / nrm);
  }
}

__global__ __launch_bounds__(1024) void k_topk(const float* __restrict__ ts, int n,
                                               int* __restrict__ perm, int k) {
  __shared__ unsigned long long keys[4096];
  int t = threadIdx.x;
  for (int i = t; i < n; i += 1024) {
    unsigned bits = __float_as_uint(ts[i]);
    unsigned u = (bits & 0x80000000u) ? ~bits : (bits | 0x80000000u);
    keys[i] = ((unsigned long long)u << 32) | (unsigned)(0xFFFFFFFFu - (unsigned)i);
  }
  __syncthreads();
  for (int size = 2; size <= n; size <<= 1) {
    for (int stride = size >> 1; stride > 0; stride >>= 1) {
      for (int i = t; i < n; i += 1024) {
        int l = i ^ stride;
        if (l > i) {
          bool descSeg = ((i & size) == 0);
          unsigned long long ki = keys[i], kl = keys[l];
          bool sw = descSeg ? (ki < kl) : (ki > kl);
          if (sw) { keys[i] = kl; keys[l] = ki; }
        }
      }
      __syncthreads();
    }
  }
  for (int i = t; i < k; i += 1024)
    perm[i] = (int)(0xFFFFFFFFu - (unsigned)(keys[i] & 0xFFFFFFFFu));
}

__global__ void k_gather(const float* __restrict__ x, const int* __restrict__ perm,
                         const float* __restrict__ ts, float* __restrict__ out, int k) {
  int i = blockIdx.x * 256 + threadIdx.x;
  if (i < k * 128) {
    int r = i >> 7, c = i & 127;
    int p = perm[r];
    out[i] = x[(size_t)p * 128 + c] * ts[p];
  }
}

__global__ void k_scatadd(float* __restrict__ dst, const float* __restrict__ src,
                          const int* __restrict__ perm, int k) {
  int i = blockIdx.x * 256 + threadIdx.x;
  if (i < k * 128) {
    int r = i >> 7, c = i & 127;
    dst[(size_t)perm[r] * 128 + c] += src[i];
  }
}

// ---------------- augment: bf16 A1 (offdiag A, diag 1) + transpose ----------------
__global__ __launch_bounds__(256) void k_prep(const float* __restrict__ A, u16* __restrict__ A1,
                                              u16* __restrict__ A1T, int n) {
  __shared__ float tile[32][33];
  int bi = blockIdx.y, bj = blockIdx.x;
  int tx = threadIdx.x & 31, ty = threadIdx.x >> 5;
  int r0 = bi * 32, c0 = bj * 32;
  #pragma unroll
  for (int yy = 0; yy < 4; ++yy) {
    int r = ty * 4 + yy;
    int gr = r0 + r, gc = c0 + tx;
    float v = A[(size_t)gr * n + gc];
    if (gr == gc) v = 1.0f;
    tile[r][tx] = v;
    A1[(size_t)gr * n + gc] = f2bf_(v);
  }
  __syncthreads();
  #pragma unroll
  for (int yy = 0; yy < 4; ++yy) {
    int r = ty * 4 + yy;
    int gr = c0 + r, gc = r0 + tx;
    A1T[(size_t)gr * n + gc] = f2bf_(tile[tx][r]);
  }
}

// C[i][j] = (A1@A1)[perm_i][perm_j], diag -> 0; 128x128 tile, 4 waves
__global__ __launch_bounds__(256) void k_mfma_pool(const u16* __restrict__ A1, const u16* __restrict__ A1T,
                                                   const int* __restrict__ perm, float* __restrict__ C,
                                                   int M, int K) {
  __shared__ __align__(16) u16 a_lds[128 * 32];
  __shared__ __align__(16) u16 b_lds[128 * 32];
  __shared__ int pr[128], pc[128];
  int t = threadIdx.x;
  int br = blockIdx.x, bc = blockIdx.y;
  if (t < 128) pr[t] = perm[br * 128 + t];
  else pc[t - 128] = perm[bc * 128 + (t - 128)];
  __syncthreads();
  int wave = t >> 6, lane = t & 63;
  int wr = wave >> 1, wc = wave & 1;
  int lrow = lane & 15, kb = lane >> 4;
  const f32x4 z4 = {0.f, 0.f, 0.f, 0.f};
  f32x4 acc[4][4];
  #pragma unroll
  for (int a = 0; a < 4; ++a)
    #pragma unroll
    for (int b = 0; b < 4; ++b) acc[a][b] = z4;

  for (int k0 = 0; k0 < K; k0 += 32) {
    __syncthreads();
    #pragma unroll
    for (int it = 0; it < 2; ++it) {
      int q = it * 256 + t;
      int r = q >> 2, c8 = (q & 3) << 3;
      s16x8 va = *(const s16x8*)(A1 + (size_t)pr[r] * K + k0 + c8);
      *(s16x8*)&a_lds[q * 8] = va;
      s16x8 vb = *(const s16x8*)(A1T + (size_t)pc[r] * K + k0 + c8);
      *(s16x8*)&b_lds[q * 8] = vb;
    }
    __syncthreads();
    s16x8 af[4], bfv[4];
    #pragma unroll
    for (int mi = 0; mi < 4; ++mi)
      af[mi] = *(const s16x8*)&a_lds[(wr * 64 + mi * 16 + lrow) * 32 + kb * 8];
    #pragma unroll
    for (int ni = 0; ni < 4; ++ni)
      bfv[ni] = *(const s16x8*)&b_lds[(wc * 64 + ni * 16 + lrow) * 32 + kb * 8];
    #pragma unroll
    for (int mi = 0; mi < 4; ++mi)
      #pragma unroll
      for (int ni = 0; ni < 4; ++ni)
        acc[mi][ni] = __builtin_amdgcn_mfma_f32_16x16x32_bf16(af[mi], bfv[ni], acc[mi][ni], 0, 0, 0);
  }
  int rbase = (lane >> 4) * 4;
  #pragma unroll
  for (int mi = 0; mi < 4; ++mi)
    #pragma unroll
    for (int ni = 0; ni < 4; ++ni)
      #pragma unroll
      for (int j = 0; j < 4; ++j) {
        int gi = br * 128 + wr * 64 + mi * 16 + rbase + j;
        int gj = bc * 128 + wc * 64 + ni * 16 + (lane & 15);
        C[(size_t)gi * M + gj] = (gi == gj) ? 0.0f : acc[mi][ni][j];
      }
}

// ---------------- driver ----------------
static void run_gcn(hipStream_t s, const float* A, int n, const float* xinp,
                    const float* W, const float* b, float* dinv, float* tmpY,
                    u16* yTh, u16* yTl, float* zpart, int alo,
                    int act, float* outf, void* outfinal, const int* flags) {
  k_dinv<<<n, 256, 0, s>>>(A, dinv, n);
  k_xw<<<n / 16, 256, 0, s>>>(xinp, W, dinv, tmpY, n);
  k_ytr<<<n / 32, 256, 0, s>>>(tmpY, yTh, yTl, n);
  int kchunk = n / 8;
  if (alo)
    k_zgemm_mfma<1><<<dim3(n / 128, 8), 256, 0, s>>>(A, yTh, yTl, zpart, n, kchunk);
  else
    k_zgemm_mfma<0><<<dim3(n / 128, 8), 256, 0, s>>>(A, yTh, yTl, zpart, n, kchunk);
  int tot = n * 128;
  if (outf)
    k_epi<<<(tot + 255) / 256, 256, 0, s>>>(zpart, tmpY, dinv, b, outf, tot, act, n);
  else
    k_epi_out<<<(tot + 255) / 256, 256, 0, s>>>(zpart, tmpY, dinv, b, outfinal, tot, n, flags);
}

extern "C" void kernel_launch(void* const* d_in, const int* in_sizes, int n_in,
                              void* d_out, int out_size, void* d_ws, size_t ws_size,
                              hipStream_t stream) {
  (void)in_sizes; (void)n_in; (void)out_size; (void)ws_size;
  const void* x_in  = d_in[0];
  const int*  ei    = (const int*)d_in[1];
  const void* Wd_in = d_in[2];
  const void* bd_in = d_in[3];
  const void* Wu_in = d_in[4];
  const void* bu_in = d_in[5];
  const void* pw_in = d_in[6];

  char* p = (char*)d_ws;
  auto alloc = [&](size_t bytes) { char* r = p; p += (bytes + 255) & ~(size_t)255; return r; };
  float* A0   = (float*)alloc(4096ull * 4096 * 4);
  float* A1p  = (float*)alloc(2048ull * 2048 * 4);
  float* A2p  = (float*)alloc(1024ull * 1024 * 4);
  float* A3p  = (float*)alloc(512ull * 512 * 4);
  u16*   A1b  = (u16*)alloc(4096ull * 4096 * 2);   // pooling scratch; zpart/yT alias here during GCNs
  u16*   A1bT = (u16*)alloc(4096ull * 4096 * 2);
  float* xb0  = (float*)alloc(4096 * 128 * 4);
  float* xb1  = (float*)alloc(2048 * 128 * 4);
  float* xb2  = (float*)alloc(1024 * 128 * 4);
  float* xb3  = (float*)alloc(512 * 128 * 4);
  float* xin  = (float*)alloc(4096 * 128 * 4);
  float* tmpX = (float*)alloc(4096 * 128 * 4);
  float* tmpY = (float*)alloc(4096 * 128 * 4);
  float* dinv = (float*)alloc(4096 * 4);
  float* tsc  = (float*)alloc(4096 * 4);
  int*   perm1 = (int*)alloc(2048 * 4);
  int*   perm2 = (int*)alloc(1024 * 4);
  int*   perm3 = (int*)alloc(512 * 4);
  float* Wdf  = (float*)alloc(4 * 128 * 128 * 4);
  float* bdf  = (float*)alloc(4 * 128 * 4);
  float* Wuf  = (float*)alloc(3 * 128 * 128 * 4);
  float* buf_ = (float*)alloc(3 * 128 * 4);
  float* pwf  = (float*)alloc(3 * 128 * 4);
  int*   flags = (int*)alloc(4 * 4);

  // aliases into A1b (dead during GCN phases): zpart (16.78 MB) + yT hi/lo (1 MB each)
  float* zpart = (float*)A1b;                                    // 8 * 4096 * 128 * 4 B
  u16*   yTh   = (u16*)((char*)A1b + 20ull * 1024 * 1024);
  u16*   yTl   = (u16*)((char*)A1b + 23ull * 1024 * 1024);

  // dtype detection
  k_zeroflags<<<1, 64, 0, stream>>>(flags);
  k_detect<<<16, 256, 0, stream>>>((const u16*)x_in, ei, flags);

  auto cvt = [&](const void* src, float* dst, int n) {
    k_loadf<<<(n + 255) / 256, 256, 0, stream>>>(src, dst, n, flags);
  };
  cvt(x_in, xin, 4096 * 128);
  cvt(Wd_in, Wdf, 4 * 128 * 128);
  cvt(bd_in, bdf, 4 * 128);
  cvt(Wu_in, Wuf, 3 * 128 * 128);
  cvt(bu_in, buf_, 3 * 128);
  cvt(pw_in, pwf, 3 * 128);

  // adjacency
  k_fill0<<<4096, 256, 0, stream>>>((float4*)A0, 4096L * 4096 / 4);
  k_edges<<<(65536 + 255) / 256, 256, 0, stream>>>(ei, A0, 65536, 4096, flags);

  // level-0 GCN
  run_gcn(stream, A0, 4096, xin, Wdf, bdf, dinv, tmpY, yTh, yTl, zpart, 0, 1, xb0, nullptr, flags);

  // down path
  float* Anexts[3] = {A1p, A2p, A3p};
  int*   perms[3]  = {perm1, perm2, perm3};
  float* xouts[3]  = {xb1, xb2, xb3};
  int    alos[3]   = {0, 1, 1};     // A1p entries tiny (exact bf16); A2p/A3p may exceed 256
  float* Acur = A0;
  float* xcur = xb0;
  int n = 4096;
  for (int lvl = 1; lvl <= 3; ++lvl) {
    int k = n / 2;
    k_score<<<n / 4, 256, 0, stream>>>(xcur, pwf + (lvl - 1) * 128, tsc, n);
    k_topk<<<1, 1024, 0, stream>>>(tsc, n, perms[lvl - 1], k);
    k_prep<<<dim3(n / 32, n / 32), 256, 0, stream>>>(Acur, A1b, A1bT, n);
    k_mfma_pool<<<dim3(k / 128, k / 128), 256, 0, stream>>>(A1b, A1bT, perms[lvl - 1], Anexts[lvl - 1], k, n);
    k_gather<<<(k * 128 + 255) / 256, 256, 0, stream>>>(xcur, perms[lvl - 1], tsc, tmpX, k);
    run_gcn(stream, Anexts[lvl - 1], k, tmpX, Wdf + lvl * 16384, bdf + lvl * 128,
            dinv, tmpY, yTh, yTl, zpart, alos[lvl - 1], 1, xouts[lvl - 1], nullptr, flags);
    Acur = Anexts[lvl - 1];
    xcur = xouts[lvl - 1];
    n = k;
  }

  // up path
  float* prev = xb3;
  float* Ajs[3]  = {A2p, A1p, A0};
  int*   pjs[3]  = {perm3, perm2, perm1};
  float* resb[3] = {xb2, xb1, xb0};
  int    njs[3]  = {1024, 2048, 4096};
  int    alou[3] = {1, 0, 0};
  for (int i = 0; i < 3; ++i) {
    int nj = njs[i], kk = nj / 2;
    k_copy<<<(nj * 128 + 255) / 256, 256, 0, stream>>>(resb[i], tmpX, nj * 128);
    k_scatadd<<<(kk * 128 + 255) / 256, 256, 0, stream>>>(tmpX, prev, pjs[i], kk);
    if (i < 2) {
      run_gcn(stream, Ajs[i], nj, tmpX, Wuf + i * 16384, buf_ + i * 128,
              dinv, tmpY, yTh, yTl, zpart, alou[i], 1, resb[i], nullptr, flags);
      prev = resb[i];
    } else {
      run_gcn(stream, Ajs[i], nj, tmpX, Wuf + i * 16384, buf_ + i * 128,
              dinv, tmpY, yTh, yTl, zpart, alou[i], 0, nullptr, d_out, flags);
    }
  }
}

// Round 4
// 614.506 us; speedup vs baseline: 2.6966x; 1.0954x over previous
//
#include <hip/hip_runtime.h>

typedef unsigned short u16;
typedef __attribute__((ext_vector_type(4))) short s16x4;
typedef __attribute__((ext_vector_type(8))) short s16x8;
typedef __attribute__((ext_vector_type(4))) float f32x4;

__device__ __forceinline__ float bf2f_(u16 b) { return __uint_as_float(((unsigned)b) << 16); }
__device__ __forceinline__ u16 f2bf_(float f) {
  unsigned u = __float_as_uint(f);
  return (u16)((u + 0x7FFFu + ((u >> 16) & 1u)) >> 16);
}

// ---------------- dtype detection (deterministic, device-side) ----------------
__global__ void k_zeroflags(int* f) { if (threadIdx.x < 4) f[threadIdx.x] = 0; }

__global__ __launch_bounds__(256) void k_detect(const u16* __restrict__ xb,
                                                const int* __restrict__ ei,
                                                int* __restrict__ flags) {
  int i = blockIdx.x * 256 + threadIdx.x;  // 4096 threads
  int e8 = (xb[2 * i] >> 7) & 0xFF;
  int sane = (e8 >= 100 && e8 <= 140) ? 1 : 0;
  int nz = (ei[2 * i + 1] != 0) ? 1 : 0;
  #pragma unroll
  for (int off = 32; off; off >>= 1) { sane += __shfl_down(sane, off); nz += __shfl_down(nz, off); }
  if ((threadIdx.x & 63) == 0) { atomicAdd(&flags[0], sane); atomicAdd(&flags[1], nz); }
}

__global__ void k_loadf(const void* __restrict__ src, float* __restrict__ dst, int n,
                        const int* __restrict__ flags) {
  int i = blockIdx.x * 256 + threadIdx.x;
  if (i >= n) return;
  bool isbf = flags[0] >= 2048;
  dst[i] = isbf ? bf2f_(((const u16*)src)[i]) : ((const float*)src)[i];
}

// ---------------- setup ----------------
__global__ void k_fill0(float4* __restrict__ p, long n4) {
  long i = blockIdx.x * 256L + threadIdx.x;
  long stride = (long)gridDim.x * 256L;
  for (; i < n4; i += stride) p[i] = make_float4(0.f, 0.f, 0.f, 0.f);
}

__global__ void k_edges(const int* __restrict__ ei, float* __restrict__ A, int E, int n,
                        const int* __restrict__ flags) {
  int e = blockIdx.x * 256 + threadIdx.x;
  if (e >= E) return;
  bool is64 = flags[1] < 100;
  int src = is64 ? ei[2 * e] : ei[e];
  int dst = is64 ? ei[2 * E + 2 * e] : ei[E + e];
  if (src >= 0 && src < n && dst >= 0 && dst < n)
    atomicAdd(&A[(size_t)dst * n + src], 1.0f);
}

__global__ void k_copy(const float* __restrict__ src, float* __restrict__ dst, int n) {
  int i = blockIdx.x * 256 + threadIdx.x;
  if (i < n) dst[i] = src[i];
}

__global__ void k_diag0(float* __restrict__ C, int M) {
  int i = blockIdx.x * 256 + threadIdx.x;
  if (i < M) C[(size_t)i * M + i] = 0.f;
}

// ---------------- GCN pieces ----------------
__global__ __launch_bounds__(256) void k_dinv(const float* __restrict__ A, float* __restrict__ dinv, int n) {
  int row = blockIdx.x;
  const float* r = A + (size_t)row * n;
  float s = 0.f;
  for (int j = threadIdx.x; j < n; j += 256) s += r[j];
  #pragma unroll
  for (int off = 32; off; off >>= 1) s += __shfl_down(s, off);
  __shared__ float red[4];
  int wave = threadIdx.x >> 6, lane = threadIdx.x & 63;
  if (lane == 0) red[wave] = s;
  __syncthreads();
  if (threadIdx.x == 0) {
    float deg = red[0] + red[1] + red[2] + red[3] + 2.0f;
    dinv[row] = rsqrtf(deg);
  }
}

// yp[r][c] = dinv[r] * sum_k x[r][k] * W[k][c]    (16 rows per block)
__global__ __launch_bounds__(256) void k_xw(const float* __restrict__ x, const float* __restrict__ W,
                                            const float* __restrict__ dinv, float* __restrict__ yp, int n) {
  __shared__ float xs_[16 * 128];
  int t = threadIdx.x;
  int row0 = blockIdx.x * 16;
  for (int e = t; e < 16 * 128; e += 256) {
    int r = e >> 7, c = e & 127;
    xs_[e] = x[(size_t)(row0 + r) * 128 + c];
  }
  __syncthreads();
  int c = t & 127, rh = t >> 7;
  float acc[8];
  #pragma unroll
  for (int ri = 0; ri < 8; ++ri) acc[ri] = 0.f;
  for (int k = 0; k < 128; ++k) {
    float wv = W[k * 128 + c];
    #pragma unroll
    for (int ri = 0; ri < 8; ++ri) acc[ri] += xs_[(rh * 8 + ri) * 128 + k] * wv;
  }
  #pragma unroll
  for (int ri = 0; ri < 8; ++ri) {
    int r = row0 + rh * 8 + ri;
    yp[(size_t)r * 128 + c] = dinv[r] * acc[ri];
  }
}

// transpose + hi/lo split: y [n x 128] fp32 -> yTh, yTl [128 x n] bf16
__global__ __launch_bounds__(256) void k_ytr(const float* __restrict__ y,
                                             u16* __restrict__ yTh, u16* __restrict__ yTl, int n) {
  __shared__ float tile[32][129];
  int t = threadIdx.x;
  int r0 = blockIdx.x * 32;
  #pragma unroll
  for (int it = 0; it < 4; ++it) {
    int q = it * 256 + t;
    int r = q >> 5, c4 = (q & 31) * 4;
    float4 v = *(const float4*)&y[(size_t)(r0 + r) * 128 + c4];
    tile[r][c4] = v.x; tile[r][c4 + 1] = v.y; tile[r][c4 + 2] = v.z; tile[r][c4 + 3] = v.w;
  }
  __syncthreads();
  #pragma unroll
  for (int it = 0; it < 2; ++it) {
    int q = it * 256 + t;
    int c = q >> 2, r8 = (q & 3) * 8;
    s16x8 h, l;
    #pragma unroll
    for (int j = 0; j < 8; ++j) {
      float v = tile[r8 + j][c];
      u16 hb = f2bf_(v);
      h[j] = (short)hb;
      l[j] = (short)f2bf_(v - bf2f_(hb));
    }
    *(s16x8*)&yTh[(size_t)c * n + r0 + r8] = h;
    *(s16x8*)&yTl[(size_t)c * n + r0 + r8] = l;
  }
}

// z-partials: zpart[s][i][c] = sum_{k in chunk s} A[i][k]*y[k][c].
// BK=64, XOR-swizzled LDS (row*64, group^=(row&7)); 128x128 tile, 4 waves.
template<int ALO>
__global__ __launch_bounds__(256) void k_zgemm_mfma(const float* __restrict__ A,
                                                    const u16* __restrict__ yTh,
                                                    const u16* __restrict__ yTl,
                                                    float* __restrict__ zpart,
                                                    int n, int kchunk) {
  __shared__ __align__(16) u16 ah_[128 * 64];
  __shared__ __align__(16) u16 al_[ALO ? 128 * 64 : 8];
  __shared__ __align__(16) u16 bh_[128 * 64];
  __shared__ __align__(16) u16 bl_[128 * 64];
  int t = threadIdx.x;
  int row0 = blockIdx.x * 128;
  int s = blockIdx.y;
  int kbase = s * kchunk;
  int wave = t >> 6, lane = t & 63;
  int wr = wave >> 1, wc = wave & 1;
  int lrow = lane & 15, kb = lane >> 4;
  const f32x4 z4 = {0.f, 0.f, 0.f, 0.f};
  f32x4 acc[4][4];
  #pragma unroll
  for (int a = 0; a < 4; ++a)
    #pragma unroll
    for (int b = 0; b < 4; ++b) acc[a][b] = z4;

  for (int k0 = 0; k0 < kchunk; k0 += 64) {
    int koff = kbase + k0;
    __syncthreads();
    // A tile 128x64 fp32 -> bf16 hi(/lo), swizzled
    #pragma unroll
    for (int it = 0; it < 8; ++it) {
      int q = it * 256 + t;            // 2048 float4 chunks
      int r = q >> 4, i4 = q & 15;
      int g = i4 >> 1, h4 = (i4 & 1) * 4;
      float4 v = *(const float4*)&A[(size_t)(row0 + r) * n + koff + i4 * 4];
      float vv[4] = {v.x, v.y, v.z, v.w};
      s16x4 hh, ll;
      #pragma unroll
      for (int j = 0; j < 4; ++j) {
        u16 hb = f2bf_(vv[j]);
        hh[j] = (short)hb;
        if (ALO) ll[j] = (short)f2bf_(vv[j] - bf2f_(hb));
      }
      int ld = r * 64 + ((g ^ (r & 7)) << 3) + h4;
      *(s16x4*)&ah_[ld] = hh;
      if (ALO) *(s16x4*)&al_[ld] = ll;
    }
    // B tiles 128x64 bf16 (k-contiguous rows), swizzled
    #pragma unroll
    for (int it = 0; it < 4; ++it) {
      int q = it * 256 + t;            // 1024 s16x8 chunks each
      int r = q >> 3, g = q & 7;
      int ld = r * 64 + ((g ^ (r & 7)) << 3);
      *(s16x8*)&bh_[ld] = *(const s16x8*)(yTh + (size_t)r * n + koff + g * 8);
      *(s16x8*)&bl_[ld] = *(const s16x8*)(yTl + (size_t)r * n + koff + g * 8);
    }
    __syncthreads();
    #pragma unroll
    for (int ks = 0; ks < 2; ++ks) {
      int gg = ks * 4 + kb;
      int gsw = (gg ^ (lrow & 7)) << 3;
      s16x8 af[4], alf[4], bhf[4], blf[4];
      #pragma unroll
      for (int mi = 0; mi < 4; ++mi) {
        int row = wr * 64 + mi * 16 + lrow;
        af[mi] = *(const s16x8*)&ah_[row * 64 + gsw];
        if (ALO) alf[mi] = *(const s16x8*)&al_[row * 64 + gsw];
      }
      #pragma unroll
      for (int ni = 0; ni < 4; ++ni) {
        int row = wc * 64 + ni * 16 + lrow;
        bhf[ni] = *(const s16x8*)&bh_[row * 64 + gsw];
        blf[ni] = *(const s16x8*)&bl_[row * 64 + gsw];
      }
      #pragma unroll
      for (int mi = 0; mi < 4; ++mi)
        #pragma unroll
        for (int ni = 0; ni < 4; ++ni) {
          acc[mi][ni] = __builtin_amdgcn_mfma_f32_16x16x32_bf16(af[mi], bhf[ni], acc[mi][ni], 0, 0, 0);
          acc[mi][ni] = __builtin_amdgcn_mfma_f32_16x16x32_bf16(af[mi], blf[ni], acc[mi][ni], 0, 0, 0);
          if (ALO) {
            acc[mi][ni] = __builtin_amdgcn_mfma_f32_16x16x32_bf16(alf[mi], bhf[ni], acc[mi][ni], 0, 0, 0);
            acc[mi][ni] = __builtin_amdgcn_mfma_f32_16x16x32_bf16(alf[mi], blf[ni], acc[mi][ni], 0, 0, 0);
          }
        }
    }
  }
  int rbase = (lane >> 4) * 4;
  #pragma unroll
  for (int mi = 0; mi < 4; ++mi)
    #pragma unroll
    for (int ni = 0; ni < 4; ++ni)
      #pragma unroll
      for (int j = 0; j < 4; ++j) {
        int gi = row0 + wr * 64 + mi * 16 + rbase + j;
        int gj = wc * 64 + ni * 16 + (lane & 15);
        zpart[((size_t)s * n + gi) * 128 + gj] = acc[mi][ni][j];
      }
}

// epilogue: v = dinv[r]*(sum_s zpart + 2*yp) + b[c]; optional leakyrelu; fp32 out
__global__ void k_epi(const float* __restrict__ zpart, const float* __restrict__ yp,
                      const float* __restrict__ dinv, const float* __restrict__ b,
                      float* __restrict__ outf, int tot, int act, int n, int S) {
  int i = blockIdx.x * 256 + threadIdx.x;
  if (i >= tot) return;
  int r = i >> 7, c = i & 127;
  float z = 0.f;
  for (int s = 0; s < S; ++s) z += zpart[((size_t)s * n + r) * 128 + c];
  float v = dinv[r] * (z + 2.0f * yp[i]) + b[c];
  if (act) v = (v >= 0.f) ? v : 0.01f * v;
  outf[i] = v;
}

__global__ void k_epi_out(const float* __restrict__ zpart, const float* __restrict__ yp,
                          const float* __restrict__ dinv, const float* __restrict__ b,
                          void* __restrict__ out, int tot, int n, int S, const int* __restrict__ flags) {
  int i = blockIdx.x * 256 + threadIdx.x;
  if (i >= tot) return;
  int r = i >> 7, c = i & 127;
  float z = 0.f;
  for (int s = 0; s < S; ++s) z += zpart[((size_t)s * n + r) * 128 + c];
  float v = dinv[r] * (z + 2.0f * yp[i]) + b[c];
  if (flags[0] >= 2048) ((u16*)out)[i] = f2bf_(v);
  else ((float*)out)[i] = v;
}

// ---------------- top-k pooling ----------------
__global__ __launch_bounds__(256) void k_score(const float* __restrict__ x, const float* __restrict__ w,
                                               float* __restrict__ ts, int n) {
  int wave = threadIdx.x >> 6, lane = threadIdx.x & 63;
  int row = blockIdx.x * 4 + wave;
  float w0 = w[lane], w1 = w[64 + lane];
  float nrm = w0 * w0 + w1 * w1;
  #pragma unroll
  for (int off = 32; off; off >>= 1) nrm += __shfl_down(nrm, off);
  nrm = sqrtf(__shfl(nrm, 0));
  if (row < n) {
    const float* xr = x + (size_t)row * 128;
    float d = xr[lane] * w0 + xr[64 + lane] * w1;
    #pragma unroll
    for (int off = 32; off; off >>= 1) d += __shfl_down(d, off);
    if (lane == 0) ts[row] = tanhf(d / nrm);
  }
}

// rank-select top-k: rank_i = #{j: key_j > key_i}; perm[rank_i]=i for rank_i<k.
// key = (monotone-mapped score << 32) | ~index  -> matches stable descending top_k.
__global__ __launch_bounds__(256) void k_rank(const float* __restrict__ ts, int n, int k,
                                              int* __restrict__ perm) {
  __shared__ unsigned long long ch[1024];
  int i = blockIdx.x * 256 + threadIdx.x;
  unsigned bits = __float_as_uint(ts[i]);
  unsigned u = (bits & 0x80000000u) ? ~bits : (bits | 0x80000000u);
  unsigned long long my = ((unsigned long long)u << 32) | (unsigned)(0xFFFFFFFFu - (unsigned)i);
  int rank = 0;
  for (int base = 0; base < n; base += 1024) {
    for (int j = threadIdx.x; j < 1024; j += 256) {
      int idx = base + j;
      unsigned b2 = __float_as_uint(ts[idx]);
      unsigned u2 = (b2 & 0x80000000u) ? ~b2 : (b2 | 0x80000000u);
      ch[j] = ((unsigned long long)u2 << 32) | (unsigned)(0xFFFFFFFFu - (unsigned)idx);
    }
    __syncthreads();
    #pragma unroll 8
    for (int j = 0; j < 1024; ++j) rank += (ch[j] > my) ? 1 : 0;
    __syncthreads();
  }
  if (rank < k) perm[rank] = i;
}

__global__ void k_gather(const float* __restrict__ x, const int* __restrict__ perm,
                         const float* __restrict__ ts, float* __restrict__ out, int k) {
  int i = blockIdx.x * 256 + threadIdx.x;
  if (i < k * 128) {
    int r = i >> 7, c = i & 127;
    int p = perm[r];
    out[i] = x[(size_t)p * 128 + c] * ts[p];
  }
}

__global__ void k_scatadd(float* __restrict__ dst, const float* __restrict__ src,
                          const int* __restrict__ perm, int k) {
  int i = blockIdx.x * 256 + threadIdx.x;
  if (i < k * 128) {
    int r = i >> 7, c = i & 127;
    dst[(size_t)perm[r] * 128 + c] += src[i];
  }
}

// ---------------- augment: bf16 A1 (offdiag A, diag 1) + transpose ----------------
__global__ __launch_bounds__(256) void k_prep(const float* __restrict__ A, u16* __restrict__ A1,
                                              u16* __restrict__ A1T, int n) {
  __shared__ float tile[32][33];
  int bi = blockIdx.y, bj = blockIdx.x;
  int tx = threadIdx.x & 31, ty = threadIdx.x >> 5;
  int r0 = bi * 32, c0 = bj * 32;
  #pragma unroll
  for (int yy = 0; yy < 4; ++yy) {
    int r = ty * 4 + yy;
    int gr = r0 + r, gc = c0 + tx;
    float v = A[(size_t)gr * n + gc];
    if (gr == gc) v = 1.0f;
    tile[r][tx] = v;
    A1[(size_t)gr * n + gc] = f2bf_(v);
  }
  __syncthreads();
  #pragma unroll
  for (int yy = 0; yy < 4; ++yy) {
    int r = ty * 4 + yy;
    int gr = c0 + r, gc = r0 + tx;
    A1T[(size_t)gr * n + gc] = f2bf_(tile[tx][r]);
  }
}

// Cpart += (A1@A1)[perm_i][perm_j] over k-chunk; split-K via blockIdx.z, atomicAdd
// (exact: integer-valued). BK=64, XOR-swizzled LDS. Diag zeroed afterwards by k_diag0.
__global__ __launch_bounds__(256) void k_mfma_pool(const u16* __restrict__ A1, const u16* __restrict__ A1T,
                                                   const int* __restrict__ perm, float* __restrict__ C,
                                                   int M, int K, int kchunk) {
  __shared__ __align__(16) u16 a_lds[128 * 64];
  __shared__ __align__(16) u16 b_lds[128 * 64];
  __shared__ int pr[128], pc[128];
  int t = threadIdx.x;
  int br = blockIdx.x, bc = blockIdx.y;
  int kbase = blockIdx.z * kchunk;
  if (t < 128) pr[t] = perm[br * 128 + t];
  else pc[t - 128] = perm[bc * 128 + (t - 128)];
  __syncthreads();
  int wave = t >> 6, lane = t & 63;
  int wr = wave >> 1, wc = wave & 1;
  int lrow = lane & 15, kb = lane >> 4;
  const f32x4 z4 = {0.f, 0.f, 0.f, 0.f};
  f32x4 acc[4][4];
  #pragma unroll
  for (int a = 0; a < 4; ++a)
    #pragma unroll
    for (int b = 0; b < 4; ++b) acc[a][b] = z4;

  for (int k0 = 0; k0 < kchunk; k0 += 64) {
    int koff = kbase + k0;
    __syncthreads();
    #pragma unroll
    for (int it = 0; it < 4; ++it) {
      int q = it * 256 + t;            // 1024 s16x8 chunks
      int r = q >> 3, g = q & 7;
      int ld = r * 64 + ((g ^ (r & 7)) << 3);
      *(s16x8*)&a_lds[ld] = *(const s16x8*)(A1 + (size_t)pr[r] * K + koff + g * 8);
      *(s16x8*)&b_lds[ld] = *(const s16x8*)(A1T + (size_t)pc[r] * K + koff + g * 8);
    }
    __syncthreads();
    #pragma unroll
    for (int ks = 0; ks < 2; ++ks) {
      int gg = ks * 4 + kb;
      int gsw = (gg ^ (lrow & 7)) << 3;
      s16x8 af[4], bfv[4];
      #pragma unroll
      for (int mi = 0; mi < 4; ++mi)
        af[mi] = *(const s16x8*)&a_lds[(wr * 64 + mi * 16 + lrow) * 64 + gsw];
      #pragma unroll
      for (int ni = 0; ni < 4; ++ni)
        bfv[ni] = *(const s16x8*)&b_lds[(wc * 64 + ni * 16 + lrow) * 64 + gsw];
      #pragma unroll
      for (int mi = 0; mi < 4; ++mi)
        #pragma unroll
        for (int ni = 0; ni < 4; ++ni)
          acc[mi][ni] = __builtin_amdgcn_mfma_f32_16x16x32_bf16(af[mi], bfv[ni], acc[mi][ni], 0, 0, 0);
    }
  }
  int rbase = (lane >> 4) * 4;
  #pragma unroll
  for (int mi = 0; mi < 4; ++mi)
    #pragma unroll
    for (int ni = 0; ni < 4; ++ni)
      #pragma unroll
      for (int j = 0; j < 4; ++j) {
        int gi = br * 128 + wr * 64 + mi * 16 + rbase + j;
        int gj = bc * 128 + wc * 64 + ni * 16 + (lane & 15);
        atomicAdd(&C[(size_t)gi * M + gj], acc[mi][ni][j]);
      }
}

// ---------------- driver ----------------
static void run_gcn(hipStream_t s, const float* A, int n, const float* xinp,
                    const float* W, const float* b, float* dinv, float* tmpY,
                    u16* yTh, u16* yTl, float* zpart, int alo,
                    int act, float* outf, void* outfinal, const int* flags) {
  k_dinv<<<n, 256, 0, s>>>(A, dinv, n);
  k_xw<<<n / 16, 256, 0, s>>>(xinp, W, dinv, tmpY, n);
  k_ytr<<<n / 32, 256, 0, s>>>(tmpY, yTh, yTl, n);
  int S = (n >= 2048) ? 16 : (n == 1024 ? 8 : 4);
  int kchunk = n / S;
  if (alo)
    k_zgemm_mfma<1><<<dim3(n / 128, S), 256, 0, s>>>(A, yTh, yTl, zpart, n, kchunk);
  else
    k_zgemm_mfma<0><<<dim3(n / 128, S), 256, 0, s>>>(A, yTh, yTl, zpart, n, kchunk);
  int tot = n * 128;
  if (outf)
    k_epi<<<(tot + 255) / 256, 256, 0, s>>>(zpart, tmpY, dinv, b, outf, tot, act, n, S);
  else
    k_epi_out<<<(tot + 255) / 256, 256, 0, s>>>(zpart, tmpY, dinv, b, outfinal, tot, n, S, flags);
}

extern "C" void kernel_launch(void* const* d_in, const int* in_sizes, int n_in,
                              void* d_out, int out_size, void* d_ws, size_t ws_size,
                              hipStream_t stream) {
  (void)in_sizes; (void)n_in; (void)out_size; (void)ws_size;
  const void* x_in  = d_in[0];
  const int*  ei    = (const int*)d_in[1];
  const void* Wd_in = d_in[2];
  const void* bd_in = d_in[3];
  const void* Wu_in = d_in[4];
  const void* bu_in = d_in[5];
  const void* pw_in = d_in[6];

  char* p = (char*)d_ws;
  auto alloc = [&](size_t bytes) { char* r = p; p += (bytes + 255) & ~(size_t)255; return r; };
  float* A0   = (float*)alloc(4096ull * 4096 * 4);
  float* A1p  = (float*)alloc(2048ull * 2048 * 4);
  float* A2p  = (float*)alloc(1024ull * 1024 * 4);
  float* A3p  = (float*)alloc(512ull * 512 * 4);
  u16*   A1b  = (u16*)alloc(4096ull * 4096 * 2);   // pool src; zpart aliases during GCNs
  u16*   A1bT = (u16*)alloc(4096ull * 4096 * 2);   // pool src^T; yTh/yTl alias during GCNs
  float* xb0  = (float*)alloc(4096 * 128 * 4);
  float* xb1  = (float*)alloc(2048 * 128 * 4);
  float* xb2  = (float*)alloc(1024 * 128 * 4);
  float* xb3  = (float*)alloc(512 * 128 * 4);
  float* xin  = (float*)alloc(4096 * 128 * 4);
  float* tmpX = (float*)alloc(4096 * 128 * 4);
  float* tmpY = (float*)alloc(4096 * 128 * 4);
  float* dinv = (float*)alloc(4096 * 4);
  float* tsc  = (float*)alloc(4096 * 4);
  int*   perm1 = (int*)alloc(2048 * 4);
  int*   perm2 = (int*)alloc(1024 * 4);
  int*   perm3 = (int*)alloc(512 * 4);
  float* Wdf  = (float*)alloc(4 * 128 * 128 * 4);
  float* bdf  = (float*)alloc(4 * 128 * 4);
  float* Wuf  = (float*)alloc(3 * 128 * 128 * 4);
  float* buf_ = (float*)alloc(3 * 128 * 4);
  float* pwf  = (float*)alloc(3 * 128 * 4);
  int*   flags = (int*)alloc(4 * 4);

  // aliases (dead regions during GCN phases)
  float* zpart = (float*)A1b;           // 16 * 4096 * 128 * 4 B = 33.5 MB = |A1b|
  u16*   yTh   = (u16*)A1bT;            // 1 MB
  u16*   yTl   = (u16*)A1bT + 128 * 4096;

  // dtype detection
  k_zeroflags<<<1, 64, 0, stream>>>(flags);
  k_detect<<<16, 256, 0, stream>>>((const u16*)x_in, ei, flags);

  auto cvt = [&](const void* src, float* dst, int n) {
    k_loadf<<<(n + 255) / 256, 256, 0, stream>>>(src, dst, n, flags);
  };
  cvt(x_in, xin, 4096 * 128);
  cvt(Wd_in, Wdf, 4 * 128 * 128);
  cvt(bd_in, bdf, 4 * 128);
  cvt(Wu_in, Wuf, 3 * 128 * 128);
  cvt(bu_in, buf_, 3 * 128);
  cvt(pw_in, pwf, 3 * 128);

  // adjacency
  k_fill0<<<4096, 256, 0, stream>>>((float4*)A0, 4096L * 4096 / 4);
  k_edges<<<(65536 + 255) / 256, 256, 0, stream>>>(ei, A0, 65536, 4096, flags);

  // level-0 GCN
  run_gcn(stream, A0, 4096, xin, Wdf, bdf, dinv, tmpY, yTh, yTl, zpart, 0, 1, xb0, nullptr, flags);

  // down path
  float* Anexts[3] = {A1p, A2p, A3p};
  int*   perms[3]  = {perm1, perm2, perm3};
  float* xouts[3]  = {xb1, xb2, xb3};
  int    alos[3]   = {0, 1, 1};
  int    spool[3]  = {2, 4, 8};
  float* Acur = A0;
  float* xcur = xb0;
  int n = 4096;
  for (int lvl = 1; lvl <= 3; ++lvl) {
    int k = n / 2;
    k_score<<<n / 4, 256, 0, stream>>>(xcur, pwf + (lvl - 1) * 128, tsc, n);
    k_rank<<<n / 256, 256, 0, stream>>>(tsc, n, k, perms[lvl - 1]);
    k_prep<<<dim3(n / 32, n / 32), 256, 0, stream>>>(Acur, A1b, A1bT, n);
    float* Cn = Anexts[lvl - 1];
    int Sp = spool[lvl - 1];
    k_fill0<<<2048, 256, 0, stream>>>((float4*)Cn, (long)k * k / 4);
    k_mfma_pool<<<dim3(k / 128, k / 128, Sp), 256, 0, stream>>>(A1b, A1bT, perms[lvl - 1], Cn, k, n, n / Sp);
    k_diag0<<<(k + 255) / 256, 256, 0, stream>>>(Cn, k);
    k_gather<<<(k * 128 + 255) / 256, 256, 0, stream>>>(xcur, perms[lvl - 1], tsc, tmpX, k);
    run_gcn(stream, Cn, k, tmpX, Wdf + lvl * 16384, bdf + lvl * 128,
            dinv, tmpY, yTh, yTl, zpart, alos[lvl - 1], 1, xouts[lvl - 1], nullptr, flags);
    Acur = Cn;
    xcur = xouts[lvl - 1];
    n = k;
  }

  // up path
  float* prev = xb3;
  float* Ajs[3]  = {A2p, A1p, A0};
  int*   pjs[3]  = {perm3, perm2, perm1};
  float* resb[3] = {xb2, xb1, xb0};
  int    njs[3]  = {1024, 2048, 4096};
  int    alou[3] = {1, 0, 0};
  for (int i = 0; i < 3; ++i) {
    int nj = njs[i], kk = nj / 2;
    k_copy<<<(nj * 128 + 255) / 256, 256, 0, stream>>>(resb[i], tmpX, nj * 128);
    k_scatadd<<<(kk * 128 + 255) / 256, 256, 0, stream>>>(tmpX, prev, pjs[i], kk);
    if (i < 2) {
      run_gcn(stream, Ajs[i], nj, tmpX, Wuf + i * 16384, buf_ + i * 128,
              dinv, tmpY, yTh, yTl, zpart, alou[i], 1, resb[i], nullptr, flags);
      prev = resb[i];
    } else {
      run_gcn(stream, Ajs[i], nj, tmpX, Wuf + i * 16384, buf_ + i * 128,
              dinv, tmpY, yTh, yTl, zpart, alou[i], 0, nullptr, d_out, flags);
    }
  }
}

// Round 5
// 566.666 us; speedup vs baseline: 2.9242x; 1.0844x over previous
//
#include <hip/hip_runtime.h>

typedef unsigned short u16;
typedef __attribute__((ext_vector_type(4))) short s16x4;
typedef __attribute__((ext_vector_type(8))) short s16x8;
typedef __attribute__((ext_vector_type(4))) float f32x4;

__device__ __forceinline__ float bf2f_(u16 b) { return __uint_as_float(((unsigned)b) << 16); }
__device__ __forceinline__ u16 f2bf_(float f) {
  unsigned u = __float_as_uint(f);
  return (u16)((u + 0x7FFFu + ((u >> 16) & 1u)) >> 16);
}

// decode edge e from int32 or int64 edge_index per flags[1]
__device__ __forceinline__ void edge_decode(const int* ei, int e, int E, const int* flags,
                                            int& src, int& dst) {
  bool is64 = flags[1] < 100;
  src = is64 ? ei[2 * e] : ei[e];
  dst = is64 ? ei[2 * E + 2 * e] : ei[E + e];
}

// ---------------- dtype detection (deterministic, device-side) ----------------
__global__ void k_zeroflags(int* f) { if (threadIdx.x < 4) f[threadIdx.x] = 0; }

__global__ __launch_bounds__(256) void k_detect(const u16* __restrict__ xb,
                                                const int* __restrict__ ei,
                                                int* __restrict__ flags) {
  int i = blockIdx.x * 256 + threadIdx.x;  // 4096 threads
  int e8 = (xb[2 * i] >> 7) & 0xFF;
  int sane = (e8 >= 100 && e8 <= 140) ? 1 : 0;
  int nz = (ei[2 * i + 1] != 0) ? 1 : 0;
  #pragma unroll
  for (int off = 32; off; off >>= 1) { sane += __shfl_down(sane, off); nz += __shfl_down(nz, off); }
  if ((threadIdx.x & 63) == 0) { atomicAdd(&flags[0], sane); atomicAdd(&flags[1], nz); }
}

__global__ void k_loadf(const void* __restrict__ src, float* __restrict__ dst, int n,
                        const int* __restrict__ flags) {
  int i = blockIdx.x * 256 + threadIdx.x;
  if (i >= n) return;
  bool isbf = flags[0] >= 2048;
  dst[i] = isbf ? bf2f_(((const u16*)src)[i]) : ((const float*)src)[i];
}

// ---------------- setup ----------------
__global__ void k_fill0(float4* __restrict__ p, long n4) {
  long i = blockIdx.x * 256L + threadIdx.x;
  long stride = (long)gridDim.x * 256L;
  for (; i < n4; i += stride) p[i] = make_float4(0.f, 0.f, 0.f, 0.f);
}

__global__ void k_edges(const int* __restrict__ ei, float* __restrict__ A, int E, int n,
                        const int* __restrict__ flags) {
  int e = blockIdx.x * 256 + threadIdx.x;
  if (e >= E) return;
  int src, dst; edge_decode(ei, e, E, flags, src, dst);
  if (src >= 0 && src < n && dst >= 0 && dst < n)
    atomicAdd(&A[(size_t)dst * n + src], 1.0f);
}

__global__ void k_copy(const float* __restrict__ src, float* __restrict__ dst, int n) {
  int i = blockIdx.x * 256 + threadIdx.x;
  if (i < n) dst[i] = src[i];
}

__global__ void k_diag0(float* __restrict__ C, int M) {
  int i = blockIdx.x * 256 + threadIdx.x;
  if (i < M) C[(size_t)i * M + i] = 0.f;
}

// ---------------- CSR build for sparse L1 pool (self-edges excluded) ----------------
__global__ void k_degzero(int* __restrict__ a, int n2) {
  int i = blockIdx.x * 256 + threadIdx.x;
  if (i < n2) a[i] = 0;
}

__global__ void k_degcnt(const int* __restrict__ ei, int E, int n, const int* __restrict__ flags,
                         int* __restrict__ indeg, int* __restrict__ outdeg) {
  int e = blockIdx.x * 256 + threadIdx.x;
  if (e >= E) return;
  int src, dst; edge_decode(ei, e, E, flags, src, dst);
  if (src < 0 || src >= n || dst < 0 || dst >= n || src == dst) return;
  atomicAdd(&indeg[dst], 1);
  atomicAdd(&outdeg[src], 1);
}

// exclusive scan of indeg/outdeg (n multiple of 1024) -> offsets + cursors
__global__ __launch_bounds__(1024) void k_scan(const int* __restrict__ indeg, const int* __restrict__ outdeg,
                                               int* __restrict__ inoff, int* __restrict__ outoff,
                                               int* __restrict__ incur, int* __restrict__ outcur, int n) {
  __shared__ int part[1024];
  int t = threadIdx.x;
  int per = n / 1024;
  for (int pass = 0; pass < 2; ++pass) {
    const int* deg = pass ? outdeg : indeg;
    int* off = pass ? outoff : inoff;
    int* cur = pass ? outcur : incur;
    int local[8];
    int s = 0;
    for (int j = 0; j < per; ++j) { local[j] = s; s += deg[t * per + j]; }
    part[t] = s;
    __syncthreads();
    for (int d = 1; d < 1024; d <<= 1) {
      int v = (t >= d) ? part[t - d] : 0;
      __syncthreads();
      part[t] += v;
      __syncthreads();
    }
    int base = (t == 0) ? 0 : part[t - 1];
    for (int j = 0; j < per; ++j) {
      off[t * per + j] = base + local[j];
      cur[t * per + j] = base + local[j];
    }
    if (t == 1023) off[n] = part[1023];
    __syncthreads();
  }
}

__global__ void k_csrfill(const int* __restrict__ ei, int E, int n, const int* __restrict__ flags,
                          int* __restrict__ incur, int* __restrict__ outcur,
                          int* __restrict__ inlist, int* __restrict__ outlist) {
  int e = blockIdx.x * 256 + threadIdx.x;
  if (e >= E) return;
  int src, dst; edge_decode(ei, e, E, flags, src, dst);
  if (src < 0 || src >= n || dst < 0 || dst >= n || src == dst) return;
  inlist[atomicAdd(&incur[dst], 1)] = src;
  outlist[atomicAdd(&outcur[src], 1)] = dst;
}

__global__ void k_invinit(int* __restrict__ inv, int n) {
  int i = blockIdx.x * 256 + threadIdx.x;
  if (i < n) inv[i] = -1;
}
__global__ void k_invset(const int* __restrict__ perm, int* __restrict__ inv, int k) {
  int i = blockIdx.x * 256 + threadIdx.x;
  if (i < k) inv[perm[i]] = i;
}

// sparse pool: C[ri][rj] += Ao2 path counts. One wave per node v:
// pairs (out-edge v->i) x (in-edge j->v) contribute 1 to (i,j); i==j (diag) skipped.
// All values small integers -> fp32 atomicAdd exact & order-independent (deterministic).
__global__ __launch_bounds__(256) void k_spool(const int* __restrict__ inoff, const int* __restrict__ inlist,
                                               const int* __restrict__ outoff, const int* __restrict__ outlist,
                                               const int* __restrict__ inv, float* __restrict__ C,
                                               int M, int n) {
  int wave = threadIdx.x >> 6, lane = threadIdx.x & 63;
  int v = blockIdx.x * 4 + wave;
  if (v >= n) return;
  int ib = inoff[v], ni = inoff[v + 1] - ib;
  int ob = outoff[v], no = outoff[v + 1] - ob;
  int tot = ni * no;
  for (int p = lane; p < tot; p += 64) {
    int oi = p / ni, ii = p - oi * ni;
    int i = outlist[ob + oi];
    int j = inlist[ib + ii];
    if (i == j) continue;
    int ri = inv[i], rj = inv[j];
    if (ri >= 0 && rj >= 0) atomicAdd(&C[(size_t)ri * M + rj], 1.0f);
  }
}

// + 2*Ao term
__global__ void k_spedge(const int* __restrict__ ei, int E, int n, const int* __restrict__ flags,
                         const int* __restrict__ inv, float* __restrict__ C, int M) {
  int e = blockIdx.x * 256 + threadIdx.x;
  if (e >= E) return;
  int src, dst; edge_decode(ei, e, E, flags, src, dst);
  if (src < 0 || src >= n || dst < 0 || dst >= n || src == dst) return;
  int ri = inv[dst], rj = inv[src];
  if (ri >= 0 && rj >= 0) atomicAdd(&C[(size_t)ri * M + rj], 2.0f);
}

// ---------------- GCN pieces ----------------
__global__ __launch_bounds__(256) void k_dinv(const float* __restrict__ A, float* __restrict__ dinv, int n) {
  int row = blockIdx.x;
  const float* r = A + (size_t)row * n;
  float s = 0.f;
  for (int j = threadIdx.x; j < n; j += 256) s += r[j];
  #pragma unroll
  for (int off = 32; off; off >>= 1) s += __shfl_down(s, off);
  __shared__ float red[4];
  int wave = threadIdx.x >> 6, lane = threadIdx.x & 63;
  if (lane == 0) red[wave] = s;
  __syncthreads();
  if (threadIdx.x == 0) {
    float deg = red[0] + red[1] + red[2] + red[3] + 2.0f;
    dinv[row] = rsqrtf(deg);
  }
}

__global__ __launch_bounds__(256) void k_xw(const float* __restrict__ x, const float* __restrict__ W,
                                            const float* __restrict__ dinv, float* __restrict__ yp, int n) {
  __shared__ float xs_[16 * 128];
  int t = threadIdx.x;
  int row0 = blockIdx.x * 16;
  for (int e = t; e < 16 * 128; e += 256) {
    int r = e >> 7, c = e & 127;
    xs_[e] = x[(size_t)(row0 + r) * 128 + c];
  }
  __syncthreads();
  int c = t & 127, rh = t >> 7;
  float acc[8];
  #pragma unroll
  for (int ri = 0; ri < 8; ++ri) acc[ri] = 0.f;
  for (int k = 0; k < 128; ++k) {
    float wv = W[k * 128 + c];
    #pragma unroll
    for (int ri = 0; ri < 8; ++ri) acc[ri] += xs_[(rh * 8 + ri) * 128 + k] * wv;
  }
  #pragma unroll
  for (int ri = 0; ri < 8; ++ri) {
    int r = row0 + rh * 8 + ri;
    yp[(size_t)r * 128 + c] = dinv[r] * acc[ri];
  }
}

__global__ __launch_bounds__(256) void k_ytr(const float* __restrict__ y,
                                             u16* __restrict__ yTh, u16* __restrict__ yTl, int n) {
  __shared__ float tile[32][129];
  int t = threadIdx.x;
  int r0 = blockIdx.x * 32;
  #pragma unroll
  for (int it = 0; it < 4; ++it) {
    int q = it * 256 + t;
    int r = q >> 5, c4 = (q & 31) * 4;
    float4 v = *(const float4*)&y[(size_t)(r0 + r) * 128 + c4];
    tile[r][c4] = v.x; tile[r][c4 + 1] = v.y; tile[r][c4 + 2] = v.z; tile[r][c4 + 3] = v.w;
  }
  __syncthreads();
  #pragma unroll
  for (int it = 0; it < 2; ++it) {
    int q = it * 256 + t;
    int c = q >> 2, r8 = (q & 3) * 8;
    s16x8 h, l;
    #pragma unroll
    for (int j = 0; j < 8; ++j) {
      float v = tile[r8 + j][c];
      u16 hb = f2bf_(v);
      h[j] = (short)hb;
      l[j] = (short)f2bf_(v - bf2f_(hb));
    }
    *(s16x8*)&yTh[(size_t)c * n + r0 + r8] = h;
    *(s16x8*)&yTl[(size_t)c * n + r0 + r8] = l;
  }
}

// z-partials: zpart[s][i][c] = sum_{k in chunk s} A[i][k]*y[k][c].
// BK=64, XOR-swizzled LDS; 128x128 tile, 4 waves.
template<int ALO>
__global__ __launch_bounds__(256) void k_zgemm_mfma(const float* __restrict__ A,
                                                    const u16* __restrict__ yTh,
                                                    const u16* __restrict__ yTl,
                                                    float* __restrict__ zpart,
                                                    int n, int kchunk) {
  __shared__ __align__(16) u16 ah_[128 * 64];
  __shared__ __align__(16) u16 al_[ALO ? 128 * 64 : 8];
  __shared__ __align__(16) u16 bh_[128 * 64];
  __shared__ __align__(16) u16 bl_[128 * 64];
  int t = threadIdx.x;
  int row0 = blockIdx.x * 128;
  int s = blockIdx.y;
  int kbase = s * kchunk;
  int wave = t >> 6, lane = t & 63;
  int wr = wave >> 1, wc = wave & 1;
  int lrow = lane & 15, kb = lane >> 4;
  const f32x4 z4 = {0.f, 0.f, 0.f, 0.f};
  f32x4 acc[4][4];
  #pragma unroll
  for (int a = 0; a < 4; ++a)
    #pragma unroll
    for (int b = 0; b < 4; ++b) acc[a][b] = z4;

  for (int k0 = 0; k0 < kchunk; k0 += 64) {
    int koff = kbase + k0;
    __syncthreads();
    #pragma unroll
    for (int it = 0; it < 8; ++it) {
      int q = it * 256 + t;            // 2048 float4 chunks
      int r = q >> 4, i4 = q & 15;
      int g = i4 >> 1, h4 = (i4 & 1) * 4;
      float4 v = *(const float4*)&A[(size_t)(row0 + r) * n + koff + i4 * 4];
      float vv[4] = {v.x, v.y, v.z, v.w};
      s16x4 hh, ll;
      #pragma unroll
      for (int j = 0; j < 4; ++j) {
        u16 hb = f2bf_(vv[j]);
        hh[j] = (short)hb;
        if (ALO) ll[j] = (short)f2bf_(vv[j] - bf2f_(hb));
      }
      int ld = r * 64 + ((g ^ (r & 7)) << 3) + h4;
      *(s16x4*)&ah_[ld] = hh;
      if (ALO) *(s16x4*)&al_[ld] = ll;
    }
    #pragma unroll
    for (int it = 0; it < 4; ++it) {
      int q = it * 256 + t;            // 1024 s16x8 chunks each
      int r = q >> 3, g = q & 7;
      int ld = r * 64 + ((g ^ (r & 7)) << 3);
      *(s16x8*)&bh_[ld] = *(const s16x8*)(yTh + (size_t)r * n + koff + g * 8);
      *(s16x8*)&bl_[ld] = *(const s16x8*)(yTl + (size_t)r * n + koff + g * 8);
    }
    __syncthreads();
    #pragma unroll
    for (int ks = 0; ks < 2; ++ks) {
      int gg = ks * 4 + kb;
      int gsw = (gg ^ (lrow & 7)) << 3;
      s16x8 af[4], alf[4], bhf[4], blf[4];
      #pragma unroll
      for (int mi = 0; mi < 4; ++mi) {
        int row = wr * 64 + mi * 16 + lrow;
        af[mi] = *(const s16x8*)&ah_[row * 64 + gsw];
        if (ALO) alf[mi] = *(const s16x8*)&al_[row * 64 + gsw];
      }
      #pragma unroll
      for (int ni = 0; ni < 4; ++ni) {
        int row = wc * 64 + ni * 16 + lrow;
        bhf[ni] = *(const s16x8*)&bh_[row * 64 + gsw];
        blf[ni] = *(const s16x8*)&bl_[row * 64 + gsw];
      }
      #pragma unroll
      for (int mi = 0; mi < 4; ++mi)
        #pragma unroll
        for (int ni = 0; ni < 4; ++ni) {
          acc[mi][ni] = __builtin_amdgcn_mfma_f32_16x16x32_bf16(af[mi], bhf[ni], acc[mi][ni], 0, 0, 0);
          acc[mi][ni] = __builtin_amdgcn_mfma_f32_16x16x32_bf16(af[mi], blf[ni], acc[mi][ni], 0, 0, 0);
          if (ALO) {
            acc[mi][ni] = __builtin_amdgcn_mfma_f32_16x16x32_bf16(alf[mi], bhf[ni], acc[mi][ni], 0, 0, 0);
            acc[mi][ni] = __builtin_amdgcn_mfma_f32_16x16x32_bf16(alf[mi], blf[ni], acc[mi][ni], 0, 0, 0);
          }
        }
    }
  }
  int rbase = (lane >> 4) * 4;
  #pragma unroll
  for (int mi = 0; mi < 4; ++mi)
    #pragma unroll
    for (int ni = 0; ni < 4; ++ni)
      #pragma unroll
      for (int j = 0; j < 4; ++j) {
        int gi = row0 + wr * 64 + mi * 16 + rbase + j;
        int gj = wc * 64 + ni * 16 + (lane & 15);
        zpart[((size_t)s * n + gi) * 128 + gj] = acc[mi][ni][j];
      }
}

__global__ void k_epi(const float* __restrict__ zpart, const float* __restrict__ yp,
                      const float* __restrict__ dinv, const float* __restrict__ b,
                      float* __restrict__ outf, int tot, int act, int n, int S) {
  int i = blockIdx.x * 256 + threadIdx.x;
  if (i >= tot) return;
  int r = i >> 7, c = i & 127;
  float z = 0.f;
  for (int s = 0; s < S; ++s) z += zpart[((size_t)s * n + r) * 128 + c];
  float v = dinv[r] * (z + 2.0f * yp[i]) + b[c];
  if (act) v = (v >= 0.f) ? v : 0.01f * v;
  outf[i] = v;
}

__global__ void k_epi_out(const float* __restrict__ zpart, const float* __restrict__ yp,
                          const float* __restrict__ dinv, const float* __restrict__ b,
                          void* __restrict__ out, int tot, int n, int S, const int* __restrict__ flags) {
  int i = blockIdx.x * 256 + threadIdx.x;
  if (i >= tot) return;
  int r = i >> 7, c = i & 127;
  float z = 0.f;
  for (int s = 0; s < S; ++s) z += zpart[((size_t)s * n + r) * 128 + c];
  float v = dinv[r] * (z + 2.0f * yp[i]) + b[c];
  if (flags[0] >= 2048) ((u16*)out)[i] = f2bf_(v);
  else ((float*)out)[i] = v;
}

// ---------------- top-k pooling ----------------
__global__ __launch_bounds__(256) void k_score(const float* __restrict__ x, const float* __restrict__ w,
                                               float* __restrict__ ts, int n) {
  int wave = threadIdx.x >> 6, lane = threadIdx.x & 63;
  int row = blockIdx.x * 4 + wave;
  float w0 = w[lane], w1 = w[64 + lane];
  float nrm = w0 * w0 + w1 * w1;
  #pragma unroll
  for (int off = 32; off; off >>= 1) nrm += __shfl_down(nrm, off);
  nrm = sqrtf(__shfl(nrm, 0));
  if (row < n) {
    const float* xr = x + (size_t)row * 128;
    float d = xr[lane] * w0 + xr[64 + lane] * w1;
    #pragma unroll
    for (int off = 32; off; off >>= 1) d += __shfl_down(d, off);
    if (lane == 0) ts[row] = tanhf(d / nrm);
  }
}

__global__ __launch_bounds__(256) void k_rank(const float* __restrict__ ts, int n, int k,
                                              int* __restrict__ perm) {
  __shared__ unsigned long long ch[1024];
  int i = blockIdx.x * 256 + threadIdx.x;
  unsigned bits = __float_as_uint(ts[i]);
  unsigned u = (bits & 0x80000000u) ? ~bits : (bits | 0x80000000u);
  unsigned long long my = ((unsigned long long)u << 32) | (unsigned)(0xFFFFFFFFu - (unsigned)i);
  int rank = 0;
  for (int base = 0; base < n; base += 1024) {
    for (int j = threadIdx.x; j < 1024; j += 256) {
      int idx = base + j;
      unsigned b2 = __float_as_uint(ts[idx]);
      unsigned u2 = (b2 & 0x80000000u) ? ~b2 : (b2 | 0x80000000u);
      ch[j] = ((unsigned long long)u2 << 32) | (unsigned)(0xFFFFFFFFu - (unsigned)idx);
    }
    __syncthreads();
    #pragma unroll 8
    for (int j = 0; j < 1024; ++j) rank += (ch[j] > my) ? 1 : 0;
    __syncthreads();
  }
  if (rank < k) perm[rank] = i;
}

__global__ void k_gather(const float* __restrict__ x, const int* __restrict__ perm,
                         const float* __restrict__ ts, float* __restrict__ out, int k) {
  int i = blockIdx.x * 256 + threadIdx.x;
  if (i < k * 128) {
    int r = i >> 7, c = i & 127;
    int p = perm[r];
    out[i] = x[(size_t)p * 128 + c] * ts[p];
  }
}

__global__ void k_scatadd(float* __restrict__ dst, const float* __restrict__ src,
                          const int* __restrict__ perm, int k) {
  int i = blockIdx.x * 256 + threadIdx.x;
  if (i < k * 128) {
    int r = i >> 7, c = i & 127;
    dst[(size_t)perm[r] * 128 + c] += src[i];
  }
}

// ---------------- dense augment for L2/L3: bf16 A1 (offdiag A, diag 1) + transpose ----------------
__global__ __launch_bounds__(256) void k_prep(const float* __restrict__ A, u16* __restrict__ A1,
                                              u16* __restrict__ A1T, int n) {
  __shared__ float tile[32][33];
  int bi = blockIdx.y, bj = blockIdx.x;
  int tx = threadIdx.x & 31, ty = threadIdx.x >> 5;
  int r0 = bi * 32, c0 = bj * 32;
  #pragma unroll
  for (int yy = 0; yy < 4; ++yy) {
    int r = ty * 4 + yy;
    int gr = r0 + r, gc = c0 + tx;
    float v = A[(size_t)gr * n + gc];
    if (gr == gc) v = 1.0f;
    tile[r][tx] = v;
    A1[(size_t)gr * n + gc] = f2bf_(v);
  }
  __syncthreads();
  #pragma unroll
  for (int yy = 0; yy < 4; ++yy) {
    int r = ty * 4 + yy;
    int gr = c0 + r, gc = r0 + tx;
    A1T[(size_t)gr * n + gc] = f2bf_(tile[tx][r]);
  }
}

// dense pool for L2/L3: split-K atomicAdd (exact: integer-valued). BK=64, swizzled.
__global__ __launch_bounds__(256) void k_mfma_pool(const u16* __restrict__ A1, const u16* __restrict__ A1T,
                                                   const int* __restrict__ perm, float* __restrict__ C,
                                                   int M, int K, int kchunk) {
  __shared__ __align__(16) u16 a_lds[128 * 64];
  __shared__ __align__(16) u16 b_lds[128 * 64];
  __shared__ int pr[128], pc[128];
  int t = threadIdx.x;
  int br = blockIdx.x, bc = blockIdx.y;
  int kbase = blockIdx.z * kchunk;
  if (t < 128) pr[t] = perm[br * 128 + t];
  else pc[t - 128] = perm[bc * 128 + (t - 128)];
  __syncthreads();
  int wave = t >> 6, lane = t & 63;
  int wr = wave >> 1, wc = wave & 1;
  int lrow = lane & 15, kb = lane >> 4;
  const f32x4 z4 = {0.f, 0.f, 0.f, 0.f};
  f32x4 acc[4][4];
  #pragma unroll
  for (int a = 0; a < 4; ++a)
    #pragma unroll
    for (int b = 0; b < 4; ++b) acc[a][b] = z4;

  for (int k0 = 0; k0 < kchunk; k0 += 64) {
    int koff = kbase + k0;
    __syncthreads();
    #pragma unroll
    for (int it = 0; it < 4; ++it) {
      int q = it * 256 + t;
      int r = q >> 3, g = q & 7;
      int ld = r * 64 + ((g ^ (r & 7)) << 3);
      *(s16x8*)&a_lds[ld] = *(const s16x8*)(A1 + (size_t)pr[r] * K + koff + g * 8);
      *(s16x8*)&b_lds[ld] = *(const s16x8*)(A1T + (size_t)pc[r] * K + koff + g * 8);
    }
    __syncthreads();
    #pragma unroll
    for (int ks = 0; ks < 2; ++ks) {
      int gg = ks * 4 + kb;
      int gsw = (gg ^ (lrow & 7)) << 3;
      s16x8 af[4], bfv[4];
      #pragma unroll
      for (int mi = 0; mi < 4; ++mi)
        af[mi] = *(const s16x8*)&a_lds[(wr * 64 + mi * 16 + lrow) * 64 + gsw];
      #pragma unroll
      for (int ni = 0; ni < 4; ++ni)
        bfv[ni] = *(const s16x8*)&b_lds[(wc * 64 + ni * 16 + lrow) * 64 + gsw];
      #pragma unroll
      for (int mi = 0; mi < 4; ++mi)
        #pragma unroll
        for (int ni = 0; ni < 4; ++ni)
          acc[mi][ni] = __builtin_amdgcn_mfma_f32_16x16x32_bf16(af[mi], bfv[ni], acc[mi][ni], 0, 0, 0);
    }
  }
  int rbase = (lane >> 4) * 4;
  #pragma unroll
  for (int mi = 0; mi < 4; ++mi)
    #pragma unroll
    for (int ni = 0; ni < 4; ++ni)
      #pragma unroll
      for (int j = 0; j < 4; ++j) {
        int gi = br * 128 + wr * 64 + mi * 16 + rbase + j;
        int gj = bc * 128 + wc * 64 + ni * 16 + (lane & 15);
        atomicAdd(&C[(size_t)gi * M + gj], acc[mi][ni][j]);
      }
}

// ---------------- driver ----------------
static void run_gcn(hipStream_t s, const float* A, int n, const float* xinp,
                    const float* W, const float* b, float* dinv, int compute_dinv, float* tmpY,
                    u16* yTh, u16* yTl, float* zpart, int alo,
                    int act, float* outf, void* outfinal, const int* flags) {
  if (compute_dinv) k_dinv<<<n, 256, 0, s>>>(A, dinv, n);
  k_xw<<<n / 16, 256, 0, s>>>(xinp, W, dinv, tmpY, n);
  k_ytr<<<n / 32, 256, 0, s>>>(tmpY, yTh, yTl, n);
  int S = (n >= 2048) ? 16 : (n == 1024 ? 8 : 4);
  int kchunk = n / S;
  if (alo)
    k_zgemm_mfma<1><<<dim3(n / 128, S), 256, 0, s>>>(A, yTh, yTl, zpart, n, kchunk);
  else
    k_zgemm_mfma<0><<<dim3(n / 128, S), 256, 0, s>>>(A, yTh, yTl, zpart, n, kchunk);
  int tot = n * 128;
  if (outf)
    k_epi<<<(tot + 255) / 256, 256, 0, s>>>(zpart, tmpY, dinv, b, outf, tot, act, n, S);
  else
    k_epi_out<<<(tot + 255) / 256, 256, 0, s>>>(zpart, tmpY, dinv, b, outfinal, tot, n, S, flags);
}

extern "C" void kernel_launch(void* const* d_in, const int* in_sizes, int n_in,
                              void* d_out, int out_size, void* d_ws, size_t ws_size,
                              hipStream_t stream) {
  (void)in_sizes; (void)n_in; (void)out_size; (void)ws_size;
  const void* x_in  = d_in[0];
  const int*  ei    = (const int*)d_in[1];
  const void* Wd_in = d_in[2];
  const void* bd_in = d_in[3];
  const void* Wu_in = d_in[4];
  const void* bu_in = d_in[5];
  const void* pw_in = d_in[6];

  char* p = (char*)d_ws;
  auto alloc = [&](size_t bytes) { char* r = p; p += (bytes + 255) & ~(size_t)255; return r; };
  float* A0   = (float*)alloc(4096ull * 4096 * 4);
  float* A1p  = (float*)alloc(2048ull * 2048 * 4);
  float* A2p  = (float*)alloc(1024ull * 1024 * 4);
  float* A3p  = (float*)alloc(512ull * 512 * 4);
  u16*   A1b  = (u16*)alloc(4096ull * 4096 * 2);   // L2/L3 pool src; zpart aliases during GCNs
  u16*   A1bT = (u16*)alloc(4096ull * 4096 * 2);   // L2/L3 pool src^T; yTh/yTl alias during GCNs
  float* xb0  = (float*)alloc(4096 * 128 * 4);
  float* xb1  = (float*)alloc(2048 * 128 * 4);
  float* xb2  = (float*)alloc(1024 * 128 * 4);
  float* xb3  = (float*)alloc(512 * 128 * 4);
  float* xin  = (float*)alloc(4096 * 128 * 4);
  float* tmpX = (float*)alloc(4096 * 128 * 4);
  float* tmpY = (float*)alloc(4096 * 128 * 4);
  float* dinv0 = (float*)alloc(4096 * 4);
  float* dinv1 = (float*)alloc(2048 * 4);
  float* dinv2 = (float*)alloc(1024 * 4);
  float* dinv3 = (float*)alloc(512 * 4);
  float* tsc  = (float*)alloc(4096 * 4);
  int*   perm1 = (int*)alloc(2048 * 4);
  int*   perm2 = (int*)alloc(1024 * 4);
  int*   perm3 = (int*)alloc(512 * 4);
  float* Wdf  = (float*)alloc(4 * 128 * 128 * 4);
  float* bdf  = (float*)alloc(4 * 128 * 4);
  float* Wuf  = (float*)alloc(3 * 128 * 128 * 4);
  float* buf_ = (float*)alloc(3 * 128 * 4);
  float* pwf  = (float*)alloc(3 * 128 * 4);
  int*   flags = (int*)alloc(4 * 4);
  // CSR for sparse L1 pool
  int* indeg  = (int*)alloc(4096 * 4);
  int* outdeg = (int*)alloc(4096 * 4);
  int* inoff  = (int*)alloc(4097 * 4);
  int* outoff = (int*)alloc(4097 * 4);
  int* incur  = (int*)alloc(4096 * 4);
  int* outcur = (int*)alloc(4096 * 4);
  int* inlist = (int*)alloc(65536 * 4);
  int* outlist= (int*)alloc(65536 * 4);
  int* inv    = (int*)alloc(4096 * 4);

  // aliases (dead regions during GCN phases)
  float* zpart = (float*)A1b;           // 16 * 4096 * 128 * 4 B = 33.5 MB = |A1b|
  u16*   yTh   = (u16*)A1bT;            // 1 MB
  u16*   yTl   = (u16*)A1bT + 128 * 4096;

  const int E = 65536, N0 = 4096;

  // dtype detection
  k_zeroflags<<<1, 64, 0, stream>>>(flags);
  k_detect<<<16, 256, 0, stream>>>((const u16*)x_in, ei, flags);

  auto cvt = [&](const void* src, float* dst, int n) {
    k_loadf<<<(n + 255) / 256, 256, 0, stream>>>(src, dst, n, flags);
  };
  cvt(x_in, xin, 4096 * 128);
  cvt(Wd_in, Wdf, 4 * 128 * 128);
  cvt(bd_in, bdf, 4 * 128);
  cvt(Wu_in, Wuf, 3 * 128 * 128);
  cvt(bu_in, buf_, 3 * 128);
  cvt(pw_in, pwf, 3 * 128);

  // adjacency (dense) + CSR (for sparse pool)
  k_fill0<<<4096, 256, 0, stream>>>((float4*)A0, 4096L * 4096 / 4);
  k_edges<<<(E + 255) / 256, 256, 0, stream>>>(ei, A0, E, N0, flags);
  k_degzero<<<(2 * N0 + 255) / 256, 256, 0, stream>>>(indeg, 2 * N0);   // indeg+outdeg contiguous
  k_degcnt<<<(E + 255) / 256, 256, 0, stream>>>(ei, E, N0, flags, indeg, outdeg);
  k_scan<<<1, 1024, 0, stream>>>(indeg, outdeg, inoff, outoff, incur, outcur, N0);
  k_csrfill<<<(E + 255) / 256, 256, 0, stream>>>(ei, E, N0, flags, incur, outcur, inlist, outlist);

  // level-0 GCN
  run_gcn(stream, A0, 4096, xin, Wdf, bdf, dinv0, 1, tmpY, yTh, yTl, zpart, 0, 1, xb0, nullptr, flags);

  // ---- level 1: sparse pool (A 0.4% dense -> edge-pair join) ----
  {
    int n = 4096, k = 2048;
    k_score<<<n / 4, 256, 0, stream>>>(xb0, pwf, tsc, n);
    k_rank<<<n / 256, 256, 0, stream>>>(tsc, n, k, perm1);
    k_invinit<<<(n + 255) / 256, 256, 0, stream>>>(inv, n);
    k_invset<<<(k + 255) / 256, 256, 0, stream>>>(perm1, inv, k);
    k_fill0<<<2048, 256, 0, stream>>>((float4*)A1p, (long)k * k / 4);
    k_spool<<<n / 4, 256, 0, stream>>>(inoff, inlist, outoff, outlist, inv, A1p, k, n);
    k_spedge<<<(E + 255) / 256, 256, 0, stream>>>(ei, E, n, flags, inv, A1p, k);
    k_gather<<<(k * 128 + 255) / 256, 256, 0, stream>>>(xb0, perm1, tsc, tmpX, k);
    run_gcn(stream, A1p, k, tmpX, Wdf + 16384, bdf + 128, dinv1, 1, tmpY, yTh, yTl, zpart, 0, 1, xb1, nullptr, flags);
  }

  // ---- levels 2,3: dense MFMA pool ----
  {
    float* Acurs[2]  = {A1p, A2p};
    float* Anexts[2] = {A2p, A3p};
    int*   perms[2]  = {perm2, perm3};
    float* xcurs[2]  = {xb1, xb2};
    float* xouts[2]  = {xb2, xb3};
    float* dinvs[2]  = {dinv2, dinv3};
    int    alos[2]   = {1, 1};
    int    spoolS[2] = {4, 8};
    int    ns[2]     = {2048, 1024};
    for (int li = 0; li < 2; ++li) {
      int n = ns[li], k = n / 2, lvl = li + 2;
      k_score<<<n / 4, 256, 0, stream>>>(xcurs[li], pwf + (lvl - 1) * 128, tsc, n);
      k_rank<<<n / 256, 256, 0, stream>>>(tsc, n, k, perms[li]);
      k_prep<<<dim3(n / 32, n / 32), 256, 0, stream>>>(Acurs[li], A1b, A1bT, n);
      float* Cn = Anexts[li];
      int Sp = spoolS[li];
      k_fill0<<<2048, 256, 0, stream>>>((float4*)Cn, (long)k * k / 4);
      k_mfma_pool<<<dim3(k / 128, k / 128, Sp), 256, 0, stream>>>(A1b, A1bT, perms[li], Cn, k, n, n / Sp);
      k_diag0<<<(k + 255) / 256, 256, 0, stream>>>(Cn, k);
      k_gather<<<(k * 128 + 255) / 256, 256, 0, stream>>>(xcurs[li], perms[li], tsc, tmpX, k);
      run_gcn(stream, Cn, k, tmpX, Wdf + lvl * 16384, bdf + lvl * 128,
              dinvs[li], 1, tmpY, yTh, yTl, zpart, alos[li], 1, xouts[li], nullptr, flags);
    }
  }

  // up path (dinv cached from down path)
  float* prev = xb3;
  float* Ajs[3]  = {A2p, A1p, A0};
  float* dinvu[3] = {dinv2, dinv1, dinv0};
  int*   pjs[3]  = {perm3, perm2, perm1};
  float* resb[3] = {xb2, xb1, xb0};
  int    njs[3]  = {1024, 2048, 4096};
  int    alou[3] = {1, 0, 0};
  for (int i = 0; i < 3; ++i) {
    int nj = njs[i], kk = nj / 2;
    k_copy<<<(nj * 128 + 255) / 256, 256, 0, stream>>>(resb[i], tmpX, nj * 128);
    k_scatadd<<<(kk * 128 + 255) / 256, 256, 0, stream>>>(tmpX, prev, pjs[i], kk);
    if (i < 2) {
      run_gcn(stream, Ajs[i], nj, tmpX, Wuf + i * 16384, buf_ + i * 128,
              dinvu[i], 0, tmpY, yTh, yTl, zpart, alou[i], 1, resb[i], nullptr, flags);
      prev = resb[i];
    } else {
      run_gcn(stream, Ajs[i], nj, tmpX, Wuf + i * 16384, buf_ + i * 128,
              dinvu[i], 0, tmpY, yTh, yTl, zpart, alou[i], 0, nullptr, d_out, flags);
    }
  }
}

// Round 6
// 471.366 us; speedup vs baseline: 3.5154x; 1.2022x over previous
//
#include <hip/hip_runtime.h>

typedef unsigned short u16;
typedef __attribute__((ext_vector_type(4))) short s16x4;
typedef __attribute__((ext_vector_type(8))) short s16x8;
typedef __attribute__((ext_vector_type(4))) float f32x4;

__device__ __forceinline__ float bf2f_(u16 b) { return __uint_as_float(((unsigned)b) << 16); }
__device__ __forceinline__ u16 f2bf_(float f) {
  unsigned u = __float_as_uint(f);
  return (u16)((u + 0x7FFFu + ((u >> 16) & 1u)) >> 16);
}

// decode edge e from int32 or int64 edge_index per flags[1]
__device__ __forceinline__ void edge_decode(const int* ei, int e, int E, const int* flags,
                                            int& src, int& dst) {
  bool is64 = flags[1] < 100;
  src = is64 ? ei[2 * e] : ei[e];
  dst = is64 ? ei[2 * E + 2 * e] : ei[E + e];
}

// ---------------- dtype detection (deterministic, device-side) ----------------
__global__ void k_zeroflags(int* f) { if (threadIdx.x < 4) f[threadIdx.x] = 0; }

__global__ __launch_bounds__(256) void k_detect(const u16* __restrict__ xb,
                                                const int* __restrict__ ei,
                                                int* __restrict__ flags) {
  int i = blockIdx.x * 256 + threadIdx.x;  // 4096 threads
  int e8 = (xb[2 * i] >> 7) & 0xFF;
  int sane = (e8 >= 100 && e8 <= 140) ? 1 : 0;
  int nz = (ei[2 * i + 1] != 0) ? 1 : 0;
  #pragma unroll
  for (int off = 32; off; off >>= 1) { sane += __shfl_down(sane, off); nz += __shfl_down(nz, off); }
  if ((threadIdx.x & 63) == 0) { atomicAdd(&flags[0], sane); atomicAdd(&flags[1], nz); }
}

__global__ void k_loadf(const void* __restrict__ src, float* __restrict__ dst, int n,
                        const int* __restrict__ flags) {
  int i = blockIdx.x * 256 + threadIdx.x;
  if (i >= n) return;
  bool isbf = flags[0] >= 2048;
  dst[i] = isbf ? bf2f_(((const u16*)src)[i]) : ((const float*)src)[i];
}

// ---------------- setup ----------------
__global__ void k_fill0(float4* __restrict__ p, long n4) {
  long i = blockIdx.x * 256L + threadIdx.x;
  long stride = (long)gridDim.x * 256L;
  for (; i < n4; i += stride) p[i] = make_float4(0.f, 0.f, 0.f, 0.f);
}

__global__ void k_edges(const int* __restrict__ ei, float* __restrict__ A, int E, int n,
                        const int* __restrict__ flags) {
  int e = blockIdx.x * 256 + threadIdx.x;
  if (e >= E) return;
  int src, dst; edge_decode(ei, e, E, flags, src, dst);
  if (src >= 0 && src < n && dst >= 0 && dst < n)
    atomicAdd(&A[(size_t)dst * n + src], 1.0f);
}

__global__ void k_copy(const float* __restrict__ src, float* __restrict__ dst, int n) {
  int i = blockIdx.x * 256 + threadIdx.x;
  if (i < n) dst[i] = src[i];
}

__global__ void k_diag0(float* __restrict__ C, int M) {
  int i = blockIdx.x * 256 + threadIdx.x;
  if (i < M) C[(size_t)i * M + i] = 0.f;
}

// ---------------- CSR build for sparse L1 pool (self-edges excluded) ----------------
__global__ void k_degzero(int* __restrict__ a, int n2) {
  int i = blockIdx.x * 256 + threadIdx.x;
  if (i < n2) a[i] = 0;
}

__global__ void k_degcnt(const int* __restrict__ ei, int E, int n, const int* __restrict__ flags,
                         int* __restrict__ indeg, int* __restrict__ outdeg) {
  int e = blockIdx.x * 256 + threadIdx.x;
  if (e >= E) return;
  int src, dst; edge_decode(ei, e, E, flags, src, dst);
  if (src < 0 || src >= n || dst < 0 || dst >= n || src == dst) return;
  atomicAdd(&indeg[dst], 1);
  atomicAdd(&outdeg[src], 1);
}

// exclusive scan of indeg/outdeg (n multiple of 1024) -> offsets + cursors
__global__ __launch_bounds__(1024) void k_scan(const int* __restrict__ indeg, const int* __restrict__ outdeg,
                                               int* __restrict__ inoff, int* __restrict__ outoff,
                                               int* __restrict__ incur, int* __restrict__ outcur, int n) {
  __shared__ int part[1024];
  int t = threadIdx.x;
  int per = n / 1024;
  for (int pass = 0; pass < 2; ++pass) {
    const int* deg = pass ? outdeg : indeg;
    int* off = pass ? outoff : inoff;
    int* cur = pass ? outcur : incur;
    int local[8];
    int s = 0;
    for (int j = 0; j < per; ++j) { local[j] = s; s += deg[t * per + j]; }
    part[t] = s;
    __syncthreads();
    for (int d = 1; d < 1024; d <<= 1) {
      int v = (t >= d) ? part[t - d] : 0;
      __syncthreads();
      part[t] += v;
      __syncthreads();
    }
    int base = (t == 0) ? 0 : part[t - 1];
    for (int j = 0; j < per; ++j) {
      off[t * per + j] = base + local[j];
      cur[t * per + j] = base + local[j];
    }
    if (t == 1023) off[n] = part[1023];
    __syncthreads();
  }
}

__global__ void k_csrfill(const int* __restrict__ ei, int E, int n, const int* __restrict__ flags,
                          int* __restrict__ incur, int* __restrict__ outcur,
                          int* __restrict__ inlist, int* __restrict__ outlist) {
  int e = blockIdx.x * 256 + threadIdx.x;
  if (e >= E) return;
  int src, dst; edge_decode(ei, e, E, flags, src, dst);
  if (src < 0 || src >= n || dst < 0 || dst >= n || src == dst) return;
  inlist[atomicAdd(&incur[dst], 1)] = src;
  outlist[atomicAdd(&outcur[src], 1)] = dst;
}

// sparse pool: C[ri][rj] += Ao2 path counts. One wave per node v.
__global__ __launch_bounds__(256) void k_spool(const int* __restrict__ inoff, const int* __restrict__ inlist,
                                               const int* __restrict__ outoff, const int* __restrict__ outlist,
                                               const int* __restrict__ inv, float* __restrict__ C,
                                               int M, int n) {
  int wave = threadIdx.x >> 6, lane = threadIdx.x & 63;
  int v = blockIdx.x * 4 + wave;
  if (v >= n) return;
  int ib = inoff[v], ni = inoff[v + 1] - ib;
  int ob = outoff[v], no = outoff[v + 1] - ob;
  int tot = ni * no;
  for (int p = lane; p < tot; p += 64) {
    int oi = p / ni, ii = p - oi * ni;
    int i = outlist[ob + oi];
    int j = inlist[ib + ii];
    if (i == j) continue;
    int ri = inv[i], rj = inv[j];
    if (ri >= 0 && rj >= 0) atomicAdd(&C[(size_t)ri * M + rj], 1.0f);
  }
}

// + 2*Ao term
__global__ void k_spedge(const int* __restrict__ ei, int E, int n, const int* __restrict__ flags,
                         const int* __restrict__ inv, float* __restrict__ C, int M) {
  int e = blockIdx.x * 256 + threadIdx.x;
  if (e >= E) return;
  int src, dst; edge_decode(ei, e, E, flags, src, dst);
  if (src < 0 || src >= n || dst < 0 || dst >= n || src == dst) return;
  int ri = inv[dst], rj = inv[src];
  if (ri >= 0 && rj >= 0) atomicAdd(&C[(size_t)ri * M + rj], 2.0f);
}

// ---------------- GCN pieces ----------------
__global__ __launch_bounds__(256) void k_dinv(const float* __restrict__ A, float* __restrict__ dinv, int n) {
  int row = blockIdx.x;
  const float* r = A + (size_t)row * n;
  float s = 0.f;
  for (int j = threadIdx.x; j < n; j += 256) s += r[j];
  #pragma unroll
  for (int off = 32; off; off >>= 1) s += __shfl_down(s, off);
  __shared__ float red[4];
  int wave = threadIdx.x >> 6, lane = threadIdx.x & 63;
  if (lane == 0) red[wave] = s;
  __syncthreads();
  if (threadIdx.x == 0) {
    float deg = red[0] + red[1] + red[2] + red[3] + 2.0f;
    dinv[row] = rsqrtf(deg);
  }
}

__global__ __launch_bounds__(256) void k_xw(const float* __restrict__ x, const float* __restrict__ W,
                                            const float* __restrict__ dinv, float* __restrict__ yp, int n) {
  __shared__ float xs_[16 * 128];
  int t = threadIdx.x;
  int row0 = blockIdx.x * 16;
  for (int e = t; e < 16 * 128; e += 256) {
    int r = e >> 7, c = e & 127;
    xs_[e] = x[(size_t)(row0 + r) * 128 + c];
  }
  __syncthreads();
  int c = t & 127, rh = t >> 7;
  float acc[8];
  #pragma unroll
  for (int ri = 0; ri < 8; ++ri) acc[ri] = 0.f;
  for (int k = 0; k < 128; ++k) {
    float wv = W[k * 128 + c];
    #pragma unroll
    for (int ri = 0; ri < 8; ++ri) acc[ri] += xs_[(rh * 8 + ri) * 128 + k] * wv;
  }
  #pragma unroll
  for (int ri = 0; ri < 8; ++ri) {
    int r = row0 + rh * 8 + ri;
    yp[(size_t)r * 128 + c] = dinv[r] * acc[ri];
  }
}

__global__ __launch_bounds__(256) void k_ytr(const float* __restrict__ y,
                                             u16* __restrict__ yTh, u16* __restrict__ yTl, int n) {
  __shared__ float tile[32][129];
  int t = threadIdx.x;
  int r0 = blockIdx.x * 32;
  #pragma unroll
  for (int it = 0; it < 4; ++it) {
    int q = it * 256 + t;
    int r = q >> 5, c4 = (q & 31) * 4;
    float4 v = *(const float4*)&y[(size_t)(r0 + r) * 128 + c4];
    tile[r][c4] = v.x; tile[r][c4 + 1] = v.y; tile[r][c4 + 2] = v.z; tile[r][c4 + 3] = v.w;
  }
  __syncthreads();
  #pragma unroll
  for (int it = 0; it < 2; ++it) {
    int q = it * 256 + t;
    int c = q >> 2, r8 = (q & 3) * 8;
    s16x8 h, l;
    #pragma unroll
    for (int j = 0; j < 8; ++j) {
      float v = tile[r8 + j][c];
      u16 hb = f2bf_(v);
      h[j] = (short)hb;
      l[j] = (short)f2bf_(v - bf2f_(hb));
    }
    *(s16x8*)&yTh[(size_t)c * n + r0 + r8] = h;
    *(s16x8*)&yTl[(size_t)c * n + r0 + r8] = l;
  }
}

// z-partials: zpart[s][i][c] = sum_{k in chunk s} A[i][k]*y[k][c].
// BK=64, XOR-swizzled LDS; 128x128 tile, 4 waves.
template<int ALO>
__global__ __launch_bounds__(256) void k_zgemm_mfma(const float* __restrict__ A,
                                                    const u16* __restrict__ yTh,
                                                    const u16* __restrict__ yTl,
                                                    float* __restrict__ zpart,
                                                    int n, int kchunk) {
  __shared__ __align__(16) u16 ah_[128 * 64];
  __shared__ __align__(16) u16 al_[ALO ? 128 * 64 : 8];
  __shared__ __align__(16) u16 bh_[128 * 64];
  __shared__ __align__(16) u16 bl_[128 * 64];
  int t = threadIdx.x;
  int row0 = blockIdx.x * 128;
  int s = blockIdx.y;
  int kbase = s * kchunk;
  int wave = t >> 6, lane = t & 63;
  int wr = wave >> 1, wc = wave & 1;
  int lrow = lane & 15, kb = lane >> 4;
  const f32x4 z4 = {0.f, 0.f, 0.f, 0.f};
  f32x4 acc[4][4];
  #pragma unroll
  for (int a = 0; a < 4; ++a)
    #pragma unroll
    for (int b = 0; b < 4; ++b) acc[a][b] = z4;

  for (int k0 = 0; k0 < kchunk; k0 += 64) {
    int koff = kbase + k0;
    __syncthreads();
    #pragma unroll
    for (int it = 0; it < 8; ++it) {
      int q = it * 256 + t;            // 2048 float4 chunks
      int r = q >> 4, i4 = q & 15;
      int g = i4 >> 1, h4 = (i4 & 1) * 4;
      float4 v = *(const float4*)&A[(size_t)(row0 + r) * n + koff + i4 * 4];
      float vv[4] = {v.x, v.y, v.z, v.w};
      s16x4 hh, ll;
      #pragma unroll
      for (int j = 0; j < 4; ++j) {
        u16 hb = f2bf_(vv[j]);
        hh[j] = (short)hb;
        if (ALO) ll[j] = (short)f2bf_(vv[j] - bf2f_(hb));
      }
      int ld = r * 64 + ((g ^ (r & 7)) << 3) + h4;
      *(s16x4*)&ah_[ld] = hh;
      if (ALO) *(s16x4*)&al_[ld] = ll;
    }
    #pragma unroll
    for (int it = 0; it < 4; ++it) {
      int q = it * 256 + t;            // 1024 s16x8 chunks each
      int r = q >> 3, g = q & 7;
      int ld = r * 64 + ((g ^ (r & 7)) << 3);
      *(s16x8*)&bh_[ld] = *(const s16x8*)(yTh + (size_t)r * n + koff + g * 8);
      *(s16x8*)&bl_[ld] = *(const s16x8*)(yTl + (size_t)r * n + koff + g * 8);
    }
    __syncthreads();
    #pragma unroll
    for (int ks = 0; ks < 2; ++ks) {
      int gg = ks * 4 + kb;
      int gsw = (gg ^ (lrow & 7)) << 3;
      s16x8 af[4], alf[4], bhf[4], blf[4];
      #pragma unroll
      for (int mi = 0; mi < 4; ++mi) {
        int row = wr * 64 + mi * 16 + lrow;
        af[mi] = *(const s16x8*)&ah_[row * 64 + gsw];
        if (ALO) alf[mi] = *(const s16x8*)&al_[row * 64 + gsw];
      }
      #pragma unroll
      for (int ni = 0; ni < 4; ++ni) {
        int row = wc * 64 + ni * 16 + lrow;
        bhf[ni] = *(const s16x8*)&bh_[row * 64 + gsw];
        blf[ni] = *(const s16x8*)&bl_[row * 64 + gsw];
      }
      #pragma unroll
      for (int mi = 0; mi < 4; ++mi)
        #pragma unroll
        for (int ni = 0; ni < 4; ++ni) {
          acc[mi][ni] = __builtin_amdgcn_mfma_f32_16x16x32_bf16(af[mi], bhf[ni], acc[mi][ni], 0, 0, 0);
          acc[mi][ni] = __builtin_amdgcn_mfma_f32_16x16x32_bf16(af[mi], blf[ni], acc[mi][ni], 0, 0, 0);
          if (ALO) {
            acc[mi][ni] = __builtin_amdgcn_mfma_f32_16x16x32_bf16(alf[mi], bhf[ni], acc[mi][ni], 0, 0, 0);
            acc[mi][ni] = __builtin_amdgcn_mfma_f32_16x16x32_bf16(alf[mi], blf[ni], acc[mi][ni], 0, 0, 0);
          }
        }
    }
  }
  int rbase = (lane >> 4) * 4;
  #pragma unroll
  for (int mi = 0; mi < 4; ++mi)
    #pragma unroll
    for (int ni = 0; ni < 4; ++ni)
      #pragma unroll
      for (int j = 0; j < 4; ++j) {
        int gi = row0 + wr * 64 + mi * 16 + rbase + j;
        int gj = wc * 64 + ni * 16 + (lane & 15);
        zpart[((size_t)s * n + gi) * 128 + gj] = acc[mi][ni][j];
      }
}

__global__ void k_epi(const float* __restrict__ zpart, const float* __restrict__ yp,
                      const float* __restrict__ dinv, const float* __restrict__ b,
                      float* __restrict__ outf, int tot, int act, int n, int S) {
  int i = blockIdx.x * 256 + threadIdx.x;
  if (i >= tot) return;
  int r = i >> 7, c = i & 127;
  float z = 0.f;
  for (int s = 0; s < S; ++s) z += zpart[((size_t)s * n + r) * 128 + c];
  float v = dinv[r] * (z + 2.0f * yp[i]) + b[c];
  if (act) v = (v >= 0.f) ? v : 0.01f * v;
  outf[i] = v;
}

__global__ void k_epi_out(const float* __restrict__ zpart, const float* __restrict__ yp,
                          const float* __restrict__ dinv, const float* __restrict__ b,
                          void* __restrict__ out, int tot, int n, int S, const int* __restrict__ flags) {
  int i = blockIdx.x * 256 + threadIdx.x;
  if (i >= tot) return;
  int r = i >> 7, c = i & 127;
  float z = 0.f;
  for (int s = 0; s < S; ++s) z += zpart[((size_t)s * n + r) * 128 + c];
  float v = dinv[r] * (z + 2.0f * yp[i]) + b[c];
  if (flags[0] >= 2048) ((u16*)out)[i] = f2bf_(v);
  else ((float*)out)[i] = v;
}

// ---------------- top-k pooling ----------------
__global__ __launch_bounds__(256) void k_score(const float* __restrict__ x, const float* __restrict__ w,
                                               float* __restrict__ ts, int n) {
  int wave = threadIdx.x >> 6, lane = threadIdx.x & 63;
  int row = blockIdx.x * 4 + wave;
  float w0 = w[lane], w1 = w[64 + lane];
  float nrm = w0 * w0 + w1 * w1;
  #pragma unroll
  for (int off = 32; off; off >>= 1) nrm += __shfl_down(nrm, off);
  nrm = sqrtf(__shfl(nrm, 0));
  if (row < n) {
    const float* xr = x + (size_t)row * 128;
    float d = xr[lane] * w0 + xr[64 + lane] * w1;
    #pragma unroll
    for (int off = 32; off; off >>= 1) d += __shfl_down(d, off);
    if (lane == 0) ts[row] = tanhf(d / nrm);
  }
}

// wave-per-candidate rank select: rank_i = #{j: key_j > key_i}; perm[rank]=i if rank<k.
// Unique keys (index embedded) -> race-free; optionally writes inv[i] = rank<k ? rank : -1.
__global__ __launch_bounds__(256) void k_rank(const float* __restrict__ ts, int n, int k,
                                              int* __restrict__ perm, int* __restrict__ inv) {
  int wave = threadIdx.x >> 6, lane = threadIdx.x & 63;
  int i = blockIdx.x * 4 + wave;
  if (i >= n) return;
  unsigned bits = __float_as_uint(ts[i]);
  unsigned u = (bits & 0x80000000u) ? ~bits : (bits | 0x80000000u);
  unsigned long long my = ((unsigned long long)u << 32) | (unsigned)(0xFFFFFFFFu - (unsigned)i);
  int rank = 0;
  for (int j = lane; j < n; j += 64) {
    unsigned b2 = __float_as_uint(ts[j]);
    unsigned u2 = (b2 & 0x80000000u) ? ~b2 : (b2 | 0x80000000u);
    unsigned long long kj = ((unsigned long long)u2 << 32) | (unsigned)(0xFFFFFFFFu - (unsigned)j);
    rank += (kj > my) ? 1 : 0;
  }
  #pragma unroll
  for (int off = 32; off; off >>= 1) rank += __shfl_down(rank, off);
  if (lane == 0) {
    if (rank < k) perm[rank] = i;
    if (inv) inv[i] = (rank < k) ? rank : -1;
  }
}

__global__ void k_gather(const float* __restrict__ x, const int* __restrict__ perm,
                         const float* __restrict__ ts, float* __restrict__ out, int k) {
  int i = blockIdx.x * 256 + threadIdx.x;
  if (i < k * 128) {
    int r = i >> 7, c = i & 127;
    int p = perm[r];
    out[i] = x[(size_t)p * 128 + c] * ts[p];
  }
}

__global__ void k_scatadd(float* __restrict__ dst, const float* __restrict__ src,
                          const int* __restrict__ perm, int k) {
  int i = blockIdx.x * 256 + threadIdx.x;
  if (i < k * 128) {
    int r = i >> 7, c = i & 127;
    dst[(size_t)perm[r] * 128 + c] += src[i];
  }
}

// ---------------- dense augment for L2/L3 ----------------
__global__ __launch_bounds__(256) void k_prep(const float* __restrict__ A, u16* __restrict__ A1,
                                              u16* __restrict__ A1T, int n) {
  __shared__ float tile[32][33];
  int bi = blockIdx.y, bj = blockIdx.x;
  int tx = threadIdx.x & 31, ty = threadIdx.x >> 5;
  int r0 = bi * 32, c0 = bj * 32;
  #pragma unroll
  for (int yy = 0; yy < 4; ++yy) {
    int r = ty * 4 + yy;
    int gr = r0 + r, gc = c0 + tx;
    float v = A[(size_t)gr * n + gc];
    if (gr == gc) v = 1.0f;
    tile[r][tx] = v;
    A1[(size_t)gr * n + gc] = f2bf_(v);
  }
  __syncthreads();
  #pragma unroll
  for (int yy = 0; yy < 4; ++yy) {
    int r = ty * 4 + yy;
    int gr = c0 + r, gc = r0 + tx;
    A1T[(size_t)gr * n + gc] = f2bf_(tile[tx][r]);
  }
}

// dense pool for L2/L3: split-K atomicAdd (exact: integer-valued). BK=64, swizzled.
__global__ __launch_bounds__(256) void k_mfma_pool(const u16* __restrict__ A1, const u16* __restrict__ A1T,
                                                   const int* __restrict__ perm, float* __restrict__ C,
                                                   int M, int K, int kchunk) {
  __shared__ __align__(16) u16 a_lds[128 * 64];
  __shared__ __align__(16) u16 b_lds[128 * 64];
  __shared__ int pr[128], pc[128];
  int t = threadIdx.x;
  int br = blockIdx.x, bc = blockIdx.y;
  int kbase = blockIdx.z * kchunk;
  if (t < 128) pr[t] = perm[br * 128 + t];
  else pc[t - 128] = perm[bc * 128 + (t - 128)];
  __syncthreads();
  int wave = t >> 6, lane = t & 63;
  int wr = wave >> 1, wc = wave & 1;
  int lrow = lane & 15, kb = lane >> 4;
  const f32x4 z4 = {0.f, 0.f, 0.f, 0.f};
  f32x4 acc[4][4];
  #pragma unroll
  for (int a = 0; a < 4; ++a)
    #pragma unroll
    for (int b = 0; b < 4; ++b) acc[a][b] = z4;

  for (int k0 = 0; k0 < kchunk; k0 += 64) {
    int koff = kbase + k0;
    __syncthreads();
    #pragma unroll
    for (int it = 0; it < 4; ++it) {
      int q = it * 256 + t;
      int r = q >> 3, g = q & 7;
      int ld = r * 64 + ((g ^ (r & 7)) << 3);
      *(s16x8*)&a_lds[ld] = *(const s16x8*)(A1 + (size_t)pr[r] * K + koff + g * 8);
      *(s16x8*)&b_lds[ld] = *(const s16x8*)(A1T + (size_t)pc[r] * K + koff + g * 8);
    }
    __syncthreads();
    #pragma unroll
    for (int ks = 0; ks < 2; ++ks) {
      int gg = ks * 4 + kb;
      int gsw = (gg ^ (lrow & 7)) << 3;
      s16x8 af[4], bfv[4];
      #pragma unroll
      for (int mi = 0; mi < 4; ++mi)
        af[mi] = *(const s16x8*)&a_lds[(wr * 64 + mi * 16 + lrow) * 64 + gsw];
      #pragma unroll
      for (int ni = 0; ni < 4; ++ni)
        bfv[ni] = *(const s16x8*)&b_lds[(wc * 64 + ni * 16 + lrow) * 64 + gsw];
      #pragma unroll
      for (int mi = 0; mi < 4; ++mi)
        #pragma unroll
        for (int ni = 0; ni < 4; ++ni)
          acc[mi][ni] = __builtin_amdgcn_mfma_f32_16x16x32_bf16(af[mi], bfv[ni], acc[mi][ni], 0, 0, 0);
    }
  }
  int rbase = (lane >> 4) * 4;
  #pragma unroll
  for (int mi = 0; mi < 4; ++mi)
    #pragma unroll
    for (int ni = 0; ni < 4; ++ni)
      #pragma unroll
      for (int j = 0; j < 4; ++j) {
        int gi = br * 128 + wr * 64 + mi * 16 + rbase + j;
        int gj = bc * 128 + wc * 64 + ni * 16 + (lane & 15);
        atomicAdd(&C[(size_t)gi * M + gj], acc[mi][ni][j]);
      }
}

// ---------------- driver ----------------
static void run_gcn(hipStream_t s, const float* A, int n, const float* xinp,
                    const float* W, const float* b, float* dinv, int compute_dinv, float* tmpY,
                    u16* yTh, u16* yTl, float* zpart, int alo,
                    int act, float* outf, void* outfinal, const int* flags) {
  if (compute_dinv) k_dinv<<<n, 256, 0, s>>>(A, dinv, n);
  k_xw<<<n / 16, 256, 0, s>>>(xinp, W, dinv, tmpY, n);
  k_ytr<<<n / 32, 256, 0, s>>>(tmpY, yTh, yTl, n);
  int S = (n >= 2048) ? 16 : (n == 1024 ? 8 : 4);
  int kchunk = n / S;
  if (alo)
    k_zgemm_mfma<1><<<dim3(n / 128, S), 256, 0, s>>>(A, yTh, yTl, zpart, n, kchunk);
  else
    k_zgemm_mfma<0><<<dim3(n / 128, S), 256, 0, s>>>(A, yTh, yTl, zpart, n, kchunk);
  int tot = n * 128;
  if (outf)
    k_epi<<<(tot + 255) / 256, 256, 0, s>>>(zpart, tmpY, dinv, b, outf, tot, act, n, S);
  else
    k_epi_out<<<(tot + 255) / 256, 256, 0, s>>>(zpart, tmpY, dinv, b, outfinal, tot, n, S, flags);
}

extern "C" void kernel_launch(void* const* d_in, const int* in_sizes, int n_in,
                              void* d_out, int out_size, void* d_ws, size_t ws_size,
                              hipStream_t stream) {
  (void)in_sizes; (void)n_in; (void)out_size; (void)ws_size;
  const void* x_in  = d_in[0];
  const int*  ei    = (const int*)d_in[1];
  const void* Wd_in = d_in[2];
  const void* bd_in = d_in[3];
  const void* Wu_in = d_in[4];
  const void* bu_in = d_in[5];
  const void* pw_in = d_in[6];

  char* p = (char*)d_ws;
  auto alloc = [&](size_t bytes) { char* r = p; p += (bytes + 255) & ~(size_t)255; return r; };
  float* A0   = (float*)alloc(4096ull * 4096 * 4);
  float* A1p  = (float*)alloc(2048ull * 2048 * 4);
  float* A2p  = (float*)alloc(1024ull * 1024 * 4);
  float* A3p  = (float*)alloc(512ull * 512 * 4);
  u16*   A1b  = (u16*)alloc(4096ull * 4096 * 2);   // L2/L3 pool src; zpart aliases during GCNs
  u16*   A1bT = (u16*)alloc(4096ull * 4096 * 2);   // L2/L3 pool src^T; yTh/yTl alias during GCNs
  float* xb0  = (float*)alloc(4096 * 128 * 4);
  float* xb1  = (float*)alloc(2048 * 128 * 4);
  float* xb2  = (float*)alloc(1024 * 128 * 4);
  float* xb3  = (float*)alloc(512 * 128 * 4);
  float* xin  = (float*)alloc(4096 * 128 * 4);
  float* tmpX = (float*)alloc(4096 * 128 * 4);
  float* tmpY = (float*)alloc(4096 * 128 * 4);
  float* dinv0 = (float*)alloc(4096 * 4);
  float* dinv1 = (float*)alloc(2048 * 4);
  float* dinv2 = (float*)alloc(1024 * 4);
  float* dinv3 = (float*)alloc(512 * 4);
  float* tsc  = (float*)alloc(4096 * 4);
  int*   perm1 = (int*)alloc(2048 * 4);
  int*   perm2 = (int*)alloc(1024 * 4);
  int*   perm3 = (int*)alloc(512 * 4);
  float* Wdf  = (float*)alloc(4 * 128 * 128 * 4);
  float* bdf  = (float*)alloc(4 * 128 * 4);
  float* Wuf  = (float*)alloc(3 * 128 * 128 * 4);
  float* buf_ = (float*)alloc(3 * 128 * 4);
  float* pwf  = (float*)alloc(3 * 128 * 4);
  int*   flags = (int*)alloc(4 * 4);
  // CSR for sparse L1 pool
  int* indeg  = (int*)alloc(4096 * 4);
  int* outdeg = (int*)alloc(4096 * 4);
  int* inoff  = (int*)alloc(4097 * 4);
  int* outoff = (int*)alloc(4097 * 4);
  int* incur  = (int*)alloc(4096 * 4);
  int* outcur = (int*)alloc(4096 * 4);
  int* inlist = (int*)alloc(65536 * 4);
  int* outlist= (int*)alloc(65536 * 4);
  int* inv    = (int*)alloc(4096 * 4);

  // aliases (dead regions during GCN phases)
  float* zpart = (float*)A1b;           // 16 * 4096 * 128 * 4 B = 33.5 MB = |A1b|
  u16*   yTh   = (u16*)A1bT;            // 1 MB
  u16*   yTl   = (u16*)A1bT + 128 * 4096;

  const int E = 65536, N0 = 4096;

  // dtype detection
  k_zeroflags<<<1, 64, 0, stream>>>(flags);
  k_detect<<<16, 256, 0, stream>>>((const u16*)x_in, ei, flags);

  auto cvt = [&](const void* src, float* dst, int n) {
    k_loadf<<<(n + 255) / 256, 256, 0, stream>>>(src, dst, n, flags);
  };
  cvt(x_in, xin, 4096 * 128);
  cvt(Wd_in, Wdf, 4 * 128 * 128);
  cvt(bd_in, bdf, 4 * 128);
  cvt(Wu_in, Wuf, 3 * 128 * 128);
  cvt(bu_in, buf_, 3 * 128);
  cvt(pw_in, pwf, 3 * 128);

  // adjacency (dense) + CSR (for sparse pool)
  k_fill0<<<4096, 256, 0, stream>>>((float4*)A0, 4096L * 4096 / 4);
  k_edges<<<(E + 255) / 256, 256, 0, stream>>>(ei, A0, E, N0, flags);
  k_degzero<<<(2 * N0 + 255) / 256, 256, 0, stream>>>(indeg, 2 * N0);
  k_degcnt<<<(E + 255) / 256, 256, 0, stream>>>(ei, E, N0, flags, indeg, outdeg);
  k_scan<<<1, 1024, 0, stream>>>(indeg, outdeg, inoff, outoff, incur, outcur, N0);
  k_csrfill<<<(E + 255) / 256, 256, 0, stream>>>(ei, E, N0, flags, incur, outcur, inlist, outlist);

  // level-0 GCN
  run_gcn(stream, A0, 4096, xin, Wdf, bdf, dinv0, 1, tmpY, yTh, yTl, zpart, 0, 1, xb0, nullptr, flags);

  // ---- level 1: sparse pool ----
  {
    int n = 4096, k = 2048;
    k_score<<<n / 4, 256, 0, stream>>>(xb0, pwf, tsc, n);
    k_rank<<<n / 4, 256, 0, stream>>>(tsc, n, k, perm1, inv);
    k_fill0<<<2048, 256, 0, stream>>>((float4*)A1p, (long)k * k / 4);
    k_spool<<<n / 4, 256, 0, stream>>>(inoff, inlist, outoff, outlist, inv, A1p, k, n);
    k_spedge<<<(E + 255) / 256, 256, 0, stream>>>(ei, E, n, flags, inv, A1p, k);
    k_gather<<<(k * 128 + 255) / 256, 256, 0, stream>>>(xb0, perm1, tsc, tmpX, k);
    run_gcn(stream, A1p, k, tmpX, Wdf + 16384, bdf + 128, dinv1, 1, tmpY, yTh, yTl, zpart, 0, 1, xb1, nullptr, flags);
  }

  // ---- levels 2,3: dense MFMA pool ----
  {
    float* Acurs[2]  = {A1p, A2p};
    float* Anexts[2] = {A2p, A3p};
    int*   perms[2]  = {perm2, perm3};
    float* xcurs[2]  = {xb1, xb2};
    float* xouts[2]  = {xb2, xb3};
    float* dinvs[2]  = {dinv2, dinv3};
    int    alos[2]   = {1, 1};
    int    spoolS[2] = {4, 8};
    int    ns[2]     = {2048, 1024};
    for (int li = 0; li < 2; ++li) {
      int n = ns[li], k = n / 2, lvl = li + 2;
      k_score<<<n / 4, 256, 0, stream>>>(xcurs[li], pwf + (lvl - 1) * 128, tsc, n);
      k_rank<<<n / 4, 256, 0, stream>>>(tsc, n, k, perms[li], nullptr);
      k_prep<<<dim3(n / 32, n / 32), 256, 0, stream>>>(Acurs[li], A1b, A1bT, n);
      float* Cn = Anexts[li];
      int Sp = spoolS[li];
      k_fill0<<<2048, 256, 0, stream>>>((float4*)Cn, (long)k * k / 4);
      k_mfma_pool<<<dim3(k / 128, k / 128, Sp), 256, 0, stream>>>(A1b, A1bT, perms[li], Cn, k, n, n / Sp);
      k_diag0<<<(k + 255) / 256, 256, 0, stream>>>(Cn, k);
      k_gather<<<(k * 128 + 255) / 256, 256, 0, stream>>>(xcurs[li], perms[li], tsc, tmpX, k);
      run_gcn(stream, Cn, k, tmpX, Wdf + lvl * 16384, bdf + lvl * 128,
              dinvs[li], 1, tmpY, yTh, yTl, zpart, alos[li], 1, xouts[li], nullptr, flags);
    }
  }

  // up path (dinv cached from down path)
  float* prev = xb3;
  float* Ajs[3]  = {A2p, A1p, A0};
  float* dinvu[3] = {dinv2, dinv1, dinv0};
  int*   pjs[3]  = {perm3, perm2, perm1};
  float* resb[3] = {xb2, xb1, xb0};
  int    njs[3]  = {1024, 2048, 4096};
  int    alou[3] = {1, 0, 0};
  for (int i = 0; i < 3; ++i) {
    int nj = njs[i], kk = nj / 2;
    k_copy<<<(nj * 128 + 255) / 256, 256, 0, stream>>>(resb[i], tmpX, nj * 128);
    k_scatadd<<<(kk * 128 + 255) / 256, 256, 0, stream>>>(tmpX, prev, pjs[i], kk);
    if (i < 2) {
      run_gcn(stream, Ajs[i], nj, tmpX, Wuf + i * 16384, buf_ + i * 128,
              dinvu[i], 0, tmpY, yTh, yTl, zpart, alou[i], 1, resb[i], nullptr, flags);
      prev = resb[i];
    } else {
      run_gcn(stream, Ajs[i], nj, tmpX, Wuf + i * 16384, buf_ + i * 128,
              dinvu[i], 0, tmpY, yTh, yTl, zpart, alou[i], 0, nullptr, d_out, flags);
    }
  }
}

// Round 7
// 459.983 us; speedup vs baseline: 3.6024x; 1.0247x over previous
//
#include <hip/hip_runtime.h>

typedef unsigned short u16;
typedef __attribute__((ext_vector_type(4))) short s16x4;
typedef __attribute__((ext_vector_type(8))) short s16x8;
typedef __attribute__((ext_vector_type(4))) float f32x4;

__device__ __forceinline__ float bf2f_(u16 b) { return __uint_as_float(((unsigned)b) << 16); }
__device__ __forceinline__ u16 f2bf_(float f) {
  unsigned u = __float_as_uint(f);
  return (u16)((u + 0x7FFFu + ((u >> 16) & 1u)) >> 16);
}

__device__ __forceinline__ void edge_decode(const int* ei, int e, int E, const int* flags,
                                            int& src, int& dst) {
  bool is64 = flags[1] < 100;
  src = is64 ? ei[2 * e] : ei[e];
  dst = is64 ? ei[2 * E + 2 * e] : ei[E + e];
}

// ---------------- dtype detection ----------------
__global__ void k_zeroi(int* a, int n) {
  int i = blockIdx.x * 256 + threadIdx.x;
  if (i < n) a[i] = 0;
}

__global__ __launch_bounds__(256) void k_detect(const u16* __restrict__ xb,
                                                const int* __restrict__ ei,
                                                int* __restrict__ flags) {
  int i = blockIdx.x * 256 + threadIdx.x;  // 4096 threads
  int e8 = (xb[2 * i] >> 7) & 0xFF;
  int sane = (e8 >= 100 && e8 <= 140) ? 1 : 0;
  int nz = (ei[2 * i + 1] != 0) ? 1 : 0;
  #pragma unroll
  for (int off = 32; off; off >>= 1) { sane += __shfl_down(sane, off); nz += __shfl_down(nz, off); }
  if ((threadIdx.x & 63) == 0) { atomicAdd(&flags[0], sane); atomicAdd(&flags[1], nz); }
}

// one-shot conversion of all 6 float inputs (bf16 or fp32 per flag)
__global__ void k_loadall(const void* x, const void* wd, const void* bd, const void* wu,
                          const void* bu, const void* pw,
                          float* xin, float* Wdf, float* bdf, float* Wuf, float* buf_, float* pwf,
                          const int* __restrict__ flags) {
  int i = blockIdx.x * 256 + threadIdx.x;
  const void* src; float* dst; int off;
  if (i < 524288) { src = x; dst = xin; off = i; }
  else if (i < 589824) { src = wd; dst = Wdf; off = i - 524288; }
  else if (i < 590336) { src = bd; dst = bdf; off = i - 589824; }
  else if (i < 639488) { src = wu; dst = Wuf; off = i - 590336; }
  else if (i < 639872) { src = bu; dst = buf_; off = i - 639488; }
  else if (i < 640256) { src = pw; dst = pwf; off = i - 639872; }
  else return;
  bool isbf = flags[0] >= 2048;
  dst[off] = isbf ? bf2f_(((const u16*)src)[off]) : ((const float*)src)[off];
}

// ---------------- generic fill ----------------
__global__ void k_fill0(float4* __restrict__ p, long n4) {
  long i = blockIdx.x * 256L + threadIdx.x;
  long stride = (long)gridDim.x * 256L;
  for (; i < n4; i += stride) p[i] = make_float4(0.f, 0.f, 0.f, 0.f);
}

__global__ void k_diag0(float* __restrict__ C, int M) {
  int i = blockIdx.x * 256 + threadIdx.x;
  if (i < M) C[(size_t)i * M + i] = 0.f;
}

// ---------------- CSR build ----------------
// pool CSR (self-edges excluded): indeg/outdeg/inlist/outlist
// spmv CSR (all edges):           indeg2/inlist2
__global__ void k_degcnt(const int* __restrict__ ei, int E, int n, const int* __restrict__ flags,
                         int* __restrict__ indeg, int* __restrict__ outdeg, int* __restrict__ indeg2) {
  int e = blockIdx.x * 256 + threadIdx.x;
  if (e >= E) return;
  int src, dst; edge_decode(ei, e, E, flags, src, dst);
  if (src < 0 || src >= n || dst < 0 || dst >= n) return;
  atomicAdd(&indeg2[dst], 1);
  if (src == dst) return;
  atomicAdd(&indeg[dst], 1);
  atomicAdd(&outdeg[src], 1);
}

__global__ __launch_bounds__(1024) void k_scan3(const int* __restrict__ d0, const int* __restrict__ d1,
                                                const int* __restrict__ d2,
                                                int* o0, int* o1, int* o2,
                                                int* c0, int* c1, int* c2, int n) {
  __shared__ int part[1024];
  int t = threadIdx.x;
  int per = n / 1024;
  for (int pass = 0; pass < 3; ++pass) {
    const int* deg = pass == 0 ? d0 : (pass == 1 ? d1 : d2);
    int* off = pass == 0 ? o0 : (pass == 1 ? o1 : o2);
    int* cur = pass == 0 ? c0 : (pass == 1 ? c1 : c2);
    int local[8];
    int s = 0;
    for (int j = 0; j < per; ++j) { local[j] = s; s += deg[t * per + j]; }
    part[t] = s;
    __syncthreads();
    for (int d = 1; d < 1024; d <<= 1) {
      int v = (t >= d) ? part[t - d] : 0;
      __syncthreads();
      part[t] += v;
      __syncthreads();
    }
    int base = (t == 0) ? 0 : part[t - 1];
    for (int j = 0; j < per; ++j) {
      off[t * per + j] = base + local[j];
      cur[t * per + j] = base + local[j];
    }
    if (t == 1023) off[n] = part[1023];
    __syncthreads();
  }
}

__global__ void k_csrfill(const int* __restrict__ ei, int E, int n, const int* __restrict__ flags,
                          int* __restrict__ incur, int* __restrict__ outcur, int* __restrict__ incur2,
                          int* __restrict__ inlist, int* __restrict__ outlist, int* __restrict__ inlist2) {
  int e = blockIdx.x * 256 + threadIdx.x;
  if (e >= E) return;
  int src, dst; edge_decode(ei, e, E, flags, src, dst);
  if (src < 0 || src >= n || dst < 0 || dst >= n) return;
  inlist2[atomicAdd(&incur2[dst], 1)] = src;
  if (src == dst) return;
  inlist[atomicAdd(&incur[dst], 1)] = src;
  outlist[atomicAdd(&outcur[src], 1)] = dst;
}

// sort each spmv CSR row ascending -> deterministic fp sum order
__global__ void k_csrsort(const int* __restrict__ inoff2, int* __restrict__ inlist2, int n) {
  int i = blockIdx.x * 256 + threadIdx.x;
  if (i >= n) return;
  int ib = inoff2[i], ie = inoff2[i + 1];
  for (int a = ib + 1; a < ie; ++a) {
    int v = inlist2[a];
    int b2 = a - 1;
    while (b2 >= ib && inlist2[b2] > v) { inlist2[b2 + 1] = inlist2[b2]; --b2; }
    inlist2[b2 + 1] = v;
  }
}

// dinv0 from edge counts: deg = indeg2 (all edges incl self, with multiplicity) + 2
__global__ void k_dinvcsr(const int* __restrict__ indeg2, float* __restrict__ dinv, int n) {
  int i = blockIdx.x * 256 + threadIdx.x;
  if (i < n) dinv[i] = rsqrtf((float)indeg2[i] + 2.0f);
}

// ---------------- sparse L1 pool ----------------
__global__ __launch_bounds__(256) void k_spool(const int* __restrict__ inoff, const int* __restrict__ inlist,
                                               const int* __restrict__ outoff, const int* __restrict__ outlist,
                                               const int* __restrict__ inv, float* __restrict__ C,
                                               int M, int n) {
  int wave = threadIdx.x >> 6, lane = threadIdx.x & 63;
  int v = blockIdx.x * 4 + wave;
  if (v >= n) return;
  int ib = inoff[v], ni = inoff[v + 1] - ib;
  int ob = outoff[v], no = outoff[v + 1] - ob;
  int tot = ni * no;
  for (int p = lane; p < tot; p += 64) {
    int oi = p / ni, ii = p - oi * ni;
    int i = outlist[ob + oi];
    int j = inlist[ib + ii];
    if (i == j) continue;
    int ri = inv[i], rj = inv[j];
    if (ri >= 0 && rj >= 0) atomicAdd(&C[(size_t)ri * M + rj], 1.0f);
  }
}

__global__ void k_spedge(const int* __restrict__ ei, int E, int n, const int* __restrict__ flags,
                         const int* __restrict__ inv, float* __restrict__ C, int M) {
  int e = blockIdx.x * 256 + threadIdx.x;
  if (e >= E) return;
  int src, dst; edge_decode(ei, e, E, flags, src, dst);
  if (src < 0 || src >= n || dst < 0 || dst >= n || src == dst) return;
  int ri = inv[dst], rj = inv[src];
  if (ri >= 0 && rj >= 0) atomicAdd(&C[(size_t)ri * M + rj], 2.0f);
}

// ---------------- GCN pieces ----------------
__global__ __launch_bounds__(256) void k_dinv(const float* __restrict__ A, float* __restrict__ dinv, int n) {
  int row = blockIdx.x;
  const float* r = A + (size_t)row * n;
  float s = 0.f;
  for (int j = threadIdx.x; j < n; j += 256) s += r[j];
  #pragma unroll
  for (int off = 32; off; off >>= 1) s += __shfl_down(s, off);
  __shared__ float red[4];
  int wave = threadIdx.x >> 6, lane = threadIdx.x & 63;
  if (lane == 0) red[wave] = s;
  __syncthreads();
  if (threadIdx.x == 0) {
    float deg = red[0] + red[1] + red[2] + red[3] + 2.0f;
    dinv[row] = rsqrtf(deg);
  }
}

__global__ __launch_bounds__(256) void k_xw(const float* __restrict__ x, const float* __restrict__ W,
                                            const float* __restrict__ dinv, float* __restrict__ yp, int n) {
  __shared__ float xs_[16 * 128];
  int t = threadIdx.x;
  int row0 = blockIdx.x * 16;
  for (int e = t; e < 16 * 128; e += 256) {
    int r = e >> 7, c = e & 127;
    xs_[e] = x[(size_t)(row0 + r) * 128 + c];
  }
  __syncthreads();
  int c = t & 127, rh = t >> 7;
  float acc[8];
  #pragma unroll
  for (int ri = 0; ri < 8; ++ri) acc[ri] = 0.f;
  for (int k = 0; k < 128; ++k) {
    float wv = W[k * 128 + c];
    #pragma unroll
    for (int ri = 0; ri < 8; ++ri) acc[ri] += xs_[(rh * 8 + ri) * 128 + k] * wv;
  }
  #pragma unroll
  for (int ri = 0; ri < 8; ++ri) {
    int r = row0 + rh * 8 + ri;
    yp[(size_t)r * 128 + c] = dinv[r] * acc[ri];
  }
}

// fused CSR SpMV + GCN epilogue: v = dinv[i]*(sum_s y[s] + 2*y[i]) + b; act / final-out
template<int FINAL>
__global__ __launch_bounds__(256) void k_spmv(const int* __restrict__ inoff2, const int* __restrict__ inlist2,
                                              const float* __restrict__ y, const float* __restrict__ dinv,
                                              const float* __restrict__ b,
                                              float* __restrict__ outf, void* __restrict__ outv,
                                              int n, int act, const int* __restrict__ flags) {
  int wave = threadIdx.x >> 6, lane = threadIdx.x & 63;
  int i = blockIdx.x * 4 + wave;
  if (i >= n) return;
  int ib = inoff2[i], ie = inoff2[i + 1];
  float z0 = 0.f, z1 = 0.f;
  for (int e = ib; e < ie; ++e) {
    int s = inlist2[e];
    z0 += y[(size_t)s * 128 + lane];
    z1 += y[(size_t)s * 128 + 64 + lane];
  }
  float di = dinv[i];
  float y0 = y[(size_t)i * 128 + lane], y1 = y[(size_t)i * 128 + 64 + lane];
  float v0 = di * (z0 + 2.0f * y0) + b[lane];
  float v1 = di * (z1 + 2.0f * y1) + b[64 + lane];
  if (act) { v0 = (v0 >= 0.f) ? v0 : 0.01f * v0; v1 = (v1 >= 0.f) ? v1 : 0.01f * v1; }
  if (FINAL) {
    if (flags[0] >= 2048) {
      ((u16*)outv)[(size_t)i * 128 + lane] = f2bf_(v0);
      ((u16*)outv)[(size_t)i * 128 + 64 + lane] = f2bf_(v1);
    } else {
      ((float*)outv)[(size_t)i * 128 + lane] = v0;
      ((float*)outv)[(size_t)i * 128 + 64 + lane] = v1;
    }
  } else {
    outf[(size_t)i * 128 + lane] = v0;
    outf[(size_t)i * 128 + 64 + lane] = v1;
  }
}

__global__ __launch_bounds__(256) void k_ytr(const float* __restrict__ y,
                                             u16* __restrict__ yTh, u16* __restrict__ yTl, int n) {
  __shared__ float tile[32][129];
  int t = threadIdx.x;
  int r0 = blockIdx.x * 32;
  #pragma unroll
  for (int it = 0; it < 4; ++it) {
    int q = it * 256 + t;
    int r = q >> 5, c4 = (q & 31) * 4;
    float4 v = *(const float4*)&y[(size_t)(r0 + r) * 128 + c4];
    tile[r][c4] = v.x; tile[r][c4 + 1] = v.y; tile[r][c4 + 2] = v.z; tile[r][c4 + 3] = v.w;
  }
  __syncthreads();
  #pragma unroll
  for (int it = 0; it < 2; ++it) {
    int q = it * 256 + t;
    int c = q >> 2, r8 = (q & 3) * 8;
    s16x8 h, l;
    #pragma unroll
    for (int j = 0; j < 8; ++j) {
      float v = tile[r8 + j][c];
      u16 hb = f2bf_(v);
      h[j] = (short)hb;
      l[j] = (short)f2bf_(v - bf2f_(hb));
    }
    *(s16x8*)&yTh[(size_t)c * n + r0 + r8] = h;
    *(s16x8*)&yTl[(size_t)c * n + r0 + r8] = l;
  }
}

// dense zgemm (n<=2048): zpart[s][i][c] = sum_{k in chunk} A[i][k]*y[k][c]
template<int ALO>
__global__ __launch_bounds__(256) void k_zgemm_mfma(const float* __restrict__ A,
                                                    const u16* __restrict__ yTh,
                                                    const u16* __restrict__ yTl,
                                                    float* __restrict__ zpart,
                                                    int n, int kchunk) {
  __shared__ __align__(16) u16 ah_[128 * 64];
  __shared__ __align__(16) u16 al_[ALO ? 128 * 64 : 8];
  __shared__ __align__(16) u16 bh_[128 * 64];
  __shared__ __align__(16) u16 bl_[128 * 64];
  int t = threadIdx.x;
  int row0 = blockIdx.x * 128;
  int s = blockIdx.y;
  int kbase = s * kchunk;
  int wave = t >> 6, lane = t & 63;
  int wr = wave >> 1, wc = wave & 1;
  int lrow = lane & 15, kb = lane >> 4;
  const f32x4 z4 = {0.f, 0.f, 0.f, 0.f};
  f32x4 acc[4][4];
  #pragma unroll
  for (int a = 0; a < 4; ++a)
    #pragma unroll
    for (int b = 0; b < 4; ++b) acc[a][b] = z4;

  for (int k0 = 0; k0 < kchunk; k0 += 64) {
    int koff = kbase + k0;
    __syncthreads();
    #pragma unroll
    for (int it = 0; it < 8; ++it) {
      int q = it * 256 + t;
      int r = q >> 4, i4 = q & 15;
      int g = i4 >> 1, h4 = (i4 & 1) * 4;
      float4 v = *(const float4*)&A[(size_t)(row0 + r) * n + koff + i4 * 4];
      float vv[4] = {v.x, v.y, v.z, v.w};
      s16x4 hh, ll;
      #pragma unroll
      for (int j = 0; j < 4; ++j) {
        u16 hb = f2bf_(vv[j]);
        hh[j] = (short)hb;
        if (ALO) ll[j] = (short)f2bf_(vv[j] - bf2f_(hb));
      }
      int ld = r * 64 + ((g ^ (r & 7)) << 3) + h4;
      *(s16x4*)&ah_[ld] = hh;
      if (ALO) *(s16x4*)&al_[ld] = ll;
    }
    #pragma unroll
    for (int it = 0; it < 4; ++it) {
      int q = it * 256 + t;
      int r = q >> 3, g = q & 7;
      int ld = r * 64 + ((g ^ (r & 7)) << 3);
      *(s16x8*)&bh_[ld] = *(const s16x8*)(yTh + (size_t)r * n + koff + g * 8);
      *(s16x8*)&bl_[ld] = *(const s16x8*)(yTl + (size_t)r * n + koff + g * 8);
    }
    __syncthreads();
    #pragma unroll
    for (int ks = 0; ks < 2; ++ks) {
      int gg = ks * 4 + kb;
      int gsw = (gg ^ (lrow & 7)) << 3;
      s16x8 af[4], alf[4], bhf[4], blf[4];
      #pragma unroll
      for (int mi = 0; mi < 4; ++mi) {
        int row = wr * 64 + mi * 16 + lrow;
        af[mi] = *(const s16x8*)&ah_[row * 64 + gsw];
        if (ALO) alf[mi] = *(const s16x8*)&al_[row * 64 + gsw];
      }
      #pragma unroll
      for (int ni = 0; ni < 4; ++ni) {
        int row = wc * 64 + ni * 16 + lrow;
        bhf[ni] = *(const s16x8*)&bh_[row * 64 + gsw];
        blf[ni] = *(const s16x8*)&bl_[row * 64 + gsw];
      }
      #pragma unroll
      for (int mi = 0; mi < 4; ++mi)
        #pragma unroll
        for (int ni = 0; ni < 4; ++ni) {
          acc[mi][ni] = __builtin_amdgcn_mfma_f32_16x16x32_bf16(af[mi], bhf[ni], acc[mi][ni], 0, 0, 0);
          acc[mi][ni] = __builtin_amdgcn_mfma_f32_16x16x32_bf16(af[mi], blf[ni], acc[mi][ni], 0, 0, 0);
          if (ALO) {
            acc[mi][ni] = __builtin_amdgcn_mfma_f32_16x16x32_bf16(alf[mi], bhf[ni], acc[mi][ni], 0, 0, 0);
            acc[mi][ni] = __builtin_amdgcn_mfma_f32_16x16x32_bf16(alf[mi], blf[ni], acc[mi][ni], 0, 0, 0);
          }
        }
    }
  }
  int rbase = (lane >> 4) * 4;
  #pragma unroll
  for (int mi = 0; mi < 4; ++mi)
    #pragma unroll
    for (int ni = 0; ni < 4; ++ni)
      #pragma unroll
      for (int j = 0; j < 4; ++j) {
        int gi = row0 + wr * 64 + mi * 16 + rbase + j;
        int gj = wc * 64 + ni * 16 + (lane & 15);
        zpart[((size_t)s * n + gi) * 128 + gj] = acc[mi][ni][j];
      }
}

__global__ void k_epi(const float* __restrict__ zpart, const float* __restrict__ yp,
                      const float* __restrict__ dinv, const float* __restrict__ b,
                      float* __restrict__ outf, int tot, int act, int n, int S) {
  int i = blockIdx.x * 256 + threadIdx.x;
  if (i >= tot) return;
  int r = i >> 7, c = i & 127;
  float z = 0.f;
  for (int s = 0; s < S; ++s) z += zpart[((size_t)s * n + r) * 128 + c];
  float v = dinv[r] * (z + 2.0f * yp[i]) + b[c];
  if (act) v = (v >= 0.f) ? v : 0.01f * v;
  outf[i] = v;
}

// ---------------- top-k pooling ----------------
__global__ __launch_bounds__(256) void k_score(const float* __restrict__ x, const float* __restrict__ w,
                                               float* __restrict__ ts, int n) {
  int wave = threadIdx.x >> 6, lane = threadIdx.x & 63;
  int row = blockIdx.x * 4 + wave;
  float w0 = w[lane], w1 = w[64 + lane];
  float nrm = w0 * w0 + w1 * w1;
  #pragma unroll
  for (int off = 32; off; off >>= 1) nrm += __shfl_down(nrm, off);
  nrm = sqrtf(__shfl(nrm, 0));
  if (row < n) {
    const float* xr = x + (size_t)row * 128;
    float d = xr[lane] * w0 + xr[64 + lane] * w1;
    #pragma unroll
    for (int off = 32; off; off >>= 1) d += __shfl_down(d, off);
    if (lane == 0) ts[row] = tanhf(d / nrm);
  }
}

// wave-per-candidate rank select; writes perm[rank]=i (rank<k) and inv[i]
__global__ __launch_bounds__(256) void k_rank(const float* __restrict__ ts, int n, int k,
                                              int* __restrict__ perm, int* __restrict__ inv) {
  int wave = threadIdx.x >> 6, lane = threadIdx.x & 63;
  int i = blockIdx.x * 4 + wave;
  if (i >= n) return;
  unsigned bits = __float_as_uint(ts[i]);
  unsigned u = (bits & 0x80000000u) ? ~bits : (bits | 0x80000000u);
  unsigned long long my = ((unsigned long long)u << 32) | (unsigned)(0xFFFFFFFFu - (unsigned)i);
  int rank = 0;
  for (int j = lane; j < n; j += 64) {
    unsigned b2 = __float_as_uint(ts[j]);
    unsigned u2 = (b2 & 0x80000000u) ? ~b2 : (b2 | 0x80000000u);
    unsigned long long kj = ((unsigned long long)u2 << 32) | (unsigned)(0xFFFFFFFFu - (unsigned)j);
    rank += (kj > my) ? 1 : 0;
  }
  #pragma unroll
  for (int off = 32; off; off >>= 1) rank += __shfl_down(rank, off);
  if (lane == 0) {
    if (rank < k) perm[rank] = i;
    inv[i] = (rank < k) ? rank : -1;
  }
}

__global__ void k_gather(const float* __restrict__ x, const int* __restrict__ perm,
                         const float* __restrict__ ts, float* __restrict__ out, int k) {
  int i = blockIdx.x * 256 + threadIdx.x;
  if (i < k * 128) {
    int r = i >> 7, c = i & 127;
    int p = perm[r];
    out[i] = x[(size_t)p * 128 + c] * ts[p];
  }
}

// fused unpool: dst[r] = res[r] + (inv[r]>=0 ? prev[inv[r]] : 0)
__global__ void k_unpool(const float* __restrict__ res, const float* __restrict__ prev,
                         const int* __restrict__ inv, float* __restrict__ dst, int tot) {
  int idx = blockIdx.x * 256 + threadIdx.x;
  if (idx >= tot) return;
  int r = idx >> 7, c = idx & 127;
  int ir = inv[r];
  float v = res[idx];
  if (ir >= 0) v += prev[(size_t)ir * 128 + c];
  dst[idx] = v;
}

// ---------------- dense augment for L2/L3 ----------------
__global__ __launch_bounds__(256) void k_prep(const float* __restrict__ A, u16* __restrict__ A1,
                                              u16* __restrict__ A1T, int n) {
  __shared__ float tile[32][33];
  int bi = blockIdx.y, bj = blockIdx.x;
  int tx = threadIdx.x & 31, ty = threadIdx.x >> 5;
  int r0 = bi * 32, c0 = bj * 32;
  #pragma unroll
  for (int yy = 0; yy < 4; ++yy) {
    int r = ty * 4 + yy;
    int gr = r0 + r, gc = c0 + tx;
    float v = A[(size_t)gr * n + gc];
    if (gr == gc) v = 1.0f;
    tile[r][tx] = v;
    A1[(size_t)gr * n + gc] = f2bf_(v);
  }
  __syncthreads();
  #pragma unroll
  for (int yy = 0; yy < 4; ++yy) {
    int r = ty * 4 + yy;
    int gr = c0 + r, gc = r0 + tx;
    A1T[(size_t)gr * n + gc] = f2bf_(tile[tx][r]);
  }
}

// dense pool (L2/L3): split-K atomicAdd (exact integers). BK=64, swizzled.
__global__ __launch_bounds__(256) void k_mfma_pool(const u16* __restrict__ A1, const u16* __restrict__ A1T,
                                                   const int* __restrict__ perm, float* __restrict__ C,
                                                   int M, int K, int kchunk) {
  __shared__ __align__(16) u16 a_lds[128 * 64];
  __shared__ __align__(16) u16 b_lds[128 * 64];
  __shared__ int pr[128], pc[128];
  int t = threadIdx.x;
  int br = blockIdx.x, bc = blockIdx.y;
  int kbase = blockIdx.z * kchunk;
  if (t < 128) pr[t] = perm[br * 128 + t];
  else pc[t - 128] = perm[bc * 128 + (t - 128)];
  __syncthreads();
  int wave = t >> 6, lane = t & 63;
  int wr = wave >> 1, wc = wave & 1;
  int lrow = lane & 15, kb = lane >> 4;
  const f32x4 z4 = {0.f, 0.f, 0.f, 0.f};
  f32x4 acc[4][4];
  #pragma unroll
  for (int a = 0; a < 4; ++a)
    #pragma unroll
    for (int b = 0; b < 4; ++b) acc[a][b] = z4;

  for (int k0 = 0; k0 < kchunk; k0 += 64) {
    int koff = kbase + k0;
    __syncthreads();
    #pragma unroll
    for (int it = 0; it < 4; ++it) {
      int q = it * 256 + t;
      int r = q >> 3, g = q & 7;
      int ld = r * 64 + ((g ^ (r & 7)) << 3);
      *(s16x8*)&a_lds[ld] = *(const s16x8*)(A1 + (size_t)pr[r] * K + koff + g * 8);
      *(s16x8*)&b_lds[ld] = *(const s16x8*)(A1T + (size_t)pc[r] * K + koff + g * 8);
    }
    __syncthreads();
    #pragma unroll
    for (int ks = 0; ks < 2; ++ks) {
      int gg = ks * 4 + kb;
      int gsw = (gg ^ (lrow & 7)) << 3;
      s16x8 af[4], bfv[4];
      #pragma unroll
      for (int mi = 0; mi < 4; ++mi)
        af[mi] = *(const s16x8*)&a_lds[(wr * 64 + mi * 16 + lrow) * 64 + gsw];
      #pragma unroll
      for (int ni = 0; ni < 4; ++ni)
        bfv[ni] = *(const s16x8*)&b_lds[(wc * 64 + ni * 16 + lrow) * 64 + gsw];
      #pragma unroll
      for (int mi = 0; mi < 4; ++mi)
        #pragma unroll
        for (int ni = 0; ni < 4; ++ni)
          acc[mi][ni] = __builtin_amdgcn_mfma_f32_16x16x32_bf16(af[mi], bfv[ni], acc[mi][ni], 0, 0, 0);
    }
  }
  int rbase = (lane >> 4) * 4;
  #pragma unroll
  for (int mi = 0; mi < 4; ++mi)
    #pragma unroll
    for (int ni = 0; ni < 4; ++ni)
      #pragma unroll
      for (int j = 0; j < 4; ++j) {
        int gi = br * 128 + wr * 64 + mi * 16 + rbase + j;
        int gj = bc * 128 + wc * 64 + ni * 16 + (lane & 15);
        atomicAdd(&C[(size_t)gi * M + gj], acc[mi][ni][j]);
      }
}

// ---------------- dense GCN driver (n<=2048) ----------------
static void run_gcn_dense(hipStream_t s, const float* A, int n, const float* xinp,
                          const float* W, const float* b, float* dinv, int compute_dinv, float* tmpY,
                          u16* yTh, u16* yTl, float* zpart, int alo, int act, float* outf) {
  if (compute_dinv) k_dinv<<<n, 256, 0, s>>>(A, dinv, n);
  k_xw<<<n / 16, 256, 0, s>>>(xinp, W, dinv, tmpY, n);
  k_ytr<<<n / 32, 256, 0, s>>>(tmpY, yTh, yTl, n);
  int S = (n >= 2048) ? 16 : (n == 1024 ? 8 : 4);
  int kchunk = n / S;
  if (alo)
    k_zgemm_mfma<1><<<dim3(n / 128, S), 256, 0, s>>>(A, yTh, yTl, zpart, n, kchunk);
  else
    k_zgemm_mfma<0><<<dim3(n / 128, S), 256, 0, s>>>(A, yTh, yTl, zpart, n, kchunk);
  int tot = n * 128;
  k_epi<<<(tot + 255) / 256, 256, 0, s>>>(zpart, tmpY, dinv, b, outf, tot, act, n, S);
}

extern "C" void kernel_launch(void* const* d_in, const int* in_sizes, int n_in,
                              void* d_out, int out_size, void* d_ws, size_t ws_size,
                              hipStream_t stream) {
  (void)in_sizes; (void)n_in; (void)out_size; (void)ws_size;
  const void* x_in  = d_in[0];
  const int*  ei    = (const int*)d_in[1];
  const void* Wd_in = d_in[2];
  const void* bd_in = d_in[3];
  const void* Wu_in = d_in[4];
  const void* bu_in = d_in[5];
  const void* pw_in = d_in[6];

  char* p = (char*)d_ws;
  auto alloc = [&](size_t bytes) { char* r = p; p += (bytes + 255) & ~(size_t)255; return r; };
  float* A1p  = (float*)alloc(2048ull * 2048 * 4);
  float* A2p  = (float*)alloc(1024ull * 1024 * 4);
  float* A3p  = (float*)alloc(512ull * 512 * 4);
  u16*   A1b  = (u16*)alloc(4096ull * 4096 * 2);   // L2/L3 pool src; zpart aliases during GCNs
  u16*   A1bT = (u16*)alloc(4096ull * 4096 * 2);   // L2/L3 pool src^T; yTh/yTl alias during GCNs
  float* xb0  = (float*)alloc(4096 * 128 * 4);
  float* xb1  = (float*)alloc(2048 * 128 * 4);
  float* xb2  = (float*)alloc(1024 * 128 * 4);
  float* xb3  = (float*)alloc(512 * 128 * 4);
  float* xin  = (float*)alloc(4096 * 128 * 4);
  float* tmpX = (float*)alloc(4096 * 128 * 4);
  float* tmpY = (float*)alloc(4096 * 128 * 4);
  float* dinv0 = (float*)alloc(4096 * 4);
  float* dinv1 = (float*)alloc(2048 * 4);
  float* dinv2 = (float*)alloc(1024 * 4);
  float* dinv3 = (float*)alloc(512 * 4);
  float* tsc  = (float*)alloc(4096 * 4);
  float* Wdf  = (float*)alloc(4 * 128 * 128 * 4);
  float* bdf  = (float*)alloc(4 * 128 * 4);
  float* Wuf  = (float*)alloc(3 * 128 * 128 * 4);
  float* buf_ = (float*)alloc(3 * 128 * 4);
  float* pwf  = (float*)alloc(3 * 128 * 4);
  // int block (flags + deg arrays contiguous for one-shot zero)
  int* iblk = (int*)alloc((12292 + 3 * 4097 + 3 * 4096 + 3 * 65536 + 4096 + 2048 + 1024 + 2048 + 1024 + 512) * 4);
  int* flags  = iblk;            // 4
  int* indeg  = iblk + 4;        // 4096 (pool, no self)
  int* outdeg = iblk + 4100;     // 4096
  int* indeg2 = iblk + 8196;     // 4096 (all edges)
  int* q      = iblk + 12292;
  int* inoff  = q;  q += 4097;
  int* outoff = q;  q += 4097;
  int* inoff2 = q;  q += 4097;
  int* incur  = q;  q += 4096;
  int* outcur = q;  q += 4096;
  int* incur2 = q;  q += 4096;
  int* inlist = q;  q += 65536;
  int* outlist= q;  q += 65536;
  int* inlist2= q;  q += 65536;
  int* inv1   = q;  q += 4096;
  int* inv2   = q;  q += 2048;
  int* inv3   = q;  q += 1024;
  int* perm1  = q;  q += 2048;
  int* perm2  = q;  q += 1024;
  int* perm3  = q;  q += 512;

  // aliases (dead regions during GCN phases)
  float* zpart = (float*)A1b;
  u16*   yTh   = (u16*)A1bT;
  u16*   yTl   = (u16*)A1bT + 128 * 4096;

  const int E = 65536, N0 = 4096;

  // setup: flags/deg zero, dtype detect, input conversion, CSR build
  k_zeroi<<<(12292 + 255) / 256, 256, 0, stream>>>(iblk, 12292);
  k_detect<<<16, 256, 0, stream>>>((const u16*)x_in, ei, flags);
  k_loadall<<<(640256 + 255) / 256, 256, 0, stream>>>(x_in, Wd_in, bd_in, Wu_in, bu_in, pw_in,
                                                      xin, Wdf, bdf, Wuf, buf_, pwf, flags);
  k_degcnt<<<(E + 255) / 256, 256, 0, stream>>>(ei, E, N0, flags, indeg, outdeg, indeg2);
  k_scan3<<<1, 1024, 0, stream>>>(indeg, outdeg, indeg2, inoff, outoff, inoff2,
                                  incur, outcur, incur2, N0);
  k_csrfill<<<(E + 255) / 256, 256, 0, stream>>>(ei, E, N0, flags, incur, outcur, incur2,
                                                 inlist, outlist, inlist2);
  k_csrsort<<<(N0 + 255) / 256, 256, 0, stream>>>(inoff2, inlist2, N0);
  k_dinvcsr<<<(N0 + 255) / 256, 256, 0, stream>>>(indeg2, dinv0, N0);

  // level-0 GCN (sparse, fused)
  k_xw<<<N0 / 16, 256, 0, stream>>>(xin, Wdf, dinv0, tmpY, N0);
  k_spmv<0><<<N0 / 4, 256, 0, stream>>>(inoff2, inlist2, tmpY, dinv0, bdf, xb0, nullptr, N0, 1, flags);

  // ---- level 1: sparse pool ----
  {
    int n = 4096, k = 2048;
    k_score<<<n / 4, 256, 0, stream>>>(xb0, pwf, tsc, n);
    k_rank<<<n / 4, 256, 0, stream>>>(tsc, n, k, perm1, inv1);
    k_fill0<<<2048, 256, 0, stream>>>((float4*)A1p, (long)k * k / 4);
    k_spool<<<n / 4, 256, 0, stream>>>(inoff, inlist, outoff, outlist, inv1, A1p, k, n);
    k_spedge<<<(E + 255) / 256, 256, 0, stream>>>(ei, E, n, flags, inv1, A1p, k);
    k_gather<<<(k * 128 + 255) / 256, 256, 0, stream>>>(xb0, perm1, tsc, tmpX, k);
    run_gcn_dense(stream, A1p, k, tmpX, Wdf + 16384, bdf + 128, dinv1, 1, tmpY, yTh, yTl, zpart, 0, 1, xb1);
  }

  // ---- levels 2,3: dense MFMA pool ----
  {
    float* Acurs[2]  = {A1p, A2p};
    float* Anexts[2] = {A2p, A3p};
    int*   perms[2]  = {perm2, perm3};
    int*   invs[2]   = {inv2, inv3};
    float* xcurs[2]  = {xb1, xb2};
    float* xouts[2]  = {xb2, xb3};
    float* dinvs[2]  = {dinv2, dinv3};
    int    spoolS[2] = {4, 8};
    int    ns[2]     = {2048, 1024};
    for (int li = 0; li < 2; ++li) {
      int n = ns[li], k = n / 2, lvl = li + 2;
      k_score<<<n / 4, 256, 0, stream>>>(xcurs[li], pwf + (lvl - 1) * 128, tsc, n);
      k_rank<<<n / 4, 256, 0, stream>>>(tsc, n, k, perms[li], invs[li]);
      k_prep<<<dim3(n / 32, n / 32), 256, 0, stream>>>(Acurs[li], A1b, A1bT, n);
      float* Cn = Anexts[li];
      int Sp = spoolS[li];
      k_fill0<<<2048, 256, 0, stream>>>((float4*)Cn, (long)k * k / 4);
      k_mfma_pool<<<dim3(k / 128, k / 128, Sp), 256, 0, stream>>>(A1b, A1bT, perms[li], Cn, k, n, n / Sp);
      k_diag0<<<(k + 255) / 256, 256, 0, stream>>>(Cn, k);
      k_gather<<<(k * 128 + 255) / 256, 256, 0, stream>>>(xcurs[li], perms[li], tsc, tmpX, k);
      run_gcn_dense(stream, Cn, k, tmpX, Wdf + lvl * 16384, bdf + lvl * 128,
                    dinvs[li], 1, tmpY, yTh, yTl, zpart, 1, 1, xouts[li]);
    }
  }

  // up path (dinv cached; unpool fused via inv maps)
  // i=0: n=1024, A2p; i=1: n=2048, A1p; i=2: n=4096, sparse A0
  k_unpool<<<(1024 * 128 + 255) / 256, 256, 0, stream>>>(xb2, xb3, inv3, tmpX, 1024 * 128);
  run_gcn_dense(stream, A2p, 1024, tmpX, Wuf, buf_, dinv2, 0, tmpY, yTh, yTl, zpart, 1, 1, xb2);

  k_unpool<<<(2048 * 128 + 255) / 256, 256, 0, stream>>>(xb1, xb2, inv2, tmpX, 2048 * 128);
  run_gcn_dense(stream, A1p, 2048, tmpX, Wuf + 16384, buf_ + 128, dinv1, 0, tmpY, yTh, yTl, zpart, 0, 1, xb1);

  k_unpool<<<(4096 * 128 + 255) / 256, 256, 0, stream>>>(xb0, xb1, inv1, tmpX, 4096 * 128);
  k_xw<<<N0 / 16, 256, 0, stream>>>(tmpX, Wuf + 2 * 16384, dinv0, tmpY, N0);
  k_spmv<1><<<N0 / 4, 256, 0, stream>>>(inoff2, inlist2, tmpY, dinv0, buf_ + 2 * 128, nullptr, d_out, N0, 0, flags);
}

// Round 8
// 392.167 us; speedup vs baseline: 4.2254x; 1.1729x over previous
//
#include <hip/hip_runtime.h>

typedef unsigned short u16;
typedef __attribute__((ext_vector_type(4))) short s16x4;
typedef __attribute__((ext_vector_type(8))) short s16x8;
typedef __attribute__((ext_vector_type(4))) float f32x4;

__device__ __forceinline__ float bf2f_(u16 b) { return __uint_as_float(((unsigned)b) << 16); }
__device__ __forceinline__ u16 f2bf_(float f) {
  unsigned u = __float_as_uint(f);
  return (u16)((u + 0x7FFFu + ((u >> 16) & 1u)) >> 16);
}

__device__ __forceinline__ void edge_decode(const int* ei, int e, int E, const int* flags,
                                            int& src, int& dst) {
  bool is64 = flags[1] < 100;
  src = is64 ? ei[2 * e] : ei[e];
  dst = is64 ? ei[2 * E + 2 * e] : ei[E + e];
}

// ---------------- dtype detection ----------------
__global__ void k_zeroi(int* a, int n) {
  int i = blockIdx.x * 256 + threadIdx.x;
  if (i < n) a[i] = 0;
}

__global__ __launch_bounds__(256) void k_detect(const u16* __restrict__ xb,
                                                const int* __restrict__ ei,
                                                int* __restrict__ flags) {
  int i = blockIdx.x * 256 + threadIdx.x;  // 4096 threads
  int e8 = (xb[2 * i] >> 7) & 0xFF;
  int sane = (e8 >= 100 && e8 <= 140) ? 1 : 0;
  int nz = (ei[2 * i + 1] != 0) ? 1 : 0;
  #pragma unroll
  for (int off = 32; off; off >>= 1) { sane += __shfl_down(sane, off); nz += __shfl_down(nz, off); }
  if ((threadIdx.x & 63) == 0) { atomicAdd(&flags[0], sane); atomicAdd(&flags[1], nz); }
}

// one-shot conversion of all 6 float inputs (bf16 or fp32 per flag)
__global__ void k_loadall(const void* x, const void* wd, const void* bd, const void* wu,
                          const void* bu, const void* pw,
                          float* xin, float* Wdf, float* bdf, float* Wuf, float* buf_, float* pwf,
                          const int* __restrict__ flags) {
  int i = blockIdx.x * 256 + threadIdx.x;
  const void* src; float* dst; int off;
  if (i < 524288) { src = x; dst = xin; off = i; }
  else if (i < 589824) { src = wd; dst = Wdf; off = i - 524288; }
  else if (i < 590336) { src = bd; dst = bdf; off = i - 589824; }
  else if (i < 639488) { src = wu; dst = Wuf; off = i - 590336; }
  else if (i < 639872) { src = bu; dst = buf_; off = i - 639488; }
  else if (i < 640256) { src = pw; dst = pwf; off = i - 639872; }
  else return;
  bool isbf = flags[0] >= 2048;
  dst[off] = isbf ? bf2f_(((const u16*)src)[off]) : ((const float*)src)[off];
}

// ---------------- generic fill ----------------
__global__ void k_fill0(float4* __restrict__ p, long n4) {
  long i = blockIdx.x * 256L + threadIdx.x;
  long stride = (long)gridDim.x * 256L;
  for (; i < n4; i += stride) p[i] = make_float4(0.f, 0.f, 0.f, 0.f);
}

__global__ void k_diag0(float* __restrict__ C, int M) {
  int i = blockIdx.x * 256 + threadIdx.x;
  if (i < M) C[(size_t)i * M + i] = 0.f;
}

// ---------------- CSR build ----------------
__global__ void k_degcnt(const int* __restrict__ ei, int E, int n, const int* __restrict__ flags,
                         int* __restrict__ indeg, int* __restrict__ outdeg, int* __restrict__ indeg2) {
  int e = blockIdx.x * 256 + threadIdx.x;
  if (e >= E) return;
  int src, dst; edge_decode(ei, e, E, flags, src, dst);
  if (src < 0 || src >= n || dst < 0 || dst >= n) return;
  atomicAdd(&indeg2[dst], 1);
  if (src == dst) return;
  atomicAdd(&indeg[dst], 1);
  atomicAdd(&outdeg[src], 1);
}

__global__ __launch_bounds__(1024) void k_scan3(const int* __restrict__ d0, const int* __restrict__ d1,
                                                const int* __restrict__ d2,
                                                int* o0, int* o1, int* o2,
                                                int* c0, int* c1, int* c2, int n) {
  __shared__ int part[1024];
  int t = threadIdx.x;
  int per = n / 1024;
  for (int pass = 0; pass < 3; ++pass) {
    const int* deg = pass == 0 ? d0 : (pass == 1 ? d1 : d2);
    int* off = pass == 0 ? o0 : (pass == 1 ? o1 : o2);
    int* cur = pass == 0 ? c0 : (pass == 1 ? c1 : c2);
    int local[8];
    int s = 0;
    for (int j = 0; j < per; ++j) { local[j] = s; s += deg[t * per + j]; }
    part[t] = s;
    __syncthreads();
    for (int d = 1; d < 1024; d <<= 1) {
      int v = (t >= d) ? part[t - d] : 0;
      __syncthreads();
      part[t] += v;
      __syncthreads();
    }
    int base = (t == 0) ? 0 : part[t - 1];
    for (int j = 0; j < per; ++j) {
      off[t * per + j] = base + local[j];
      cur[t * per + j] = base + local[j];
    }
    if (t == 1023) off[n] = part[1023];
    __syncthreads();
  }
}

__global__ void k_csrfill(const int* __restrict__ ei, int E, int n, const int* __restrict__ flags,
                          int* __restrict__ incur, int* __restrict__ outcur, int* __restrict__ incur2,
                          int* __restrict__ inlist, int* __restrict__ outlist, int* __restrict__ inlist2) {
  int e = blockIdx.x * 256 + threadIdx.x;
  if (e >= E) return;
  int src, dst; edge_decode(ei, e, E, flags, src, dst);
  if (src < 0 || src >= n || dst < 0 || dst >= n) return;
  inlist2[atomicAdd(&incur2[dst], 1)] = src;
  if (src == dst) return;
  inlist[atomicAdd(&incur[dst], 1)] = src;
  outlist[atomicAdd(&outcur[src], 1)] = dst;
}

// wave-parallel row sort -> deterministic fp sum order in spmv.
// rank = #{smaller} + #{equal at earlier slot}; equal keys are identical values,
// so output CONTENTS are deterministic even though slot order of duplicates isn't.
__global__ __launch_bounds__(256) void k_rowsort(const int* __restrict__ inoff2,
                                                 const int* __restrict__ inlist2,
                                                 int* __restrict__ outlist2, int n) {
  int wave = threadIdx.x >> 6, lane = threadIdx.x & 63;
  int row = blockIdx.x * 4 + wave;
  if (row >= n) return;
  int ib = inoff2[row], ie = inoff2[row + 1];
  int L = ie - ib;
  for (int i = lane; i < L; i += 64) {
    int ki = inlist2[ib + i];
    int rank = 0;
    for (int j = 0; j < L; ++j) {
      int kj = inlist2[ib + j];
      rank += (kj < ki || (kj == ki && j < i)) ? 1 : 0;
    }
    outlist2[ib + rank] = ki;
  }
}

// dinv0 from edge counts: deg = indeg2 (all edges incl self, with multiplicity) + 2
__global__ void k_dinvcsr(const int* __restrict__ indeg2, float* __restrict__ dinv, int n) {
  int i = blockIdx.x * 256 + threadIdx.x;
  if (i < n) dinv[i] = rsqrtf((float)indeg2[i] + 2.0f);
}

// ---------------- sparse L1 pool ----------------
__global__ __launch_bounds__(256) void k_spool(const int* __restrict__ inoff, const int* __restrict__ inlist,
                                               const int* __restrict__ outoff, const int* __restrict__ outlist,
                                               const int* __restrict__ inv, float* __restrict__ C,
                                               int M, int n) {
  int wave = threadIdx.x >> 6, lane = threadIdx.x & 63;
  int v = blockIdx.x * 4 + wave;
  if (v >= n) return;
  int ib = inoff[v], ni = inoff[v + 1] - ib;
  int ob = outoff[v], no = outoff[v + 1] - ob;
  int tot = ni * no;
  for (int p = lane; p < tot; p += 64) {
    int oi = p / ni, ii = p - oi * ni;
    int i = outlist[ob + oi];
    int j = inlist[ib + ii];
    if (i == j) continue;
    int ri = inv[i], rj = inv[j];
    if (ri >= 0 && rj >= 0) atomicAdd(&C[(size_t)ri * M + rj], 1.0f);
  }
}

__global__ void k_spedge(const int* __restrict__ ei, int E, int n, const int* __restrict__ flags,
                         const int* __restrict__ inv, float* __restrict__ C, int M) {
  int e = blockIdx.x * 256 + threadIdx.x;
  if (e >= E) return;
  int src, dst; edge_decode(ei, e, E, flags, src, dst);
  if (src < 0 || src >= n || dst < 0 || dst >= n || src == dst) return;
  int ri = inv[dst], rj = inv[src];
  if (ri >= 0 && rj >= 0) atomicAdd(&C[(size_t)ri * M + rj], 2.0f);
}

// ---------------- GCN pieces ----------------
__global__ __launch_bounds__(256) void k_dinv(const float* __restrict__ A, float* __restrict__ dinv, int n) {
  int row = blockIdx.x;
  const float* r = A + (size_t)row * n;
  float s = 0.f;
  for (int j = threadIdx.x; j < n; j += 256) s += r[j];
  #pragma unroll
  for (int off = 32; off; off >>= 1) s += __shfl_down(s, off);
  __shared__ float red[4];
  int wave = threadIdx.x >> 6, lane = threadIdx.x & 63;
  if (lane == 0) red[wave] = s;
  __syncthreads();
  if (threadIdx.x == 0) {
    float deg = red[0] + red[1] + red[2] + red[3] + 2.0f;
    dinv[row] = rsqrtf(deg);
  }
}

__global__ __launch_bounds__(256) void k_xw(const float* __restrict__ x, const float* __restrict__ W,
                                            const float* __restrict__ dinv, float* __restrict__ yp, int n) {
  __shared__ float xs_[16 * 128];
  int t = threadIdx.x;
  int row0 = blockIdx.x * 16;
  for (int e = t; e < 16 * 128; e += 256) {
    int r = e >> 7, c = e & 127;
    xs_[e] = x[(size_t)(row0 + r) * 128 + c];
  }
  __syncthreads();
  int c = t & 127, rh = t >> 7;
  float acc[8];
  #pragma unroll
  for (int ri = 0; ri < 8; ++ri) acc[ri] = 0.f;
  for (int k = 0; k < 128; ++k) {
    float wv = W[k * 128 + c];
    #pragma unroll
    for (int ri = 0; ri < 8; ++ri) acc[ri] += xs_[(rh * 8 + ri) * 128 + k] * wv;
  }
  #pragma unroll
  for (int ri = 0; ri < 8; ++ri) {
    int r = row0 + rh * 8 + ri;
    yp[(size_t)r * 128 + c] = dinv[r] * acc[ri];
  }
}

// fused CSR SpMV + GCN epilogue
template<int FINAL>
__global__ __launch_bounds__(256) void k_spmv(const int* __restrict__ inoff2, const int* __restrict__ inlist2,
                                              const float* __restrict__ y, const float* __restrict__ dinv,
                                              const float* __restrict__ b,
                                              float* __restrict__ outf, void* __restrict__ outv,
                                              int n, int act, const int* __restrict__ flags) {
  int wave = threadIdx.x >> 6, lane = threadIdx.x & 63;
  int i = blockIdx.x * 4 + wave;
  if (i >= n) return;
  int ib = inoff2[i], ie = inoff2[i + 1];
  float z0 = 0.f, z1 = 0.f;
  for (int e = ib; e < ie; ++e) {
    int s = inlist2[e];
    z0 += y[(size_t)s * 128 + lane];
    z1 += y[(size_t)s * 128 + 64 + lane];
  }
  float di = dinv[i];
  float y0 = y[(size_t)i * 128 + lane], y1 = y[(size_t)i * 128 + 64 + lane];
  float v0 = di * (z0 + 2.0f * y0) + b[lane];
  float v1 = di * (z1 + 2.0f * y1) + b[64 + lane];
  if (act) { v0 = (v0 >= 0.f) ? v0 : 0.01f * v0; v1 = (v1 >= 0.f) ? v1 : 0.01f * v1; }
  if (FINAL) {
    if (flags[0] >= 2048) {
      ((u16*)outv)[(size_t)i * 128 + lane] = f2bf_(v0);
      ((u16*)outv)[(size_t)i * 128 + 64 + lane] = f2bf_(v1);
    } else {
      ((float*)outv)[(size_t)i * 128 + lane] = v0;
      ((float*)outv)[(size_t)i * 128 + 64 + lane] = v1;
    }
  } else {
    outf[(size_t)i * 128 + lane] = v0;
    outf[(size_t)i * 128 + 64 + lane] = v1;
  }
}

__global__ __launch_bounds__(256) void k_ytr(const float* __restrict__ y,
                                             u16* __restrict__ yTh, u16* __restrict__ yTl, int n) {
  __shared__ float tile[32][129];
  int t = threadIdx.x;
  int r0 = blockIdx.x * 32;
  #pragma unroll
  for (int it = 0; it < 4; ++it) {
    int q = it * 256 + t;
    int r = q >> 5, c4 = (q & 31) * 4;
    float4 v = *(const float4*)&y[(size_t)(r0 + r) * 128 + c4];
    tile[r][c4] = v.x; tile[r][c4 + 1] = v.y; tile[r][c4 + 2] = v.z; tile[r][c4 + 3] = v.w;
  }
  __syncthreads();
  #pragma unroll
  for (int it = 0; it < 2; ++it) {
    int q = it * 256 + t;
    int c = q >> 2, r8 = (q & 3) * 8;
    s16x8 h, l;
    #pragma unroll
    for (int j = 0; j < 8; ++j) {
      float v = tile[r8 + j][c];
      u16 hb = f2bf_(v);
      h[j] = (short)hb;
      l[j] = (short)f2bf_(v - bf2f_(hb));
    }
    *(s16x8*)&yTh[(size_t)c * n + r0 + r8] = h;
    *(s16x8*)&yTl[(size_t)c * n + r0 + r8] = l;
  }
}

// dense zgemm (n<=2048)
template<int ALO>
__global__ __launch_bounds__(256) void k_zgemm_mfma(const float* __restrict__ A,
                                                    const u16* __restrict__ yTh,
                                                    const u16* __restrict__ yTl,
                                                    float* __restrict__ zpart,
                                                    int n, int kchunk) {
  __shared__ __align__(16) u16 ah_[128 * 64];
  __shared__ __align__(16) u16 al_[ALO ? 128 * 64 : 8];
  __shared__ __align__(16) u16 bh_[128 * 64];
  __shared__ __align__(16) u16 bl_[128 * 64];
  int t = threadIdx.x;
  int row0 = blockIdx.x * 128;
  int s = blockIdx.y;
  int kbase = s * kchunk;
  int wave = t >> 6, lane = t & 63;
  int wr = wave >> 1, wc = wave & 1;
  int lrow = lane & 15, kb = lane >> 4;
  const f32x4 z4 = {0.f, 0.f, 0.f, 0.f};
  f32x4 acc[4][4];
  #pragma unroll
  for (int a = 0; a < 4; ++a)
    #pragma unroll
    for (int b = 0; b < 4; ++b) acc[a][b] = z4;

  for (int k0 = 0; k0 < kchunk; k0 += 64) {
    int koff = kbase + k0;
    __syncthreads();
    #pragma unroll
    for (int it = 0; it < 8; ++it) {
      int q = it * 256 + t;
      int r = q >> 4, i4 = q & 15;
      int g = i4 >> 1, h4 = (i4 & 1) * 4;
      float4 v = *(const float4*)&A[(size_t)(row0 + r) * n + koff + i4 * 4];
      float vv[4] = {v.x, v.y, v.z, v.w};
      s16x4 hh, ll;
      #pragma unroll
      for (int j = 0; j < 4; ++j) {
        u16 hb = f2bf_(vv[j]);
        hh[j] = (short)hb;
        if (ALO) ll[j] = (short)f2bf_(vv[j] - bf2f_(hb));
      }
      int ld = r * 64 + ((g ^ (r & 7)) << 3) + h4;
      *(s16x4*)&ah_[ld] = hh;
      if (ALO) *(s16x4*)&al_[ld] = ll;
    }
    #pragma unroll
    for (int it = 0; it < 4; ++it) {
      int q = it * 256 + t;
      int r = q >> 3, g = q & 7;
      int ld = r * 64 + ((g ^ (r & 7)) << 3);
      *(s16x8*)&bh_[ld] = *(const s16x8*)(yTh + (size_t)r * n + koff + g * 8);
      *(s16x8*)&bl_[ld] = *(const s16x8*)(yTl + (size_t)r * n + koff + g * 8);
    }
    __syncthreads();
    #pragma unroll
    for (int ks = 0; ks < 2; ++ks) {
      int gg = ks * 4 + kb;
      int gsw = (gg ^ (lrow & 7)) << 3;
      s16x8 af[4], alf[4], bhf[4], blf[4];
      #pragma unroll
      for (int mi = 0; mi < 4; ++mi) {
        int row = wr * 64 + mi * 16 + lrow;
        af[mi] = *(const s16x8*)&ah_[row * 64 + gsw];
        if (ALO) alf[mi] = *(const s16x8*)&al_[row * 64 + gsw];
      }
      #pragma unroll
      for (int ni = 0; ni < 4; ++ni) {
        int row = wc * 64 + ni * 16 + lrow;
        bhf[ni] = *(const s16x8*)&bh_[row * 64 + gsw];
        blf[ni] = *(const s16x8*)&bl_[row * 64 + gsw];
      }
      #pragma unroll
      for (int mi = 0; mi < 4; ++mi)
        #pragma unroll
        for (int ni = 0; ni < 4; ++ni) {
          acc[mi][ni] = __builtin_amdgcn_mfma_f32_16x16x32_bf16(af[mi], bhf[ni], acc[mi][ni], 0, 0, 0);
          acc[mi][ni] = __builtin_amdgcn_mfma_f32_16x16x32_bf16(af[mi], blf[ni], acc[mi][ni], 0, 0, 0);
          if (ALO) {
            acc[mi][ni] = __builtin_amdgcn_mfma_f32_16x16x32_bf16(alf[mi], bhf[ni], acc[mi][ni], 0, 0, 0);
            acc[mi][ni] = __builtin_amdgcn_mfma_f32_16x16x32_bf16(alf[mi], blf[ni], acc[mi][ni], 0, 0, 0);
          }
        }
    }
  }
  int rbase = (lane >> 4) * 4;
  #pragma unroll
  for (int mi = 0; mi < 4; ++mi)
    #pragma unroll
    for (int ni = 0; ni < 4; ++ni)
      #pragma unroll
      for (int j = 0; j < 4; ++j) {
        int gi = row0 + wr * 64 + mi * 16 + rbase + j;
        int gj = wc * 64 + ni * 16 + (lane & 15);
        zpart[((size_t)s * n + gi) * 128 + gj] = acc[mi][ni][j];
      }
}

__global__ void k_epi(const float* __restrict__ zpart, const float* __restrict__ yp,
                      const float* __restrict__ dinv, const float* __restrict__ b,
                      float* __restrict__ outf, int tot, int act, int n, int S) {
  int i = blockIdx.x * 256 + threadIdx.x;
  if (i >= tot) return;
  int r = i >> 7, c = i & 127;
  float z = 0.f;
  for (int s = 0; s < S; ++s) z += zpart[((size_t)s * n + r) * 128 + c];
  float v = dinv[r] * (z + 2.0f * yp[i]) + b[c];
  if (act) v = (v >= 0.f) ? v : 0.01f * v;
  outf[i] = v;
}

// ---------------- top-k pooling ----------------
__global__ __launch_bounds__(256) void k_score(const float* __restrict__ x, const float* __restrict__ w,
                                               float* __restrict__ ts, int n) {
  int wave = threadIdx.x >> 6, lane = threadIdx.x & 63;
  int row = blockIdx.x * 4 + wave;
  float w0 = w[lane], w1 = w[64 + lane];
  float nrm = w0 * w0 + w1 * w1;
  #pragma unroll
  for (int off = 32; off; off >>= 1) nrm += __shfl_down(nrm, off);
  nrm = sqrtf(__shfl(nrm, 0));
  if (row < n) {
    const float* xr = x + (size_t)row * 128;
    float d = xr[lane] * w0 + xr[64 + lane] * w1;
    #pragma unroll
    for (int off = 32; off; off >>= 1) d += __shfl_down(d, off);
    if (lane == 0) ts[row] = tanhf(d / nrm);
  }
}

__global__ __launch_bounds__(256) void k_rank(const float* __restrict__ ts, int n, int k,
                                              int* __restrict__ perm, int* __restrict__ inv) {
  int wave = threadIdx.x >> 6, lane = threadIdx.x & 63;
  int i = blockIdx.x * 4 + wave;
  if (i >= n) return;
  unsigned bits = __float_as_uint(ts[i]);
  unsigned u = (bits & 0x80000000u) ? ~bits : (bits | 0x80000000u);
  unsigned long long my = ((unsigned long long)u << 32) | (unsigned)(0xFFFFFFFFu - (unsigned)i);
  int rank = 0;
  for (int j = lane; j < n; j += 64) {
    unsigned b2 = __float_as_uint(ts[j]);
    unsigned u2 = (b2 & 0x80000000u) ? ~b2 : (b2 | 0x80000000u);
    unsigned long long kj = ((unsigned long long)u2 << 32) | (unsigned)(0xFFFFFFFFu - (unsigned)j);
    rank += (kj > my) ? 1 : 0;
  }
  #pragma unroll
  for (int off = 32; off; off >>= 1) rank += __shfl_down(rank, off);
  if (lane == 0) {
    if (rank < k) perm[rank] = i;
    inv[i] = (rank < k) ? rank : -1;
  }
}

__global__ void k_gather(const float* __restrict__ x, const int* __restrict__ perm,
                         const float* __restrict__ ts, float* __restrict__ out, int k) {
  int i = blockIdx.x * 256 + threadIdx.x;
  if (i < k * 128) {
    int r = i >> 7, c = i & 127;
    int p = perm[r];
    out[i] = x[(size_t)p * 128 + c] * ts[p];
  }
}

__global__ void k_unpool(const float* __restrict__ res, const float* __restrict__ prev,
                         const int* __restrict__ inv, float* __restrict__ dst, int tot) {
  int idx = blockIdx.x * 256 + threadIdx.x;
  if (idx >= tot) return;
  int r = idx >> 7, c = idx & 127;
  int ir = inv[r];
  float v = res[idx];
  if (ir >= 0) v += prev[(size_t)ir * 128 + c];
  dst[idx] = v;
}

// ---------------- dense augment for L2/L3 ----------------
__global__ __launch_bounds__(256) void k_prep(const float* __restrict__ A, u16* __restrict__ A1,
                                              u16* __restrict__ A1T, int n) {
  __shared__ float tile[32][33];
  int bi = blockIdx.y, bj = blockIdx.x;
  int tx = threadIdx.x & 31, ty = threadIdx.x >> 5;
  int r0 = bi * 32, c0 = bj * 32;
  #pragma unroll
  for (int yy = 0; yy < 4; ++yy) {
    int r = ty * 4 + yy;
    int gr = r0 + r, gc = c0 + tx;
    float v = A[(size_t)gr * n + gc];
    if (gr == gc) v = 1.0f;
    tile[r][tx] = v;
    A1[(size_t)gr * n + gc] = f2bf_(v);
  }
  __syncthreads();
  #pragma unroll
  for (int yy = 0; yy < 4; ++yy) {
    int r = ty * 4 + yy;
    int gr = c0 + r, gc = r0 + tx;
    A1T[(size_t)gr * n + gc] = f2bf_(tile[tx][r]);
  }
}

// dense pool (L2/L3): split-K atomicAdd (exact integers). BK=64, swizzled.
__global__ __launch_bounds__(256) void k_mfma_pool(const u16* __restrict__ A1, const u16* __restrict__ A1T,
                                                   const int* __restrict__ perm, float* __restrict__ C,
                                                   int M, int K, int kchunk) {
  __shared__ __align__(16) u16 a_lds[128 * 64];
  __shared__ __align__(16) u16 b_lds[128 * 64];
  __shared__ int pr[128], pc[128];
  int t = threadIdx.x;
  int br = blockIdx.x, bc = blockIdx.y;
  int kbase = blockIdx.z * kchunk;
  if (t < 128) pr[t] = perm[br * 128 + t];
  else pc[t - 128] = perm[bc * 128 + (t - 128)];
  __syncthreads();
  int wave = t >> 6, lane = t & 63;
  int wr = wave >> 1, wc = wave & 1;
  int lrow = lane & 15, kb = lane >> 4;
  const f32x4 z4 = {0.f, 0.f, 0.f, 0.f};
  f32x4 acc[4][4];
  #pragma unroll
  for (int a = 0; a < 4; ++a)
    #pragma unroll
    for (int b = 0; b < 4; ++b) acc[a][b] = z4;

  for (int k0 = 0; k0 < kchunk; k0 += 64) {
    int koff = kbase + k0;
    __syncthreads();
    #pragma unroll
    for (int it = 0; it < 4; ++it) {
      int q = it * 256 + t;
      int r = q >> 3, g = q & 7;
      int ld = r * 64 + ((g ^ (r & 7)) << 3);
      *(s16x8*)&a_lds[ld] = *(const s16x8*)(A1 + (size_t)pr[r] * K + koff + g * 8);
      *(s16x8*)&b_lds[ld] = *(const s16x8*)(A1T + (size_t)pc[r] * K + koff + g * 8);
    }
    __syncthreads();
    #pragma unroll
    for (int ks = 0; ks < 2; ++ks) {
      int gg = ks * 4 + kb;
      int gsw = (gg ^ (lrow & 7)) << 3;
      s16x8 af[4], bfv[4];
      #pragma unroll
      for (int mi = 0; mi < 4; ++mi)
        af[mi] = *(const s16x8*)&a_lds[(wr * 64 + mi * 16 + lrow) * 64 + gsw];
      #pragma unroll
      for (int ni = 0; ni < 4; ++ni)
        bfv[ni] = *(const s16x8*)&b_lds[(wc * 64 + ni * 16 + lrow) * 64 + gsw];
      #pragma unroll
      for (int mi = 0; mi < 4; ++mi)
        #pragma unroll
        for (int ni = 0; ni < 4; ++ni)
          acc[mi][ni] = __builtin_amdgcn_mfma_f32_16x16x32_bf16(af[mi], bfv[ni], acc[mi][ni], 0, 0, 0);
    }
  }
  int rbase = (lane >> 4) * 4;
  #pragma unroll
  for (int mi = 0; mi < 4; ++mi)
    #pragma unroll
    for (int ni = 0; ni < 4; ++ni)
      #pragma unroll
      for (int j = 0; j < 4; ++j) {
        int gi = br * 128 + wr * 64 + mi * 16 + rbase + j;
        int gj = bc * 128 + wc * 64 + ni * 16 + (lane & 15);
        atomicAdd(&C[(size_t)gi * M + gj], acc[mi][ni][j]);
      }
}

// ---------------- dense GCN driver (n<=2048) ----------------
static void run_gcn_dense(hipStream_t s, const float* A, int n, const float* xinp,
                          const float* W, const float* b, float* dinv, int compute_dinv, float* tmpY,
                          u16* yTh, u16* yTl, float* zpart, int alo, int act, float* outf) {
  if (compute_dinv) k_dinv<<<n, 256, 0, s>>>(A, dinv, n);
  k_xw<<<n / 16, 256, 0, s>>>(xinp, W, dinv, tmpY, n);
  k_ytr<<<n / 32, 256, 0, s>>>(tmpY, yTh, yTl, n);
  int S = (n >= 2048) ? 16 : (n == 1024 ? 8 : 4);
  int kchunk = n / S;
  if (alo)
    k_zgemm_mfma<1><<<dim3(n / 128, S), 256, 0, s>>>(A, yTh, yTl, zpart, n, kchunk);
  else
    k_zgemm_mfma<0><<<dim3(n / 128, S), 256, 0, s>>>(A, yTh, yTl, zpart, n, kchunk);
  int tot = n * 128;
  k_epi<<<(tot + 255) / 256, 256, 0, s>>>(zpart, tmpY, dinv, b, outf, tot, act, n, S);
}

extern "C" void kernel_launch(void* const* d_in, const int* in_sizes, int n_in,
                              void* d_out, int out_size, void* d_ws, size_t ws_size,
                              hipStream_t stream) {
  (void)in_sizes; (void)n_in; (void)out_size; (void)ws_size;
  const void* x_in  = d_in[0];
  const int*  ei    = (const int*)d_in[1];
  const void* Wd_in = d_in[2];
  const void* bd_in = d_in[3];
  const void* Wu_in = d_in[4];
  const void* bu_in = d_in[5];
  const void* pw_in = d_in[6];

  char* p = (char*)d_ws;
  auto alloc = [&](size_t bytes) { char* r = p; p += (bytes + 255) & ~(size_t)255; return r; };
  float* A1p  = (float*)alloc(2048ull * 2048 * 4);
  float* A2p  = (float*)alloc(1024ull * 1024 * 4);
  float* A3p  = (float*)alloc(512ull * 512 * 4);
  u16*   A1b  = (u16*)alloc(4096ull * 4096 * 2);   // L2/L3 pool src; zpart aliases during GCNs
  u16*   A1bT = (u16*)alloc(4096ull * 4096 * 2);   // L2/L3 pool src^T; yTh/yTl alias during GCNs
  float* xb0  = (float*)alloc(4096 * 128 * 4);
  float* xb1  = (float*)alloc(2048 * 128 * 4);
  float* xb2  = (float*)alloc(1024 * 128 * 4);
  float* xb3  = (float*)alloc(512 * 128 * 4);
  float* xin  = (float*)alloc(4096 * 128 * 4);
  float* tmpX = (float*)alloc(4096 * 128 * 4);
  float* tmpY = (float*)alloc(4096 * 128 * 4);
  float* dinv0 = (float*)alloc(4096 * 4);
  float* dinv1 = (float*)alloc(2048 * 4);
  float* dinv2 = (float*)alloc(1024 * 4);
  float* dinv3 = (float*)alloc(512 * 4);
  float* tsc  = (float*)alloc(4096 * 4);
  float* Wdf  = (float*)alloc(4 * 128 * 128 * 4);
  float* bdf  = (float*)alloc(4 * 128 * 4);
  float* Wuf  = (float*)alloc(3 * 128 * 128 * 4);
  float* buf_ = (float*)alloc(3 * 128 * 4);
  float* pwf  = (float*)alloc(3 * 128 * 4);
  // int block (flags + deg arrays contiguous for one-shot zero)
  int* iblk = (int*)alloc((12292 + 3 * 4097 + 3 * 4096 + 4 * 65536 + 4096 + 2048 + 1024 + 2048 + 1024 + 512) * 4);
  int* flags  = iblk;            // 4
  int* indeg  = iblk + 4;        // 4096 (pool, no self)
  int* outdeg = iblk + 4100;     // 4096
  int* indeg2 = iblk + 8196;     // 4096 (all edges)
  int* q      = iblk + 12292;
  int* inoff  = q;  q += 4097;
  int* outoff = q;  q += 4097;
  int* inoff2 = q;  q += 4097;
  int* incur  = q;  q += 4096;
  int* outcur = q;  q += 4096;
  int* incur2 = q;  q += 4096;
  int* inlist = q;  q += 65536;
  int* outlist= q;  q += 65536;
  int* inlist2= q;  q += 65536;
  int* inlist2s = q; q += 65536;   // sorted spmv rows
  int* inv1   = q;  q += 4096;
  int* inv2   = q;  q += 2048;
  int* inv3   = q;  q += 1024;
  int* perm1  = q;  q += 2048;
  int* perm2  = q;  q += 1024;
  int* perm3  = q;  q += 512;

  // aliases (dead regions during GCN phases)
  float* zpart = (float*)A1b;
  u16*   yTh   = (u16*)A1bT;
  u16*   yTl   = (u16*)A1bT + 128 * 4096;

  const int E = 65536, N0 = 4096;

  // setup: flags/deg zero, dtype detect, input conversion, CSR build
  k_zeroi<<<(12292 + 255) / 256, 256, 0, stream>>>(iblk, 12292);
  k_detect<<<16, 256, 0, stream>>>((const u16*)x_in, ei, flags);
  k_loadall<<<(640256 + 255) / 256, 256, 0, stream>>>(x_in, Wd_in, bd_in, Wu_in, bu_in, pw_in,
                                                      xin, Wdf, bdf, Wuf, buf_, pwf, flags);
  k_degcnt<<<(E + 255) / 256, 256, 0, stream>>>(ei, E, N0, flags, indeg, outdeg, indeg2);
  k_scan3<<<1, 1024, 0, stream>>>(indeg, outdeg, indeg2, inoff, outoff, inoff2,
                                  incur, outcur, incur2, N0);
  k_csrfill<<<(E + 255) / 256, 256, 0, stream>>>(ei, E, N0, flags, incur, outcur, incur2,
                                                 inlist, outlist, inlist2);
  k_rowsort<<<N0 / 4, 256, 0, stream>>>(inoff2, inlist2, inlist2s, N0);
  k_dinvcsr<<<(N0 + 255) / 256, 256, 0, stream>>>(indeg2, dinv0, N0);

  // level-0 GCN (sparse, fused)
  k_xw<<<N0 / 16, 256, 0, stream>>>(xin, Wdf, dinv0, tmpY, N0);
  k_spmv<0><<<N0 / 4, 256, 0, stream>>>(inoff2, inlist2s, tmpY, dinv0, bdf, xb0, nullptr, N0, 1, flags);

  // ---- level 1: sparse pool ----
  {
    int n = 4096, k = 2048;
    k_score<<<n / 4, 256, 0, stream>>>(xb0, pwf, tsc, n);
    k_rank<<<n / 4, 256, 0, stream>>>(tsc, n, k, perm1, inv1);
    k_fill0<<<2048, 256, 0, stream>>>((float4*)A1p, (long)k * k / 4);
    k_spool<<<n / 4, 256, 0, stream>>>(inoff, inlist, outoff, outlist, inv1, A1p, k, n);
    k_spedge<<<(E + 255) / 256, 256, 0, stream>>>(ei, E, n, flags, inv1, A1p, k);
    k_gather<<<(k * 128 + 255) / 256, 256, 0, stream>>>(xb0, perm1, tsc, tmpX, k);
    run_gcn_dense(stream, A1p, k, tmpX, Wdf + 16384, bdf + 128, dinv1, 1, tmpY, yTh, yTl, zpart, 0, 1, xb1);
  }

  // ---- levels 2,3: dense MFMA pool ----
  {
    float* Acurs[2]  = {A1p, A2p};
    float* Anexts[2] = {A2p, A3p};
    int*   perms[2]  = {perm2, perm3};
    int*   invs[2]   = {inv2, inv3};
    float* xcurs[2]  = {xb1, xb2};
    float* xouts[2]  = {xb2, xb3};
    float* dinvs[2]  = {dinv2, dinv3};
    int    spoolS[2] = {4, 8};
    int    ns[2]     = {2048, 1024};
    for (int li = 0; li < 2; ++li) {
      int n = ns[li], k = n / 2, lvl = li + 2;
      k_score<<<n / 4, 256, 0, stream>>>(xcurs[li], pwf + (lvl - 1) * 128, tsc, n);
      k_rank<<<n / 4, 256, 0, stream>>>(tsc, n, k, perms[li], invs[li]);
      k_prep<<<dim3(n / 32, n / 32), 256, 0, stream>>>(Acurs[li], A1b, A1bT, n);
      float* Cn = Anexts[li];
      int Sp = spoolS[li];
      k_fill0<<<2048, 256, 0, stream>>>((float4*)Cn, (long)k * k / 4);
      k_mfma_pool<<<dim3(k / 128, k / 128, Sp), 256, 0, stream>>>(A1b, A1bT, perms[li], Cn, k, n, n / Sp);
      k_diag0<<<(k + 255) / 256, 256, 0, stream>>>(Cn, k);
      k_gather<<<(k * 128 + 255) / 256, 256, 0, stream>>>(xcurs[li], perms[li], tsc, tmpX, k);
      run_gcn_dense(stream, Cn, k, tmpX, Wdf + lvl * 16384, bdf + lvl * 128,
                    dinvs[li], 1, tmpY, yTh, yTl, zpart, 1, 1, xouts[li]);
    }
  }

  // up path (dinv cached; unpool fused via inv maps)
  k_unpool<<<(1024 * 128 + 255) / 256, 256, 0, stream>>>(xb2, xb3, inv3, tmpX, 1024 * 128);
  run_gcn_dense(stream, A2p, 1024, tmpX, Wuf, buf_, dinv2, 0, tmpY, yTh, yTl, zpart, 1, 1, xb2);

  k_unpool<<<(2048 * 128 + 255) / 256, 256, 0, stream>>>(xb1, xb2, inv2, tmpX, 2048 * 128);
  run_gcn_dense(stream, A1p, 2048, tmpX, Wuf + 16384, buf_ + 128, dinv1, 0, tmpY, yTh, yTl, zpart, 0, 1, xb1);

  k_unpool<<<(4096 * 128 + 255) / 256, 256, 0, stream>>>(xb0, xb1, inv1, tmpX, 4096 * 128);
  k_xw<<<N0 / 16, 256, 0, stream>>>(tmpX, Wuf + 2 * 16384, dinv0, tmpY, N0);
  k_spmv<1><<<N0 / 4, 256, 0, stream>>>(inoff2, inlist2s, tmpY, dinv0, buf_ + 2 * 128, nullptr, d_out, N0, 0, flags);
}